// Round 1
// baseline (863.165 us; speedup 1.0000x reference)
//
#include <hip/hip_runtime.h>
#include <cstdint>
#include <cstddef>

// Problem constants
// B=2, C=128, H=W=128, Hs=Ws=64, DG=8, KK=9, CG=16, COUT_DCN=64
// HW = 16384

__device__ __forceinline__ float relu_(float x) { return fmaxf(x, 0.f); }

// ---------------------------------------------------------------------------
// conv1x1: out[b][oc][p] = relu(sum_c W[oc][c] * X[c][p]) (+ residual for MODE 2)
// MODE 0: in1 = feat_l (128 ch)                      -> arm
// MODE 1: in1 = arm (128 ch), in2 = feat_s upsampled nearest *2 (128 ch) -> off_feat
// MODE 2: in1 = feat_align (64 ch), in2 = arm (residual add after relu)  -> out
// Block: 256 threads, tile = 64 pixels x 128 oc. Thread: 4 oc x 8 px.
// ---------------------------------------------------------------------------
template<int MODE, int CIN>
__global__ __launch_bounds__(256) void conv1x1_kernel(
    const float* __restrict__ in1, const float* __restrict__ in2,
    const float* __restrict__ Wm, float* __restrict__ out)
{
  constexpr int IN1C = (MODE == 2) ? 64 : 128;
  const int b  = blockIdx.y;
  const int p0 = blockIdx.x * 64;
  const int tid = threadIdx.x;
  const int tx = tid & 7;      // pixel octet: px = tx*8 .. +7
  const int ty = tid >> 3;     // oc quad:    oc = ty*4 .. +3

  __shared__ float Xs[16][64];
  __shared__ float Wt[16][128];

  float acc[4][8];
#pragma unroll
  for (int i = 0; i < 4; ++i)
#pragma unroll
    for (int j = 0; j < 8; ++j) acc[i][j] = 0.f;

  const int cS  = tid >> 4;         // staging channel 0..15
  const int pxS = (tid & 15) * 4;   // staging pixel base (X)
  const int ocS = (tid & 15) * 8;   // staging oc base (W)

  for (int cc = 0; cc < CIN; cc += 16) {
    __syncthreads();
    // ---- stage X chunk [16][64]
    {
      int gc = cc + cS;
      float4 v;
      if (MODE == 1 && gc >= 128) {
        int sc = gc - 128;  // feat_s channel
        float t[4];
#pragma unroll
        for (int j = 0; j < 4; ++j) {
          int pp = p0 + pxS + j;
          int hh = pp >> 7, ww = pp & 127;
          t[j] = 2.f * in2[((size_t)(b * 128 + sc) << 12) + ((hh >> 1) << 6) + (ww >> 1)];
        }
        v = make_float4(t[0], t[1], t[2], t[3]);
      } else {
        v = *(const float4*)(in1 + ((size_t)(b * IN1C + gc) << 14) + p0 + pxS);
      }
      *(float4*)&Xs[cS][pxS] = v;
      // ---- stage W chunk transposed [16][128]
#pragma unroll
      for (int j = 0; j < 8; ++j)
        Wt[cS][ocS + j] = Wm[(ocS + j) * CIN + cc + cS];
    }
    __syncthreads();
#pragma unroll
    for (int c = 0; c < 16; ++c) {
      float4 wv = *(const float4*)&Wt[c][ty * 4];
      float4 x0 = *(const float4*)&Xs[c][tx * 8];
      float4 x1 = *(const float4*)&Xs[c][tx * 8 + 4];
      float xs[8] = {x0.x, x0.y, x0.z, x0.w, x1.x, x1.y, x1.z, x1.w};
      float wf[4] = {wv.x, wv.y, wv.z, wv.w};
#pragma unroll
      for (int i = 0; i < 4; ++i)
#pragma unroll
        for (int j = 0; j < 8; ++j)
          acc[i][j] = fmaf(wf[i], xs[j], acc[i][j]);
    }
  }

#pragma unroll
  for (int i = 0; i < 4; ++i) {
    int oc = ty * 4 + i;
    size_t base = ((size_t)(b * 128 + oc) << 14) + p0 + tx * 8;
    float r[8];
#pragma unroll
    for (int j = 0; j < 8; ++j) r[j] = relu_(acc[i][j]);
    if (MODE == 2) {
#pragma unroll
      for (int j = 0; j < 8; ++j) r[j] += in2[base + j];
    }
    *(float4*)(out + base)     = make_float4(r[0], r[1], r[2], r[3]);
    *(float4*)(out + base + 4) = make_float4(r[4], r[5], r[6], r[7]);
  }
}

// ---------------------------------------------------------------------------
// com 3x3 conv, pad=1, + bias (no relu): om[b][oc][h][w], oc in [0,216)
// Grid: (16 tiles of 32x32, 27 oc-groups of 8, B). Block 256: thread = 1 h-row
// position x 4 w pixels, 8 oc accumulators. ic chunked by 8 through LDS.
// ---------------------------------------------------------------------------
__global__ __launch_bounds__(256) void com_conv_kernel(
    const float* __restrict__ x, const float* __restrict__ cw,
    const float* __restrict__ cb, float* __restrict__ om)
{
  const int b    = blockIdx.z;
  const int ocg  = blockIdx.y;             // 0..26
  const int tile = blockIdx.x;             // 0..15
  const int th = (tile >> 2) * 32, tw = (tile & 3) * 32;
  const int tid = threadIdx.x;
  const int lw = (tid & 7) * 4;            // 0,4,..,28
  const int lh = tid >> 3;                 // 0..31

  __shared__ float Xs[8 * 34 * 34];        // 36,992 B

  float acc[8][4];
#pragma unroll
  for (int a = 0; a < 8; ++a)
#pragma unroll
    for (int p = 0; p < 4; ++p) acc[a][p] = 0.f;

  for (int cc = 0; cc < 128; cc += 8) {
    __syncthreads();
    for (int idx = tid; idx < 8 * 1156; idx += 256) {
      int ic  = idx / 1156;
      int rem = idx - ic * 1156;
      int yy  = rem / 34;
      int xx  = rem - yy * 34;
      int gh = th + yy - 1, gw = tw + xx - 1;
      float v = 0.f;
      if ((unsigned)gh < 128u && (unsigned)gw < 128u)
        v = x[((size_t)(b * 128 + cc + ic) << 14) + (gh << 7) + gw];
      Xs[idx] = v;
    }
    __syncthreads();
#pragma unroll 1
    for (int ic = 0; ic < 8; ++ic) {
      float xr[3][6];
#pragma unroll
      for (int ky = 0; ky < 3; ++ky)
#pragma unroll
        for (int xx = 0; xx < 6; ++xx)
          xr[ky][xx] = Xs[ic * 1156 + (lh + ky) * 34 + lw + xx];
      const float* wp = cw + ((size_t)(ocg * 8) * 128 + (cc + ic)) * 9;
#pragma unroll
      for (int a = 0; a < 8; ++a) {
        const float* w9 = wp + a * 1152;   // uniform address -> scalar loads
#pragma unroll
        for (int ky = 0; ky < 3; ++ky)
#pragma unroll
          for (int kx = 0; kx < 3; ++kx) {
            float wv = w9[ky * 3 + kx];
#pragma unroll
            for (int p = 0; p < 4; ++p)
              acc[a][p] = fmaf(wv, xr[ky][kx + p], acc[a][p]);
          }
      }
    }
  }

#pragma unroll
  for (int a = 0; a < 8; ++a) {
    int oc = ocg * 8 + a;
    float bv = cb[oc];
    float4 r = make_float4(acc[a][0] + bv, acc[a][1] + bv,
                           acc[a][2] + bv, acc[a][3] + bv);
    *(float4*)(om + ((size_t)(b * 216 + oc) << 14) + ((th + lh) << 7) + tw + lw) = r;
  }
}

// ---------------------------------------------------------------------------
// dcn_w transpose: wT[((g*16+c)*9 + k)*64 + o] = dcn_w[(o*128 + g*16+c)*9 + k]
// ---------------------------------------------------------------------------
__global__ __launch_bounds__(256) void wt_kernel(const float* __restrict__ dw,
                                                 float* __restrict__ wT)
{
  int idx = blockIdx.x * 256 + threadIdx.x;  // 73728 total
  int o    = idx & 63;
  int rest = idx >> 6;       // gc*9 + k
  int k    = rest % 9;
  int gc   = rest / 9;
  wT[idx] = dw[(o * 128 + gc) * 9 + k];
}

// ---------------------------------------------------------------------------
// DCN: deformable sample of nearest-upsampled feat_s + masked einsum to 64 ch,
// + bias + relu.  Block 256 = 32 px x 8 g. Each thread: partial acc[64] over
// its g (9 taps x 16 ch), then LDS reduction over g in 4 chunks of 16 oc.
// ---------------------------------------------------------------------------
__global__ __launch_bounds__(256) void dcn_kernel(
    const float* __restrict__ fs, const float* __restrict__ om,
    const float* __restrict__ wT, const float* __restrict__ db,
    float* __restrict__ al)
{
  const int b   = blockIdx.y;
  const int p0  = blockIdx.x * 32;
  const int tid = threadIdx.x;
  const int px  = tid & 31;
  const int g   = tid >> 5;
  const int p = p0 + px;
  const int h = p >> 7, w = p & 127;

  float acc[64];
#pragma unroll
  for (int o = 0; o < 64; ++o) acc[o] = 0.f;

  const size_t omb = ((size_t)b * 216) << 14;
  const float* fsg = fs + (((size_t)(b * 128 + g * 16)) << 12);
  const float* wg  = wT + g * (16 * 9 * 64);

#pragma unroll 1
  for (int k = 0; k < 9; ++k) {
    float offy = om[omb + ((size_t)(g * 18 + 2 * k) << 14) + p];
    float offx = om[omb + ((size_t)(g * 18 + 2 * k + 1) << 14) + p];
    float mraw = om[omb + ((size_t)(144 + g * 9 + k) << 14) + p];
    float mv = 1.f / (1.f + __expf(-mraw));

    float py  = (float)(h + k / 3 - 1) + offy;
    float pxx = (float)(w + k % 3 - 1) + offx;
    float y0f = floorf(py), x0f = floorf(pxx);
    float ly = py - y0f, lx = pxx - x0f;
    int y0 = (int)y0f, x0i = (int)x0f;
    int y1 = y0 + 1, x1 = x0i + 1;

    int y0c = min(max(y0, 0), 127), y1c = min(max(y1, 0), 127);
    int x0c = min(max(x0i, 0), 127), x1c = min(max(x1, 0), 127);
    int ry0 = (y0c >> 1) << 6, ry1 = (y1c >> 1) << 6;
    int cx0 = x0c >> 1, cx1 = x1c >> 1;

    float w00 = (1.f - ly) * (1.f - lx) * mv;
    float w01 = (1.f - ly) * lx * mv;
    float w10 = ly * (1.f - lx) * mv;
    float w11 = ly * lx * mv;
    bool vy0 = (unsigned)y0 < 128u, vy1 = (unsigned)y1 < 128u;
    bool vx0 = (unsigned)x0i < 128u, vx1 = (unsigned)x1 < 128u;
    w00 = (vy0 && vx0) ? w00 : 0.f;
    w01 = (vy0 && vx1) ? w01 : 0.f;
    w10 = (vy1 && vx0) ? w10 : 0.f;
    w11 = (vy1 && vx1) ? w11 : 0.f;

#pragma unroll 1
    for (int c = 0; c < 16; ++c) {
      const float* fc = fsg + (c << 12);
      float v00 = fc[ry0 + cx0];
      float v01 = fc[ry0 + cx1];
      float v10 = fc[ry1 + cx0];
      float v11 = fc[ry1 + cx1];
      float v = w00 * v00 + w01 * v01 + w10 * v10 + w11 * v11;
      const float* wp = wg + (c * 9 + k) * 64;
#pragma unroll
      for (int oq = 0; oq < 16; ++oq) {   // fully unrolled: static acc indices
        float4 w4 = *(const float4*)(wp + oq * 4);
        acc[oq * 4 + 0] = fmaf(v, w4.x, acc[oq * 4 + 0]);
        acc[oq * 4 + 1] = fmaf(v, w4.y, acc[oq * 4 + 1]);
        acc[oq * 4 + 2] = fmaf(v, w4.z, acc[oq * 4 + 2]);
        acc[oq * 4 + 3] = fmaf(v, w4.w, acc[oq * 4 + 3]);
      }
    }
  }

  // ---- reduce over g (8 threads per pixel), 4 chunks of 16 oc
  __shared__ float red[256][17];
  const int px2 = tid & 31;
  const int og  = tid >> 5;
#pragma unroll
  for (int r = 0; r < 4; ++r) {           // fully unrolled: static acc indices
    __syncthreads();
#pragma unroll
    for (int j = 0; j < 16; ++j) red[tid][j] = acc[r * 16 + j];
    __syncthreads();
#pragma unroll
    for (int jj = 0; jj < 2; ++jj) {
      int ol = og * 2 + jj;
      float s = 0.f;
#pragma unroll
      for (int gg = 0; gg < 8; ++gg) s += red[gg * 32 + px2][ol];
      int oc = r * 16 + ol;
      s += db[oc];
      al[((size_t)(b * 64 + oc) << 14) + p0 + px2] = fmaxf(s, 0.f);
    }
  }
}

// ---------------------------------------------------------------------------
extern "C" void kernel_launch(void* const* d_in, const int* in_sizes, int n_in,
                              void* d_out, int out_size, void* d_ws, size_t ws_size,
                              hipStream_t stream)
{
  const float* feat_l   = (const float*)d_in[0];
  const float* feat_s   = (const float*)d_in[1];
  const float* fsm_w    = (const float*)d_in[2];
  const float* offset_w = (const float*)d_in[3];
  const float* com_w    = (const float*)d_in[4];
  const float* com_b    = (const float*)d_in[5];
  const float* dcn_w    = (const float*)d_in[6];
  const float* dcn_b    = (const float*)d_in[7];
  const float* cat_w    = (const float*)d_in[8];
  float* out = (float*)d_out;

  float* ws  = (float*)d_ws;
  float* arm = ws;                    // 2*128*16384 = 4,194,304
  float* off = ws + 4194304;          // 4,194,304
  float* omb = ws + 8388608;          // 2*216*16384 = 7,077,888
  float* al  = ws + 15466496;         // 2*64*16384 = 2,097,152
  float* wT  = ws + 17563648;         // 73,728   (total ~70.5 MB)

  hipLaunchKernelGGL(wt_kernel, dim3(288), dim3(256), 0, stream, dcn_w, wT);
  hipLaunchKernelGGL((conv1x1_kernel<0, 128>), dim3(256, 2), dim3(256), 0, stream,
                     feat_l, nullptr, fsm_w, arm);
  hipLaunchKernelGGL((conv1x1_kernel<1, 256>), dim3(256, 2), dim3(256), 0, stream,
                     arm, feat_s, offset_w, off);
  hipLaunchKernelGGL(com_conv_kernel, dim3(16, 27, 2), dim3(256), 0, stream,
                     off, com_w, com_b, omb);
  hipLaunchKernelGGL(dcn_kernel, dim3(512, 2), dim3(256), 0, stream,
                     feat_s, omb, wT, dcn_b, al);
  hipLaunchKernelGGL((conv1x1_kernel<2, 64>), dim3(256, 2), dim3(256), 0, stream,
                     al, arm, cat_w, out);
}

// Round 2
// 689.900 us; speedup vs baseline: 1.2511x; 1.2511x over previous
//
#include <hip/hip_runtime.h>
#include <cstdint>
#include <cstddef>

// Problem constants
// B=2, C=128, H=W=128, Hs=Ws=64, DG=8, KK=9, CG=16, COUT_DCN=64
// HW = 16384

__device__ __forceinline__ float relu_(float x) { return fmaxf(x, 0.f); }

// ---------------------------------------------------------------------------
// conv1x1: out[b][oc][p] = relu(sum_c W[oc][c] * X[c][p]) (+ residual for MODE 2)
// MODE 0: in1 = feat_l (128 ch)                      -> arm
// MODE 1: in1 = arm (128 ch), in2 = feat_s upsampled nearest *2 (128 ch) -> off_feat
// MODE 2: in1 = feat_align (64 ch), in2 = arm (residual add after relu)  -> out
// ---------------------------------------------------------------------------
template<int MODE, int CIN>
__global__ __launch_bounds__(256) void conv1x1_kernel(
    const float* __restrict__ in1, const float* __restrict__ in2,
    const float* __restrict__ Wm, float* __restrict__ out)
{
  constexpr int IN1C = (MODE == 2) ? 64 : 128;
  const int b  = blockIdx.y;
  const int p0 = blockIdx.x * 64;
  const int tid = threadIdx.x;
  const int tx = tid & 7;      // pixel octet: px = tx*8 .. +7
  const int ty = tid >> 3;     // oc quad:    oc = ty*4 .. +3

  __shared__ float Xs[16][64];
  __shared__ float Wt[16][128];

  float acc[4][8];
#pragma unroll
  for (int i = 0; i < 4; ++i)
#pragma unroll
    for (int j = 0; j < 8; ++j) acc[i][j] = 0.f;

  const int cS  = tid >> 4;         // staging channel 0..15
  const int pxS = (tid & 15) * 4;   // staging pixel base (X)
  const int ocS = (tid & 15) * 8;   // staging oc base (W)

  for (int cc = 0; cc < CIN; cc += 16) {
    __syncthreads();
    {
      int gc = cc + cS;
      float4 v;
      if (MODE == 1 && gc >= 128) {
        int sc = gc - 128;  // feat_s channel
        float t[4];
#pragma unroll
        for (int j = 0; j < 4; ++j) {
          int pp = p0 + pxS + j;
          int hh = pp >> 7, ww = pp & 127;
          t[j] = 2.f * in2[((size_t)(b * 128 + sc) << 12) + ((hh >> 1) << 6) + (ww >> 1)];
        }
        v = make_float4(t[0], t[1], t[2], t[3]);
      } else {
        v = *(const float4*)(in1 + ((size_t)(b * IN1C + gc) << 14) + p0 + pxS);
      }
      *(float4*)&Xs[cS][pxS] = v;
#pragma unroll
      for (int j = 0; j < 8; ++j)
        Wt[cS][ocS + j] = Wm[(ocS + j) * CIN + cc + cS];
    }
    __syncthreads();
#pragma unroll
    for (int c = 0; c < 16; ++c) {
      float4 wv = *(const float4*)&Wt[c][ty * 4];
      float4 x0 = *(const float4*)&Xs[c][tx * 8];
      float4 x1 = *(const float4*)&Xs[c][tx * 8 + 4];
      float xs[8] = {x0.x, x0.y, x0.z, x0.w, x1.x, x1.y, x1.z, x1.w};
      float wf[4] = {wv.x, wv.y, wv.z, wv.w};
#pragma unroll
      for (int i = 0; i < 4; ++i)
#pragma unroll
        for (int j = 0; j < 8; ++j)
          acc[i][j] = fmaf(wf[i], xs[j], acc[i][j]);
    }
  }

#pragma unroll
  for (int i = 0; i < 4; ++i) {
    int oc = ty * 4 + i;
    size_t base = ((size_t)(b * 128 + oc) << 14) + p0 + tx * 8;
    float r[8];
#pragma unroll
    for (int j = 0; j < 8; ++j) r[j] = relu_(acc[i][j]);
    if (MODE == 2) {
#pragma unroll
      for (int j = 0; j < 8; ++j) r[j] += in2[base + j];
    }
    *(float4*)(out + base)     = make_float4(r[0], r[1], r[2], r[3]);
    *(float4*)(out + base + 4) = make_float4(r[4], r[5], r[6], r[7]);
  }
}

// ---------------------------------------------------------------------------
// com 3x3 conv, pad=1, + bias (no relu): om[b][oc][h][w], oc in [0,216)
// ---------------------------------------------------------------------------
__global__ __launch_bounds__(256) void com_conv_kernel(
    const float* __restrict__ x, const float* __restrict__ cw,
    const float* __restrict__ cb, float* __restrict__ om)
{
  const int b    = blockIdx.z;
  const int ocg  = blockIdx.y;             // 0..26
  const int tile = blockIdx.x;             // 0..15
  const int th = (tile >> 2) * 32, tw = (tile & 3) * 32;
  const int tid = threadIdx.x;
  const int lw = (tid & 7) * 4;            // 0,4,..,28
  const int lh = tid >> 3;                 // 0..31

  __shared__ float Xs[8 * 34 * 34];        // 36,992 B

  float acc[8][4];
#pragma unroll
  for (int a = 0; a < 8; ++a)
#pragma unroll
    for (int p = 0; p < 4; ++p) acc[a][p] = 0.f;

  for (int cc = 0; cc < 128; cc += 8) {
    __syncthreads();
    for (int idx = tid; idx < 8 * 1156; idx += 256) {
      int ic  = idx / 1156;
      int rem = idx - ic * 1156;
      int yy  = rem / 34;
      int xx  = rem - yy * 34;
      int gh = th + yy - 1, gw = tw + xx - 1;
      float v = 0.f;
      if ((unsigned)gh < 128u && (unsigned)gw < 128u)
        v = x[((size_t)(b * 128 + cc + ic) << 14) + (gh << 7) + gw];
      Xs[idx] = v;
    }
    __syncthreads();
#pragma unroll 1
    for (int ic = 0; ic < 8; ++ic) {
      float xr[3][6];
#pragma unroll
      for (int ky = 0; ky < 3; ++ky)
#pragma unroll
        for (int xx = 0; xx < 6; ++xx)
          xr[ky][xx] = Xs[ic * 1156 + (lh + ky) * 34 + lw + xx];
      const float* wp = cw + ((size_t)(ocg * 8) * 128 + (cc + ic)) * 9;
#pragma unroll
      for (int a = 0; a < 8; ++a) {
        const float* w9 = wp + a * 1152;   // uniform address -> scalar loads
#pragma unroll
        for (int ky = 0; ky < 3; ++ky)
#pragma unroll
          for (int kx = 0; kx < 3; ++kx) {
            float wv = w9[ky * 3 + kx];
#pragma unroll
            for (int p = 0; p < 4; ++p)
              acc[a][p] = fmaf(wv, xr[ky][kx + p], acc[a][p]);
          }
      }
    }
  }

#pragma unroll
  for (int a = 0; a < 8; ++a) {
    int oc = ocg * 8 + a;
    float bv = cb[oc];
    float4 r = make_float4(acc[a][0] + bv, acc[a][1] + bv,
                           acc[a][2] + bv, acc[a][3] + bv);
    *(float4*)(om + ((size_t)(b * 216 + oc) << 14) + ((th + lh) << 7) + tw + lw) = r;
  }
}

// ---------------------------------------------------------------------------
// NHWC transpose of feat_s: fsT[b][p][c] <- fs[b][c][p], p < 4096, c < 128
// ---------------------------------------------------------------------------
__global__ __launch_bounds__(256) void nhwc_kernel(const float* __restrict__ fs,
                                                   float* __restrict__ fsT)
{
  const int b  = blockIdx.z;
  const int c0 = blockIdx.y * 32;
  const int p0 = blockIdx.x * 32;
  const int tid = threadIdx.x;
  __shared__ float T[32][33];
  {
    int pxl = tid & 31, cy = tid >> 5;
#pragma unroll
    for (int j = 0; j < 4; ++j) {
      int c = cy + j * 8;
      T[c][pxl] = fs[((size_t)(b * 128 + c0 + c) << 12) + p0 + pxl];
    }
  }
  __syncthreads();
  {
    int cl = tid & 31, pr = tid >> 5;
#pragma unroll
    for (int j = 0; j < 4; ++j) {
      int pp = pr + j * 8;
      fsT[(((size_t)b << 12) + p0 + pp) * 128 + c0 + cl] = T[cl][pp];
    }
  }
}

// ---------------------------------------------------------------------------
// sample_kernel: one thread per (b,g,k,px). Bilinear-sample 16 channels of
// nearest-upsampled feat_s (via fsT NHWC), apply mask, write
// val[b][(g*16+c)*9+k][px]  (== dcn_w's native reduction index order).
// ---------------------------------------------------------------------------
__global__ __launch_bounds__(256) void sample_kernel(
    const float* __restrict__ fsT, const float* __restrict__ om,
    float* __restrict__ val)
{
  const int idx = blockIdx.x * 256 + threadIdx.x;   // B*DG*KK*HW = 2,359,296
  const int px = idx & 16383;
  const int t  = idx >> 14;        // b*72 + g*9 + k
  const int k  = t % 9;
  const int g  = (t / 9) & 7;
  const int b  = t / 72;
  const int h = px >> 7, w = px & 127;

  const size_t omb = ((size_t)b * 216) << 14;
  const float offy = om[omb + ((size_t)(g * 18 + 2 * k) << 14) + px];
  const float offx = om[omb + ((size_t)(g * 18 + 2 * k + 1) << 14) + px];
  const float mraw = om[omb + ((size_t)(144 + g * 9 + k) << 14) + px];
  const float mv = 1.f / (1.f + __expf(-mraw));

  const float py  = (float)(h + k / 3 - 1) + offy;
  const float pxx = (float)(w + k % 3 - 1) + offx;
  const float y0f = floorf(py), x0f = floorf(pxx);
  const float ly = py - y0f, lx = pxx - x0f;
  const int y0 = (int)y0f, x0i = (int)x0f;
  const int y1 = y0 + 1, x1 = x0i + 1;

  const int y0c = min(max(y0, 0), 127), y1c = min(max(y1, 0), 127);
  const int x0c = min(max(x0i, 0), 127), x1c = min(max(x1, 0), 127);

  float w00 = (1.f - ly) * (1.f - lx) * mv;
  float w01 = (1.f - ly) * lx * mv;
  float w10 = ly * (1.f - lx) * mv;
  float w11 = ly * lx * mv;
  const bool vy0 = (unsigned)y0 < 128u, vy1 = (unsigned)y1 < 128u;
  const bool vx0 = (unsigned)x0i < 128u, vx1 = (unsigned)x1 < 128u;
  w00 = (vy0 && vx0) ? w00 : 0.f;
  w01 = (vy0 && vx1) ? w01 : 0.f;
  w10 = (vy1 && vx0) ? w10 : 0.f;
  w11 = (vy1 && vx1) ? w11 : 0.f;

  // nearest-upsample: feat_up[y][x] = fs[y>>1][x>>1]; fsT rows are 64x64, 128 ch
  const float* fb = fsT + ((size_t)b << 19);
  const int a00 = ((((y0c >> 1) << 6) + (x0c >> 1)) << 7) + g * 16;
  const int a01 = ((((y0c >> 1) << 6) + (x1c >> 1)) << 7) + g * 16;
  const int a10 = ((((y1c >> 1) << 6) + (x0c >> 1)) << 7) + g * 16;
  const int a11 = ((((y1c >> 1) << 6) + (x1c >> 1)) << 7) + g * 16;

  const size_t vb = ((size_t)b * 1152 + (size_t)(g * 16) * 9 + k) * 16384 + px;

#pragma unroll
  for (int cq = 0; cq < 4; ++cq) {
    float4 v00 = *(const float4*)(fb + a00 + cq * 4);
    float4 v01 = *(const float4*)(fb + a01 + cq * 4);
    float4 v10 = *(const float4*)(fb + a10 + cq * 4);
    float4 v11 = *(const float4*)(fb + a11 + cq * 4);
    float vx_ = w00 * v00.x + w01 * v01.x + w10 * v10.x + w11 * v11.x;
    float vy_ = w00 * v00.y + w01 * v01.y + w10 * v10.y + w11 * v11.y;
    float vz_ = w00 * v00.z + w01 * v01.z + w10 * v10.z + w11 * v11.z;
    float vw_ = w00 * v00.w + w01 * v01.w + w10 * v10.w + w11 * v11.w;
    const size_t o = vb + (size_t)(cq * 4) * 9 * 16384;
    val[o]               = vx_;
    val[o + 147456]      = vy_;   // 9*16384
    val[o + 2 * 147456]  = vz_;
    val[o + 3 * 147456]  = vw_;
  }
}

// ---------------------------------------------------------------------------
// dcn_gemm: al[b][o][p] = relu( sum_{r<1152} dcn_w[o][r] * val[b][r][p] + db[o] )
// Tile: 128 px x 64 oc; 256 threads; thread = 4 oc x 8 px; CIN chunks of 16.
// ---------------------------------------------------------------------------
__global__ __launch_bounds__(256) void dcn_gemm_kernel(
    const float* __restrict__ val, const float* __restrict__ dw,
    const float* __restrict__ db, float* __restrict__ al)
{
  const int b  = blockIdx.y;
  const int p0 = blockIdx.x * 128;
  const int tid = threadIdx.x;
  const int tx = tid & 15;      // px octet base tx*8
  const int ty = tid >> 4;      // oc quad base ty*4

  __shared__ float Xs[16][128];
  __shared__ float Wt[16][64];

  float acc[4][8];
#pragma unroll
  for (int i = 0; i < 4; ++i)
#pragma unroll
    for (int j = 0; j < 8; ++j) acc[i][j] = 0.f;

  const int cS  = tid >> 4;          // 0..15
  const int pxS = (tid & 15) * 8;
  const int oS  = (tid & 15) * 4;

  for (int cc = 0; cc < 1152; cc += 16) {
    __syncthreads();
    {
      const float* src = val + ((size_t)(b * 1152 + cc + cS) << 14) + p0 + pxS;
      *(float4*)&Xs[cS][pxS]     = *(const float4*)src;
      *(float4*)&Xs[cS][pxS + 4] = *(const float4*)(src + 4);
#pragma unroll
      for (int j = 0; j < 4; ++j)
        Wt[cS][oS + j] = dw[(oS + j) * 1152 + cc + cS];
    }
    __syncthreads();
#pragma unroll
    for (int c = 0; c < 16; ++c) {
      float4 wv = *(const float4*)&Wt[c][ty * 4];
      float4 x0 = *(const float4*)&Xs[c][tx * 8];
      float4 x1 = *(const float4*)&Xs[c][tx * 8 + 4];
      float xs[8] = {x0.x, x0.y, x0.z, x0.w, x1.x, x1.y, x1.z, x1.w};
      float wf[4] = {wv.x, wv.y, wv.z, wv.w};
#pragma unroll
      for (int i = 0; i < 4; ++i)
#pragma unroll
        for (int j = 0; j < 8; ++j)
          acc[i][j] = fmaf(wf[i], xs[j], acc[i][j]);
    }
  }

#pragma unroll
  for (int i = 0; i < 4; ++i) {
    int oc = ty * 4 + i;
    float bv = db[oc];
    size_t base = ((size_t)(b * 64 + oc) << 14) + p0 + tx * 8;
    float r[8];
#pragma unroll
    for (int j = 0; j < 8; ++j) r[j] = relu_(acc[i][j] + bv);
    *(float4*)(al + base)     = make_float4(r[0], r[1], r[2], r[3]);
    *(float4*)(al + base + 4) = make_float4(r[4], r[5], r[6], r[7]);
  }
}

// ---------------------------------------------------------------------------
// FALLBACK path kernels (used only if ws_size is too small for val buffer)
// ---------------------------------------------------------------------------
__global__ __launch_bounds__(256) void wt_kernel(const float* __restrict__ dw,
                                                 float* __restrict__ wT)
{
  int idx = blockIdx.x * 256 + threadIdx.x;  // 73728 total
  int o    = idx & 63;
  int rest = idx >> 6;
  int k    = rest % 9;
  int gc   = rest / 9;
  wT[idx] = dw[(o * 128 + gc) * 9 + k];
}

__global__ __launch_bounds__(256) void dcn_kernel(
    const float* __restrict__ fs, const float* __restrict__ om,
    const float* __restrict__ wT, const float* __restrict__ db,
    float* __restrict__ al)
{
  const int b   = blockIdx.y;
  const int p0  = blockIdx.x * 32;
  const int tid = threadIdx.x;
  const int px  = tid & 31;
  const int g   = tid >> 5;
  const int p = p0 + px;
  const int h = p >> 7, w = p & 127;

  float acc[64];
#pragma unroll
  for (int o = 0; o < 64; ++o) acc[o] = 0.f;

  const size_t omb = ((size_t)b * 216) << 14;
  const float* fsg = fs + (((size_t)(b * 128 + g * 16)) << 12);
  const float* wg  = wT + g * (16 * 9 * 64);

#pragma unroll 1
  for (int k = 0; k < 9; ++k) {
    float offy = om[omb + ((size_t)(g * 18 + 2 * k) << 14) + p];
    float offx = om[omb + ((size_t)(g * 18 + 2 * k + 1) << 14) + p];
    float mraw = om[omb + ((size_t)(144 + g * 9 + k) << 14) + p];
    float mv = 1.f / (1.f + __expf(-mraw));

    float py  = (float)(h + k / 3 - 1) + offy;
    float pxx = (float)(w + k % 3 - 1) + offx;
    float y0f = floorf(py), x0f = floorf(pxx);
    float ly = py - y0f, lx = pxx - x0f;
    int y0 = (int)y0f, x0i = (int)x0f;
    int y1 = y0 + 1, x1 = x0i + 1;

    int y0c = min(max(y0, 0), 127), y1c = min(max(y1, 0), 127);
    int x0c = min(max(x0i, 0), 127), x1c = min(max(x1, 0), 127);
    int ry0 = (y0c >> 1) << 6, ry1 = (y1c >> 1) << 6;
    int cx0 = x0c >> 1, cx1 = x1c >> 1;

    float w00 = (1.f - ly) * (1.f - lx) * mv;
    float w01 = (1.f - ly) * lx * mv;
    float w10 = ly * (1.f - lx) * mv;
    float w11 = ly * lx * mv;
    bool vy0 = (unsigned)y0 < 128u, vy1 = (unsigned)y1 < 128u;
    bool vx0 = (unsigned)x0i < 128u, vx1 = (unsigned)x1 < 128u;
    w00 = (vy0 && vx0) ? w00 : 0.f;
    w01 = (vy0 && vx1) ? w01 : 0.f;
    w10 = (vy1 && vx0) ? w10 : 0.f;
    w11 = (vy1 && vx1) ? w11 : 0.f;

#pragma unroll 1
    for (int c = 0; c < 16; ++c) {
      const float* fc = fsg + (c << 12);
      float v00 = fc[ry0 + cx0];
      float v01 = fc[ry0 + cx1];
      float v10 = fc[ry1 + cx0];
      float v11 = fc[ry1 + cx1];
      float v = w00 * v00 + w01 * v01 + w10 * v10 + w11 * v11;
      const float* wp = wg + (c * 9 + k) * 64;
#pragma unroll
      for (int oq = 0; oq < 16; ++oq) {
        float4 w4 = *(const float4*)(wp + oq * 4);
        acc[oq * 4 + 0] = fmaf(v, w4.x, acc[oq * 4 + 0]);
        acc[oq * 4 + 1] = fmaf(v, w4.y, acc[oq * 4 + 1]);
        acc[oq * 4 + 2] = fmaf(v, w4.z, acc[oq * 4 + 2]);
        acc[oq * 4 + 3] = fmaf(v, w4.w, acc[oq * 4 + 3]);
      }
    }
  }

  __shared__ float red[256][17];
  const int px2 = tid & 31;
  const int og  = tid >> 5;
#pragma unroll
  for (int r = 0; r < 4; ++r) {
    __syncthreads();
#pragma unroll
    for (int j = 0; j < 16; ++j) red[tid][j] = acc[r * 16 + j];
    __syncthreads();
#pragma unroll
    for (int jj = 0; jj < 2; ++jj) {
      int ol = og * 2 + jj;
      float s = 0.f;
#pragma unroll
      for (int gg = 0; gg < 8; ++gg) s += red[gg * 32 + px2][ol];
      int oc = r * 16 + ol;
      s += db[oc];
      al[((size_t)(b * 64 + oc) << 14) + p0 + px2] = fmaxf(s, 0.f);
    }
  }
}

// ---------------------------------------------------------------------------
extern "C" void kernel_launch(void* const* d_in, const int* in_sizes, int n_in,
                              void* d_out, int out_size, void* d_ws, size_t ws_size,
                              hipStream_t stream)
{
  const float* feat_l   = (const float*)d_in[0];
  const float* feat_s   = (const float*)d_in[1];
  const float* fsm_w    = (const float*)d_in[2];
  const float* offset_w = (const float*)d_in[3];
  const float* com_w    = (const float*)d_in[4];
  const float* com_b    = (const float*)d_in[5];
  const float* dcn_w    = (const float*)d_in[6];
  const float* dcn_b    = (const float*)d_in[7];
  const float* cat_w    = (const float*)d_in[8];
  float* out = (float*)d_out;
  float* ws  = (float*)d_ws;

  // New-path layout (floats):
  //   arm 4,194,304 | om 7,077,888 | al 2,097,152 | fsT 1,048,576 |
  //   X 37,748,736  (off lives at X start; val overlays it after com_conv)
  const size_t NEED = (size_t)(4194304 + 7077888 + 2097152 + 1048576 + 37748736) * 4;

  if (ws_size >= NEED) {
    float* arm = ws;
    float* om  = ws + 4194304;
    float* al  = ws + 11272192;
    float* fsT = ws + 13369344;
    float* X   = ws + 14417920;     // off, then val
    float* off = X;
    float* val = X;

    hipLaunchKernelGGL((conv1x1_kernel<0, 128>), dim3(256, 2), dim3(256), 0, stream,
                       feat_l, nullptr, fsm_w, arm);
    hipLaunchKernelGGL(nhwc_kernel, dim3(128, 4, 2), dim3(256), 0, stream,
                       feat_s, fsT);
    hipLaunchKernelGGL((conv1x1_kernel<1, 256>), dim3(256, 2), dim3(256), 0, stream,
                       arm, feat_s, offset_w, off);
    hipLaunchKernelGGL(com_conv_kernel, dim3(16, 27, 2), dim3(256), 0, stream,
                       off, com_w, com_b, om);
    hipLaunchKernelGGL(sample_kernel, dim3(9216), dim3(256), 0, stream,
                       fsT, om, val);
    hipLaunchKernelGGL(dcn_gemm_kernel, dim3(128, 2), dim3(256), 0, stream,
                       val, dcn_w, dcn_b, al);
    hipLaunchKernelGGL((conv1x1_kernel<2, 64>), dim3(256, 2), dim3(256), 0, stream,
                       al, arm, cat_w, out);
  } else {
    // Fallback: round-1 layout/path
    float* arm = ws;                    // 4,194,304
    float* off = ws + 4194304;          // 4,194,304
    float* om  = ws + 8388608;          // 7,077,888
    float* al  = ws + 15466496;         // 2,097,152
    float* wT  = ws + 17563648;         // 73,728

    hipLaunchKernelGGL(wt_kernel, dim3(288), dim3(256), 0, stream, dcn_w, wT);
    hipLaunchKernelGGL((conv1x1_kernel<0, 128>), dim3(256, 2), dim3(256), 0, stream,
                       feat_l, nullptr, fsm_w, arm);
    hipLaunchKernelGGL((conv1x1_kernel<1, 256>), dim3(256, 2), dim3(256), 0, stream,
                       arm, feat_s, offset_w, off);
    hipLaunchKernelGGL(com_conv_kernel, dim3(16, 27, 2), dim3(256), 0, stream,
                       off, com_w, com_b, om);
    hipLaunchKernelGGL(dcn_kernel, dim3(512, 2), dim3(256), 0, stream,
                       feat_s, om, wT, dcn_b, al);
    hipLaunchKernelGGL((conv1x1_kernel<2, 64>), dim3(256, 2), dim3(256), 0, stream,
                       al, arm, cat_w, out);
  }
}

// Round 3
// 456.976 us; speedup vs baseline: 1.8889x; 1.5097x over previous
//
#include <hip/hip_runtime.h>
#include <cstdint>
#include <cstddef>

// Problem constants
// B=2, C=128, H=W=128, Hs=Ws=64, DG=8, KK=9, CG=16, COUT_DCN=64, HW=16384

typedef _Float16 f16x8 __attribute__((ext_vector_type(8)));
typedef float    f32x4 __attribute__((ext_vector_type(4)));

__device__ __forceinline__ float relu_(float x) { return fmaxf(x, 0.f); }

// ---------------------------------------------------------------------------
// conv1x1: out[b][oc][p] = relu(sum_c W[oc][c] * X[c][p]) (+ residual for MODE 2)
// ---------------------------------------------------------------------------
template<int MODE, int CIN>
__global__ __launch_bounds__(256) void conv1x1_kernel(
    const float* __restrict__ in1, const float* __restrict__ in2,
    const float* __restrict__ Wm, float* __restrict__ out)
{
  constexpr int IN1C = (MODE == 2) ? 64 : 128;
  const int b  = blockIdx.y;
  const int p0 = blockIdx.x * 64;
  const int tid = threadIdx.x;
  const int tx = tid & 7;      // pixel octet: px = tx*8 .. +7
  const int ty = tid >> 3;     // oc quad:    oc = ty*4 .. +3

  __shared__ float Xs[16][64];
  __shared__ float Wt[16][128];

  float acc[4][8];
#pragma unroll
  for (int i = 0; i < 4; ++i)
#pragma unroll
    for (int j = 0; j < 8; ++j) acc[i][j] = 0.f;

  const int cS  = tid >> 4;
  const int pxS = (tid & 15) * 4;
  const int ocS = (tid & 15) * 8;

  for (int cc = 0; cc < CIN; cc += 16) {
    __syncthreads();
    {
      int gc = cc + cS;
      float4 v;
      if (MODE == 1 && gc >= 128) {
        int sc = gc - 128;
        float t[4];
#pragma unroll
        for (int j = 0; j < 4; ++j) {
          int pp = p0 + pxS + j;
          int hh = pp >> 7, ww = pp & 127;
          t[j] = 2.f * in2[((size_t)(b * 128 + sc) << 12) + ((hh >> 1) << 6) + (ww >> 1)];
        }
        v = make_float4(t[0], t[1], t[2], t[3]);
      } else {
        v = *(const float4*)(in1 + ((size_t)(b * IN1C + gc) << 14) + p0 + pxS);
      }
      *(float4*)&Xs[cS][pxS] = v;
#pragma unroll
      for (int j = 0; j < 8; ++j)
        Wt[cS][ocS + j] = Wm[(ocS + j) * CIN + cc + cS];
    }
    __syncthreads();
#pragma unroll
    for (int c = 0; c < 16; ++c) {
      float4 wv = *(const float4*)&Wt[c][ty * 4];
      float4 x0 = *(const float4*)&Xs[c][tx * 8];
      float4 x1 = *(const float4*)&Xs[c][tx * 8 + 4];
      float xs[8] = {x0.x, x0.y, x0.z, x0.w, x1.x, x1.y, x1.z, x1.w};
      float wf[4] = {wv.x, wv.y, wv.z, wv.w};
#pragma unroll
      for (int i = 0; i < 4; ++i)
#pragma unroll
        for (int j = 0; j < 8; ++j)
          acc[i][j] = fmaf(wf[i], xs[j], acc[i][j]);
    }
  }

#pragma unroll
  for (int i = 0; i < 4; ++i) {
    int oc = ty * 4 + i;
    size_t base = ((size_t)(b * 128 + oc) << 14) + p0 + tx * 8;
    float r[8];
#pragma unroll
    for (int j = 0; j < 8; ++j) r[j] = relu_(acc[i][j]);
    if (MODE == 2) {
#pragma unroll
      for (int j = 0; j < 8; ++j) r[j] += in2[base + j];
    }
    *(float4*)(out + base)     = make_float4(r[0], r[1], r[2], r[3]);
    *(float4*)(out + base + 4) = make_float4(r[4], r[5], r[6], r[7]);
  }
}

// ---------------------------------------------------------------------------
// Wf prep: pack com_w into A-fragment order for mfma_f32_16x16x32_f16.
// Wf[((q*14 + m)*64 + lane)*8 + j] = com_w[oc=m*16+(lane&15)][ic=(q&3)*32+(lane>>4)*8+j][kk=q>>2]
// oc >= 216 -> 0 (pad to 224). 36 chunks x 14 m-tiles x 64 lanes x 8.
// ---------------------------------------------------------------------------
__global__ __launch_bounds__(256) void wf_kernel(
    const float* __restrict__ cw, _Float16* __restrict__ Wf)
{
  int idx = blockIdx.x * 256 + threadIdx.x;  // 36*14*64 = 32256 = 126*256
  int lane = idx & 63;
  int t = idx >> 6;          // q*14 + m
  int m = t % 14, q = t / 14;
  int kk = q >> 2;
  int ic0 = (q & 3) * 32 + (lane >> 4) * 8;
  int oc = m * 16 + (lane & 15);
  f16x8 v;
#pragma unroll
  for (int j = 0; j < 8; ++j) {
    float x = (oc < 216) ? cw[((size_t)oc * 128 + ic0 + j) * 9 + kk] : 0.f;
    v[j] = (_Float16)x;
  }
  ((f16x8*)Wf)[idx] = v;
}

// ---------------------------------------------------------------------------
// xcol: shifted im2col in f16, fragment-friendly layout.
// Xcol[((b*36 + q)*16384 + p)*32 + r] = off[b][(q&3)*32 + r][h + ky(q) - 1][w + kx(q) - 1]
// (0 if out of bounds), where (ky,kx) from kk = q>>2, k order = kk-major.
// ---------------------------------------------------------------------------
__global__ __launch_bounds__(256) void xcol_kernel(
    const float* __restrict__ off, _Float16* __restrict__ Xcol)
{
  const size_t idx = (size_t)blockIdx.x * 256 + threadIdx.x; // 2*36*16384
  const int p  = (int)(idx & 16383);
  const int t  = (int)(idx >> 14);    // b*36 + q
  const int q  = t % 36;
  const int b  = t / 36;
  const int kk = q >> 2, ic0 = (q & 3) * 32;
  const int ky = kk / 3 - 1, kx = kk % 3 - 1;
  const int h = p >> 7, w = p & 127;
  const int hh = h + ky, ww = w + kx;
  const bool valid = ((unsigned)hh < 128u) && ((unsigned)ww < 128u);
  const int ps = valid ? ((hh << 7) + ww) : 0;
  const float* src = off + ((size_t)(b * 128 + ic0) << 14) + ps;
  f16x8 o[4];
#pragma unroll
  for (int j = 0; j < 4; ++j)
#pragma unroll
    for (int e = 0; e < 8; ++e)
      o[j][e] = valid ? (_Float16)src[(size_t)(j * 8 + e) << 14] : (_Float16)0.f;
  f16x8* dst = (f16x8*)Xcol + idx * 4;
  dst[0] = o[0]; dst[1] = o[1]; dst[2] = o[2]; dst[3] = o[3];
}

// ---------------------------------------------------------------------------
// com GEMM via MFMA f16: om[b][oc][p] = sum_K Wf x Xcol + bias, oc<216.
// Block = 4 waves x 16 px = 64 px. Wave: 16 px x 224 oc (14 m-tiles).
// No LDS, no barriers; B-load 1 dwordx4/chunk, A-loads 14 dwordx4/chunk (L2-hot).
// D layout (m89-verified): col(px) = lane&15, row(oc_local) = (lane>>4)*4 + reg.
// ---------------------------------------------------------------------------
__global__ __launch_bounds__(256) void com_gemm_kernel(
    const _Float16* __restrict__ Xcol, const _Float16* __restrict__ Wf,
    const float* __restrict__ cb, float* __restrict__ om)
{
  const int b    = blockIdx.y;
  const int tid  = threadIdx.x;
  const int wv   = tid >> 6;
  const int lane = tid & 63;
  const int px0  = blockIdx.x * 64 + wv * 16;

  f32x4 acc[14];
#pragma unroll
  for (int m = 0; m < 14; ++m) acc[m] = (f32x4){0.f, 0.f, 0.f, 0.f};

  const f16x8* Bp = (const f16x8*)Xcol
      + ((size_t)(b * 36) * 16384 + px0 + (lane & 15)) * 4 + (lane >> 4);
  const f16x8* Ap = (const f16x8*)Wf + lane;

#pragma unroll 1
  for (int q = 0; q < 36; ++q) {
    f16x8 bf = Bp[(size_t)q * 65536];
    const f16x8* ap = Ap + q * (14 * 64);
#pragma unroll
    for (int m = 0; m < 14; ++m) {
      f16x8 af = ap[m * 64];
      acc[m] = __builtin_amdgcn_mfma_f32_16x16x32_f16(af, bf, acc[m], 0, 0, 0);
    }
  }

  const int pxl = px0 + (lane & 15);
  const int r0  = (lane >> 4) * 4;
#pragma unroll
  for (int m = 0; m < 14; ++m) {
    int ocb = m * 16 + r0;
#pragma unroll
    for (int r = 0; r < 4; ++r) {
      int oc = ocb + r;
      if (oc < 216)
        om[((size_t)(b * 216 + oc) << 14) + pxl] = acc[m][r] + cb[oc];
    }
  }
}

// ---------------------------------------------------------------------------
// NHWC transpose of feat_s: fsT[b][p][c] <- fs[b][c][p], p < 4096, c < 128
// ---------------------------------------------------------------------------
__global__ __launch_bounds__(256) void nhwc_kernel(const float* __restrict__ fs,
                                                   float* __restrict__ fsT)
{
  const int b  = blockIdx.z;
  const int c0 = blockIdx.y * 32;
  const int p0 = blockIdx.x * 32;
  const int tid = threadIdx.x;
  __shared__ float T[32][33];
  {
    int pxl = tid & 31, cy = tid >> 5;
#pragma unroll
    for (int j = 0; j < 4; ++j) {
      int c = cy + j * 8;
      T[c][pxl] = fs[((size_t)(b * 128 + c0 + c) << 12) + p0 + pxl];
    }
  }
  __syncthreads();
  {
    int cl = tid & 31, pr = tid >> 5;
#pragma unroll
    for (int j = 0; j < 4; ++j) {
      int pp = pr + j * 8;
      fsT[(((size_t)b << 12) + p0 + pp) * 128 + c0 + cl] = T[cl][pp];
    }
  }
}

// ---------------------------------------------------------------------------
// sample_kernel: one thread per (b,g,k,px). Bilinear-sample 16 channels of
// nearest-upsampled feat_s (via fsT NHWC), apply mask, write
// val[b][(g*16+c)*9+k][px]  (== dcn_w's native reduction index order).
// ---------------------------------------------------------------------------
__global__ __launch_bounds__(256) void sample_kernel(
    const float* __restrict__ fsT, const float* __restrict__ om,
    float* __restrict__ val)
{
  const int idx = blockIdx.x * 256 + threadIdx.x;   // B*DG*KK*HW = 2,359,296
  const int px = idx & 16383;
  const int t  = idx >> 14;        // b*72 + g*9 + k
  const int k  = t % 9;
  const int g  = (t / 9) & 7;
  const int b  = t / 72;
  const int h = px >> 7, w = px & 127;

  const size_t omb = ((size_t)b * 216) << 14;
  const float offy = om[omb + ((size_t)(g * 18 + 2 * k) << 14) + px];
  const float offx = om[omb + ((size_t)(g * 18 + 2 * k + 1) << 14) + px];
  const float mraw = om[omb + ((size_t)(144 + g * 9 + k) << 14) + px];
  const float mv = 1.f / (1.f + __expf(-mraw));

  const float py  = (float)(h + k / 3 - 1) + offy;
  const float pxx = (float)(w + k % 3 - 1) + offx;
  const float y0f = floorf(py), x0f = floorf(pxx);
  const float ly = py - y0f, lx = pxx - x0f;
  const int y0 = (int)y0f, x0i = (int)x0f;
  const int y1 = y0 + 1, x1 = x0i + 1;

  const int y0c = min(max(y0, 0), 127), y1c = min(max(y1, 0), 127);
  const int x0c = min(max(x0i, 0), 127), x1c = min(max(x1, 0), 127);

  float w00 = (1.f - ly) * (1.f - lx) * mv;
  float w01 = (1.f - ly) * lx * mv;
  float w10 = ly * (1.f - lx) * mv;
  float w11 = ly * lx * mv;
  const bool vy0 = (unsigned)y0 < 128u, vy1 = (unsigned)y1 < 128u;
  const bool vx0 = (unsigned)x0i < 128u, vx1 = (unsigned)x1 < 128u;
  w00 = (vy0 && vx0) ? w00 : 0.f;
  w01 = (vy0 && vx1) ? w01 : 0.f;
  w10 = (vy1 && vx0) ? w10 : 0.f;
  w11 = (vy1 && vx1) ? w11 : 0.f;

  const float* fb = fsT + ((size_t)b << 19);
  const int a00 = ((((y0c >> 1) << 6) + (x0c >> 1)) << 7) + g * 16;
  const int a01 = ((((y0c >> 1) << 6) + (x1c >> 1)) << 7) + g * 16;
  const int a10 = ((((y1c >> 1) << 6) + (x0c >> 1)) << 7) + g * 16;
  const int a11 = ((((y1c >> 1) << 6) + (x1c >> 1)) << 7) + g * 16;

  const size_t vb = ((size_t)b * 1152 + (size_t)(g * 16) * 9 + k) * 16384 + px;

#pragma unroll
  for (int cq = 0; cq < 4; ++cq) {
    float4 v00 = *(const float4*)(fb + a00 + cq * 4);
    float4 v01 = *(const float4*)(fb + a01 + cq * 4);
    float4 v10 = *(const float4*)(fb + a10 + cq * 4);
    float4 v11 = *(const float4*)(fb + a11 + cq * 4);
    float vx_ = w00 * v00.x + w01 * v01.x + w10 * v10.x + w11 * v11.x;
    float vy_ = w00 * v00.y + w01 * v01.y + w10 * v10.y + w11 * v11.y;
    float vz_ = w00 * v00.z + w01 * v01.z + w10 * v10.z + w11 * v11.z;
    float vw_ = w00 * v00.w + w01 * v01.w + w10 * v10.w + w11 * v11.w;
    const size_t o = vb + (size_t)(cq * 4) * 9 * 16384;
    val[o]               = vx_;
    val[o + 147456]      = vy_;
    val[o + 2 * 147456]  = vz_;
    val[o + 3 * 147456]  = vw_;
  }
}

// ---------------------------------------------------------------------------
// dcn_gemm: al[b][o][p] = relu( sum_{r<1152} dcn_w[o][r] * val[b][r][p] + db[o] )
// ---------------------------------------------------------------------------
__global__ __launch_bounds__(256) void dcn_gemm_kernel(
    const float* __restrict__ val, const float* __restrict__ dw,
    const float* __restrict__ db, float* __restrict__ al)
{
  const int b  = blockIdx.y;
  const int p0 = blockIdx.x * 128;
  const int tid = threadIdx.x;
  const int tx = tid & 15;
  const int ty = tid >> 4;

  __shared__ float Xs[16][128];
  __shared__ float Wt[16][64];

  float acc[4][8];
#pragma unroll
  for (int i = 0; i < 4; ++i)
#pragma unroll
    for (int j = 0; j < 8; ++j) acc[i][j] = 0.f;

  const int cS  = tid >> 4;
  const int pxS = (tid & 15) * 8;
  const int oS  = (tid & 15) * 4;

  for (int cc = 0; cc < 1152; cc += 16) {
    __syncthreads();
    {
      const float* src = val + ((size_t)(b * 1152 + cc + cS) << 14) + p0 + pxS;
      *(float4*)&Xs[cS][pxS]     = *(const float4*)src;
      *(float4*)&Xs[cS][pxS + 4] = *(const float4*)(src + 4);
#pragma unroll
      for (int j = 0; j < 4; ++j)
        Wt[cS][oS + j] = dw[(oS + j) * 1152 + cc + cS];
    }
    __syncthreads();
#pragma unroll
    for (int c = 0; c < 16; ++c) {
      float4 wv = *(const float4*)&Wt[c][ty * 4];
      float4 x0 = *(const float4*)&Xs[c][tx * 8];
      float4 x1 = *(const float4*)&Xs[c][tx * 8 + 4];
      float xs[8] = {x0.x, x0.y, x0.z, x0.w, x1.x, x1.y, x1.z, x1.w};
      float wf[4] = {wv.x, wv.y, wv.z, wv.w};
#pragma unroll
      for (int i = 0; i < 4; ++i)
#pragma unroll
        for (int j = 0; j < 8; ++j)
          acc[i][j] = fmaf(wf[i], xs[j], acc[i][j]);
    }
  }

#pragma unroll
  for (int i = 0; i < 4; ++i) {
    int oc = ty * 4 + i;
    float bv = db[oc];
    size_t base = ((size_t)(b * 64 + oc) << 14) + p0 + tx * 8;
    float r[8];
#pragma unroll
    for (int j = 0; j < 8; ++j) r[j] = relu_(acc[i][j] + bv);
    *(float4*)(al + base)     = make_float4(r[0], r[1], r[2], r[3]);
    *(float4*)(al + base + 4) = make_float4(r[4], r[5], r[6], r[7]);
  }
}

// ---------------------------------------------------------------------------
// FALLBACK path kernels (small ws): round-1 versions
// ---------------------------------------------------------------------------
__global__ __launch_bounds__(256) void com_conv_kernel(
    const float* __restrict__ x, const float* __restrict__ cw,
    const float* __restrict__ cb, float* __restrict__ om)
{
  const int b    = blockIdx.z;
  const int ocg  = blockIdx.y;
  const int tile = blockIdx.x;
  const int th = (tile >> 2) * 32, tw = (tile & 3) * 32;
  const int tid = threadIdx.x;
  const int lw = (tid & 7) * 4;
  const int lh = tid >> 3;

  __shared__ float Xs[8 * 34 * 34];

  float acc[8][4];
#pragma unroll
  for (int a = 0; a < 8; ++a)
#pragma unroll
    for (int p = 0; p < 4; ++p) acc[a][p] = 0.f;

  for (int cc = 0; cc < 128; cc += 8) {
    __syncthreads();
    for (int idx = tid; idx < 8 * 1156; idx += 256) {
      int ic  = idx / 1156;
      int rem = idx - ic * 1156;
      int yy  = rem / 34;
      int xx  = rem - yy * 34;
      int gh = th + yy - 1, gw = tw + xx - 1;
      float v = 0.f;
      if ((unsigned)gh < 128u && (unsigned)gw < 128u)
        v = x[((size_t)(b * 128 + cc + ic) << 14) + (gh << 7) + gw];
      Xs[idx] = v;
    }
    __syncthreads();
#pragma unroll 1
    for (int ic = 0; ic < 8; ++ic) {
      float xr[3][6];
#pragma unroll
      for (int ky = 0; ky < 3; ++ky)
#pragma unroll
        for (int xx = 0; xx < 6; ++xx)
          xr[ky][xx] = Xs[ic * 1156 + (lh + ky) * 34 + lw + xx];
      const float* wp = cw + ((size_t)(ocg * 8) * 128 + (cc + ic)) * 9;
#pragma unroll
      for (int a = 0; a < 8; ++a) {
        const float* w9 = wp + a * 1152;
#pragma unroll
        for (int ky = 0; ky < 3; ++ky)
#pragma unroll
          for (int kx = 0; kx < 3; ++kx) {
            float wv = w9[ky * 3 + kx];
#pragma unroll
            for (int p = 0; p < 4; ++p)
              acc[a][p] = fmaf(wv, xr[ky][kx + p], acc[a][p]);
          }
      }
    }
  }

#pragma unroll
  for (int a = 0; a < 8; ++a) {
    int oc = ocg * 8 + a;
    float bv = cb[oc];
    float4 r = make_float4(acc[a][0] + bv, acc[a][1] + bv,
                           acc[a][2] + bv, acc[a][3] + bv);
    *(float4*)(om + ((size_t)(b * 216 + oc) << 14) + ((th + lh) << 7) + tw + lw) = r;
  }
}

__global__ __launch_bounds__(256) void wt_kernel(const float* __restrict__ dw,
                                                 float* __restrict__ wT)
{
  int idx = blockIdx.x * 256 + threadIdx.x;
  int o    = idx & 63;
  int rest = idx >> 6;
  int k    = rest % 9;
  int gc   = rest / 9;
  wT[idx] = dw[(o * 128 + gc) * 9 + k];
}

__global__ __launch_bounds__(256) void dcn_kernel(
    const float* __restrict__ fs, const float* __restrict__ om,
    const float* __restrict__ wT, const float* __restrict__ db,
    float* __restrict__ al)
{
  const int b   = blockIdx.y;
  const int p0  = blockIdx.x * 32;
  const int tid = threadIdx.x;
  const int px  = tid & 31;
  const int g   = tid >> 5;
  const int p = p0 + px;
  const int h = p >> 7, w = p & 127;

  float acc[64];
#pragma unroll
  for (int o = 0; o < 64; ++o) acc[o] = 0.f;

  const size_t omb = ((size_t)b * 216) << 14;
  const float* fsg = fs + (((size_t)(b * 128 + g * 16)) << 12);
  const float* wg  = wT + g * (16 * 9 * 64);

#pragma unroll 1
  for (int k = 0; k < 9; ++k) {
    float offy = om[omb + ((size_t)(g * 18 + 2 * k) << 14) + p];
    float offx = om[omb + ((size_t)(g * 18 + 2 * k + 1) << 14) + p];
    float mraw = om[omb + ((size_t)(144 + g * 9 + k) << 14) + p];
    float mv = 1.f / (1.f + __expf(-mraw));

    float py  = (float)(h + k / 3 - 1) + offy;
    float pxx = (float)(w + k % 3 - 1) + offx;
    float y0f = floorf(py), x0f = floorf(pxx);
    float ly = py - y0f, lx = pxx - x0f;
    int y0 = (int)y0f, x0i = (int)x0f;
    int y1 = y0 + 1, x1 = x0i + 1;

    int y0c = min(max(y0, 0), 127), y1c = min(max(y1, 0), 127);
    int x0c = min(max(x0i, 0), 127), x1c = min(max(x1, 0), 127);
    int ry0 = (y0c >> 1) << 6, ry1 = (y1c >> 1) << 6;
    int cx0 = x0c >> 1, cx1 = x1c >> 1;

    float w00 = (1.f - ly) * (1.f - lx) * mv;
    float w01 = (1.f - ly) * lx * mv;
    float w10 = ly * (1.f - lx) * mv;
    float w11 = ly * lx * mv;
    bool vy0 = (unsigned)y0 < 128u, vy1 = (unsigned)y1 < 128u;
    bool vx0 = (unsigned)x0i < 128u, vx1 = (unsigned)x1 < 128u;
    w00 = (vy0 && vx0) ? w00 : 0.f;
    w01 = (vy0 && vx1) ? w01 : 0.f;
    w10 = (vy1 && vx0) ? w10 : 0.f;
    w11 = (vy1 && vx1) ? w11 : 0.f;

#pragma unroll 1
    for (int c = 0; c < 16; ++c) {
      const float* fc = fsg + (c << 12);
      float v00 = fc[ry0 + cx0];
      float v01 = fc[ry0 + cx1];
      float v10 = fc[ry1 + cx0];
      float v11 = fc[ry1 + cx1];
      float v = w00 * v00 + w01 * v01 + w10 * v10 + w11 * v11;
      const float* wp = wg + (c * 9 + k) * 64;
#pragma unroll
      for (int oq = 0; oq < 16; ++oq) {
        float4 w4 = *(const float4*)(wp + oq * 4);
        acc[oq * 4 + 0] = fmaf(v, w4.x, acc[oq * 4 + 0]);
        acc[oq * 4 + 1] = fmaf(v, w4.y, acc[oq * 4 + 1]);
        acc[oq * 4 + 2] = fmaf(v, w4.z, acc[oq * 4 + 2]);
        acc[oq * 4 + 3] = fmaf(v, w4.w, acc[oq * 4 + 3]);
      }
    }
  }

  __shared__ float red[256][17];
  const int px2 = tid & 31;
  const int og  = tid >> 5;
#pragma unroll
  for (int r = 0; r < 4; ++r) {
    __syncthreads();
#pragma unroll
    for (int j = 0; j < 16; ++j) red[tid][j] = acc[r * 16 + j];
    __syncthreads();
#pragma unroll
    for (int jj = 0; jj < 2; ++jj) {
      int ol = og * 2 + jj;
      float s = 0.f;
#pragma unroll
      for (int gg = 0; gg < 8; ++gg) s += red[gg * 32 + px2][ol];
      int oc = r * 16 + ol;
      s += db[oc];
      al[((size_t)(b * 64 + oc) << 14) + p0 + px2] = fmaxf(s, 0.f);
    }
  }
}

// ---------------------------------------------------------------------------
extern "C" void kernel_launch(void* const* d_in, const int* in_sizes, int n_in,
                              void* d_out, int out_size, void* d_ws, size_t ws_size,
                              hipStream_t stream)
{
  const float* feat_l   = (const float*)d_in[0];
  const float* feat_s   = (const float*)d_in[1];
  const float* fsm_w    = (const float*)d_in[2];
  const float* offset_w = (const float*)d_in[3];
  const float* com_w    = (const float*)d_in[4];
  const float* com_b    = (const float*)d_in[5];
  const float* dcn_w    = (const float*)d_in[6];
  const float* dcn_b    = (const float*)d_in[7];
  const float* cat_w    = (const float*)d_in[8];
  float* out = (float*)d_out;
  float* ws  = (float*)d_ws;

  // Layout (floats): arm 4,194,304 | om 7,077,888 | al 2,097,152 (Wf borrows
  // its start before al is written) | fsT 1,048,576 | X 37,748,736:
  //   off at X[0..4,194,304); Xcol f16 at X+4,194,304 (9,437,184 floats);
  //   val f32 overlays all of X after Xcol is consumed.
  const size_t NEED = (size_t)(4194304 + 7077888 + 2097152 + 1048576 + 37748736) * 4;

  if (ws_size >= NEED) {
    float* arm = ws;
    float* om  = ws + 4194304;
    float* al  = ws + 11272192;
    float* fsT = ws + 13369344;
    float* X   = ws + 14417920;
    float* off = X;
    _Float16* Xcol = (_Float16*)(X + 4194304);
    float* val = X;
    _Float16* Wf = (_Float16*)al;     // 258,048 f16 = 516 KB, dead before al write

    hipLaunchKernelGGL(wf_kernel, dim3(126), dim3(256), 0, stream, com_w, Wf);
    hipLaunchKernelGGL((conv1x1_kernel<0, 128>), dim3(256, 2), dim3(256), 0, stream,
                       feat_l, nullptr, fsm_w, arm);
    hipLaunchKernelGGL(nhwc_kernel, dim3(128, 4, 2), dim3(256), 0, stream,
                       feat_s, fsT);
    hipLaunchKernelGGL((conv1x1_kernel<1, 256>), dim3(256, 2), dim3(256), 0, stream,
                       arm, feat_s, offset_w, off);
    hipLaunchKernelGGL(xcol_kernel, dim3(4608), dim3(256), 0, stream, off, Xcol);
    hipLaunchKernelGGL(com_gemm_kernel, dim3(256, 2), dim3(256), 0, stream,
                       Xcol, Wf, com_b, om);
    hipLaunchKernelGGL(sample_kernel, dim3(9216), dim3(256), 0, stream,
                       fsT, om, val);
    hipLaunchKernelGGL(dcn_gemm_kernel, dim3(128, 2), dim3(256), 0, stream,
                       val, dcn_w, dcn_b, al);
    hipLaunchKernelGGL((conv1x1_kernel<2, 64>), dim3(256, 2), dim3(256), 0, stream,
                       al, arm, cat_w, out);
  } else {
    float* arm = ws;
    float* off = ws + 4194304;
    float* om  = ws + 8388608;
    float* al  = ws + 15466496;
    float* wT  = ws + 17563648;

    hipLaunchKernelGGL(wt_kernel, dim3(288), dim3(256), 0, stream, dcn_w, wT);
    hipLaunchKernelGGL((conv1x1_kernel<0, 128>), dim3(256, 2), dim3(256), 0, stream,
                       feat_l, nullptr, fsm_w, arm);
    hipLaunchKernelGGL((conv1x1_kernel<1, 256>), dim3(256, 2), dim3(256), 0, stream,
                       arm, feat_s, offset_w, off);
    hipLaunchKernelGGL(com_conv_kernel, dim3(16, 27, 2), dim3(256), 0, stream,
                       off, com_w, com_b, om);
    hipLaunchKernelGGL(dcn_kernel, dim3(512, 2), dim3(256), 0, stream,
                       feat_s, om, wT, dcn_b, al);
    hipLaunchKernelGGL((conv1x1_kernel<2, 64>), dim3(256, 2), dim3(256), 0, stream,
                       al, arm, cat_w, out);
  }
}

// Round 4
// 343.252 us; speedup vs baseline: 2.5147x; 1.3313x over previous
//
#include <hip/hip_runtime.h>
#include <cstdint>
#include <cstddef>

// Problem constants
// B=2, C=128, H=W=128, Hs=Ws=64, DG=8, KK=9, CG=16, COUT_DCN=64, HW=16384

typedef _Float16 f16x8 __attribute__((ext_vector_type(8)));
typedef float    f32x4 __attribute__((ext_vector_type(4)));

__device__ __forceinline__ float relu_(float x) { return fmaxf(x, 0.f); }

// ---------------------------------------------------------------------------
// conv1x1: out[b][oc][p] = relu(sum_c W[oc][c] * X[c][p]) (+ residual for MODE 2)
// ---------------------------------------------------------------------------
template<int MODE, int CIN>
__global__ __launch_bounds__(256) void conv1x1_kernel(
    const float* __restrict__ in1, const float* __restrict__ in2,
    const float* __restrict__ Wm, float* __restrict__ out)
{
  constexpr int IN1C = (MODE == 2) ? 64 : 128;
  const int b  = blockIdx.y;
  const int p0 = blockIdx.x * 64;
  const int tid = threadIdx.x;
  const int tx = tid & 7;      // pixel octet: px = tx*8 .. +7
  const int ty = tid >> 3;     // oc quad:    oc = ty*4 .. +3

  __shared__ float Xs[16][64];
  __shared__ float Wt[16][128];

  float acc[4][8];
#pragma unroll
  for (int i = 0; i < 4; ++i)
#pragma unroll
    for (int j = 0; j < 8; ++j) acc[i][j] = 0.f;

  const int cS  = tid >> 4;
  const int pxS = (tid & 15) * 4;
  const int ocS = (tid & 15) * 8;

  for (int cc = 0; cc < CIN; cc += 16) {
    __syncthreads();
    {
      int gc = cc + cS;
      float4 v;
      if (MODE == 1 && gc >= 128) {
        int sc = gc - 128;
        float t[4];
#pragma unroll
        for (int j = 0; j < 4; ++j) {
          int pp = p0 + pxS + j;
          int hh = pp >> 7, ww = pp & 127;
          t[j] = 2.f * in2[((size_t)(b * 128 + sc) << 12) + ((hh >> 1) << 6) + (ww >> 1)];
        }
        v = make_float4(t[0], t[1], t[2], t[3]);
      } else {
        v = *(const float4*)(in1 + ((size_t)(b * IN1C + gc) << 14) + p0 + pxS);
      }
      *(float4*)&Xs[cS][pxS] = v;
#pragma unroll
      for (int j = 0; j < 8; ++j)
        Wt[cS][ocS + j] = Wm[(ocS + j) * CIN + cc + cS];
    }
    __syncthreads();
#pragma unroll
    for (int c = 0; c < 16; ++c) {
      float4 wv = *(const float4*)&Wt[c][ty * 4];
      float4 x0 = *(const float4*)&Xs[c][tx * 8];
      float4 x1 = *(const float4*)&Xs[c][tx * 8 + 4];
      float xs[8] = {x0.x, x0.y, x0.z, x0.w, x1.x, x1.y, x1.z, x1.w};
      float wf[4] = {wv.x, wv.y, wv.z, wv.w};
#pragma unroll
      for (int i = 0; i < 4; ++i)
#pragma unroll
        for (int j = 0; j < 8; ++j)
          acc[i][j] = fmaf(wf[i], xs[j], acc[i][j]);
    }
  }

#pragma unroll
  for (int i = 0; i < 4; ++i) {
    int oc = ty * 4 + i;
    size_t base = ((size_t)(b * 128 + oc) << 14) + p0 + tx * 8;
    float r[8];
#pragma unroll
    for (int j = 0; j < 8; ++j) r[j] = relu_(acc[i][j]);
    if (MODE == 2) {
#pragma unroll
      for (int j = 0; j < 8; ++j) r[j] += in2[base + j];
    }
    *(float4*)(out + base)     = make_float4(r[0], r[1], r[2], r[3]);
    *(float4*)(out + base + 4) = make_float4(r[4], r[5], r[6], r[7]);
  }
}

// ---------------------------------------------------------------------------
// Wf prep: pack com_w into A-fragment order for mfma_f32_16x16x32_f16.
// Wf[((q*14 + m)*64 + lane)*8 + j] = com_w[oc=m*16+(lane&15)][ic=(q&3)*32+(lane>>4)*8+j][kk=q>>2]
// ---------------------------------------------------------------------------
__global__ __launch_bounds__(256) void wf_kernel(
    const float* __restrict__ cw, _Float16* __restrict__ Wf)
{
  int idx = blockIdx.x * 256 + threadIdx.x;  // 36*14*64 = 32256 = 126*256
  int lane = idx & 63;
  int t = idx >> 6;          // q*14 + m
  int m = t % 14, q = t / 14;
  int kk = q >> 2;
  int ic0 = (q & 3) * 32 + (lane >> 4) * 8;
  int oc = m * 16 + (lane & 15);
  f16x8 v;
#pragma unroll
  for (int j = 0; j < 8; ++j) {
    float x = (oc < 216) ? cw[((size_t)oc * 128 + ic0 + j) * 9 + kk] : 0.f;
    v[j] = (_Float16)x;
  }
  ((f16x8*)Wf)[idx] = v;
}

// ---------------------------------------------------------------------------
// Wf2 prep: pack dcn_w into A-fragments, K order r' = (g*9+k)*16 + c.
// Wf2[((q*4 + m)*64 + lane)*8 + j]: oc = m*16+(lane&15), r' = q*32+(lane>>4)*8+j,
// c = r'&15, t = r'>>4, g = t/9, k = t%9 -> dw[(oc*128 + g*16+c)*9 + k].
// ---------------------------------------------------------------------------
__global__ __launch_bounds__(256) void wf2_kernel(
    const float* __restrict__ dw, _Float16* __restrict__ Wf2)
{
  int idx = blockIdx.x * 256 + threadIdx.x;  // 36*4*64 = 9216 = 36*256
  int lane = idx & 63;
  int t = idx >> 6;          // q*4 + m
  int m = t & 3, q = t >> 2;
  int oc = m * 16 + (lane & 15);
  f16x8 v;
#pragma unroll
  for (int j = 0; j < 8; ++j) {
    int rp = q * 32 + (lane >> 4) * 8 + j;
    int c = rp & 15, tt = rp >> 4;
    int g = tt / 9, k = tt % 9;
    v[j] = (_Float16)dw[((size_t)oc * 128 + g * 16 + c) * 9 + k];
  }
  ((f16x8*)Wf2)[idx] = v;
}

// ---------------------------------------------------------------------------
// xcol: shifted im2col in f16, fragment-friendly layout.
// ---------------------------------------------------------------------------
__global__ __launch_bounds__(256) void xcol_kernel(
    const float* __restrict__ off, _Float16* __restrict__ Xcol)
{
  const size_t idx = (size_t)blockIdx.x * 256 + threadIdx.x; // 2*36*16384
  const int p  = (int)(idx & 16383);
  const int t  = (int)(idx >> 14);    // b*36 + q
  const int q  = t % 36;
  const int b  = t / 36;
  const int kk = q >> 2, ic0 = (q & 3) * 32;
  const int ky = kk / 3 - 1, kx = kk % 3 - 1;
  const int h = p >> 7, w = p & 127;
  const int hh = h + ky, ww = w + kx;
  const bool valid = ((unsigned)hh < 128u) && ((unsigned)ww < 128u);
  const int ps = valid ? ((hh << 7) + ww) : 0;
  const float* src = off + ((size_t)(b * 128 + ic0) << 14) + ps;
  f16x8 o[4];
#pragma unroll
  for (int j = 0; j < 4; ++j)
#pragma unroll
    for (int e = 0; e < 8; ++e)
      o[j][e] = valid ? (_Float16)src[(size_t)(j * 8 + e) << 14] : (_Float16)0.f;
  f16x8* dst = (f16x8*)Xcol + idx * 4;
  dst[0] = o[0]; dst[1] = o[1]; dst[2] = o[2]; dst[3] = o[3];
}

// ---------------------------------------------------------------------------
// com GEMM via MFMA f16 (unchanged from round 3; verified correct).
// ---------------------------------------------------------------------------
__global__ __launch_bounds__(256) void com_gemm_kernel(
    const _Float16* __restrict__ Xcol, const _Float16* __restrict__ Wf,
    const float* __restrict__ cb, float* __restrict__ om)
{
  const int b    = blockIdx.y;
  const int tid  = threadIdx.x;
  const int wv   = tid >> 6;
  const int lane = tid & 63;
  const int px0  = blockIdx.x * 64 + wv * 16;

  f32x4 acc[14];
#pragma unroll
  for (int m = 0; m < 14; ++m) acc[m] = (f32x4){0.f, 0.f, 0.f, 0.f};

  const f16x8* Bp = (const f16x8*)Xcol
      + ((size_t)(b * 36) * 16384 + px0 + (lane & 15)) * 4 + (lane >> 4);
  const f16x8* Ap = (const f16x8*)Wf + lane;

#pragma unroll 1
  for (int q = 0; q < 36; ++q) {
    f16x8 bf = Bp[(size_t)q * 65536];
    const f16x8* ap = Ap + q * (14 * 64);
#pragma unroll
    for (int m = 0; m < 14; ++m) {
      f16x8 af = ap[m * 64];
      acc[m] = __builtin_amdgcn_mfma_f32_16x16x32_f16(af, bf, acc[m], 0, 0, 0);
    }
  }

  const int pxl = px0 + (lane & 15);
  const int r0  = (lane >> 4) * 4;
#pragma unroll
  for (int m = 0; m < 14; ++m) {
    int ocb = m * 16 + r0;
#pragma unroll
    for (int r = 0; r < 4; ++r) {
      int oc = ocb + r;
      if (oc < 216)
        om[((size_t)(b * 216 + oc) << 14) + pxl] = acc[m][r] + cb[oc];
    }
  }
}

// ---------------------------------------------------------------------------
// NHWC transpose of feat_s: fsT[b][p][c] <- fs[b][c][p], p < 4096, c < 128
// ---------------------------------------------------------------------------
__global__ __launch_bounds__(256) void nhwc_kernel(const float* __restrict__ fs,
                                                   float* __restrict__ fsT)
{
  const int b  = blockIdx.z;
  const int c0 = blockIdx.y * 32;
  const int p0 = blockIdx.x * 32;
  const int tid = threadIdx.x;
  __shared__ float T[32][33];
  {
    int pxl = tid & 31, cy = tid >> 5;
#pragma unroll
    for (int j = 0; j < 4; ++j) {
      int c = cy + j * 8;
      T[c][pxl] = fs[((size_t)(b * 128 + c0 + c) << 12) + p0 + pxl];
    }
  }
  __syncthreads();
  {
    int cl = tid & 31, pr = tid >> 5;
#pragma unroll
    for (int j = 0; j < 4; ++j) {
      int pp = pr + j * 8;
      fsT[(((size_t)b << 12) + p0 + pp) * 128 + c0 + cl] = T[cl][pp];
    }
  }
}

// ---------------------------------------------------------------------------
// sample_kernel: one thread per (b,g,k,px). Bilinear-sample 16 channels of
// nearest-upsampled feat_s (via fsT NHWC), apply mask, write f16 into MFMA-B
// fragment layout: valh[((b*36+q)*16384+px)*32 + (t9&1)*16 + c], t9 = g*9+k,
// q = t9>>1  (K order r' = t9*16 + c, matching Wf2).
// ---------------------------------------------------------------------------
__global__ __launch_bounds__(256) void sample_kernel(
    const float* __restrict__ fsT, const float* __restrict__ om,
    _Float16* __restrict__ valh)
{
  const int idx = blockIdx.x * 256 + threadIdx.x;   // B*DG*KK*HW = 2,359,296
  const int px = idx & 16383;
  const int t  = idx >> 14;        // b*72 + g*9 + k
  const int k  = t % 9;
  const int g  = (t / 9) & 7;
  const int b  = t / 72;
  const int h = px >> 7, w = px & 127;

  const size_t omb = ((size_t)b * 216) << 14;
  const float offy = om[omb + ((size_t)(g * 18 + 2 * k) << 14) + px];
  const float offx = om[omb + ((size_t)(g * 18 + 2 * k + 1) << 14) + px];
  const float mraw = om[omb + ((size_t)(144 + g * 9 + k) << 14) + px];
  const float mv = 1.f / (1.f + __expf(-mraw));

  const float py  = (float)(h + k / 3 - 1) + offy;
  const float pxx = (float)(w + k % 3 - 1) + offx;
  const float y0f = floorf(py), x0f = floorf(pxx);
  const float ly = py - y0f, lx = pxx - x0f;
  const int y0 = (int)y0f, x0i = (int)x0f;
  const int y1 = y0 + 1, x1 = x0i + 1;

  const int y0c = min(max(y0, 0), 127), y1c = min(max(y1, 0), 127);
  const int x0c = min(max(x0i, 0), 127), x1c = min(max(x1, 0), 127);

  float w00 = (1.f - ly) * (1.f - lx) * mv;
  float w01 = (1.f - ly) * lx * mv;
  float w10 = ly * (1.f - lx) * mv;
  float w11 = ly * lx * mv;
  const bool vy0 = (unsigned)y0 < 128u, vy1 = (unsigned)y1 < 128u;
  const bool vx0 = (unsigned)x0i < 128u, vx1 = (unsigned)x1 < 128u;
  w00 = (vy0 && vx0) ? w00 : 0.f;
  w01 = (vy0 && vx1) ? w01 : 0.f;
  w10 = (vy1 && vx0) ? w10 : 0.f;
  w11 = (vy1 && vx1) ? w11 : 0.f;

  const float* fb = fsT + ((size_t)b << 19);
  const int a00 = ((((y0c >> 1) << 6) + (x0c >> 1)) << 7) + g * 16;
  const int a01 = ((((y0c >> 1) << 6) + (x1c >> 1)) << 7) + g * 16;
  const int a10 = ((((y1c >> 1) << 6) + (x0c >> 1)) << 7) + g * 16;
  const int a11 = ((((y1c >> 1) << 6) + (x1c >> 1)) << 7) + g * 16;

  f16x8 ov[2];
#pragma unroll
  for (int cq = 0; cq < 4; ++cq) {
    float4 v00 = *(const float4*)(fb + a00 + cq * 4);
    float4 v01 = *(const float4*)(fb + a01 + cq * 4);
    float4 v10 = *(const float4*)(fb + a10 + cq * 4);
    float4 v11 = *(const float4*)(fb + a11 + cq * 4);
    ov[cq >> 1][(cq & 1) * 4 + 0] = (_Float16)(w00 * v00.x + w01 * v01.x + w10 * v10.x + w11 * v11.x);
    ov[cq >> 1][(cq & 1) * 4 + 1] = (_Float16)(w00 * v00.y + w01 * v01.y + w10 * v10.y + w11 * v11.y);
    ov[cq >> 1][(cq & 1) * 4 + 2] = (_Float16)(w00 * v00.z + w01 * v01.z + w10 * v10.z + w11 * v11.z);
    ov[cq >> 1][(cq & 1) * 4 + 3] = (_Float16)(w00 * v00.w + w01 * v01.w + w10 * v10.w + w11 * v11.w);
  }

  const int t9 = g * 9 + k;
  _Float16* dst = valh + (((size_t)(b * 36 + (t9 >> 1)) * 16384 + px) * 32 + (t9 & 1) * 16);
  ((f16x8*)dst)[0] = ov[0];
  ((f16x8*)dst)[1] = ov[1];
}

// ---------------------------------------------------------------------------
// dcn GEMM via MFMA f16: al[b][oc][p] = relu(sum_{r'<1152} Wf2 x valh + db).
// Block = 4 waves; wave = 16 px x 32 oc (wave pairs share px -> B hits L1).
// Grid (512, 2) -> 4096 waves = 16/CU.
// ---------------------------------------------------------------------------
__global__ __launch_bounds__(256) void dcn_gemm_kernel(
    const _Float16* __restrict__ valh, const _Float16* __restrict__ Wf2,
    const float* __restrict__ db, float* __restrict__ al)
{
  const int b    = blockIdx.y;
  const int tid  = threadIdx.x;
  const int wv   = tid >> 6;
  const int lane = tid & 63;
  const int px0  = blockIdx.x * 32 + (wv >> 1) * 16;
  const int m0   = (wv & 1) * 2;    // 2 m-tiles per wave

  f32x4 acc[2];
  acc[0] = (f32x4){0.f, 0.f, 0.f, 0.f};
  acc[1] = (f32x4){0.f, 0.f, 0.f, 0.f};

  const f16x8* Bp = (const f16x8*)valh
      + ((size_t)(b * 36) * 16384 + px0 + (lane & 15)) * 4 + (lane >> 4);
  const f16x8* Ap = (const f16x8*)Wf2 + m0 * 64 + lane;

#pragma unroll 2
  for (int q = 0; q < 36; ++q) {
    f16x8 bf = Bp[(size_t)q * 65536];
    const f16x8* ap = Ap + q * (4 * 64);
    f16x8 a0 = ap[0];
    f16x8 a1 = ap[64];
    acc[0] = __builtin_amdgcn_mfma_f32_16x16x32_f16(a0, bf, acc[0], 0, 0, 0);
    acc[1] = __builtin_amdgcn_mfma_f32_16x16x32_f16(a1, bf, acc[1], 0, 0, 0);
  }

  const int pxl = px0 + (lane & 15);
  const int r0  = (lane >> 4) * 4;
#pragma unroll
  for (int mm = 0; mm < 2; ++mm) {
#pragma unroll
    for (int r = 0; r < 4; ++r) {
      int oc = (m0 + mm) * 16 + r0 + r;
      al[((size_t)(b * 64 + oc) << 14) + pxl] = relu_(acc[mm][r] + db[oc]);
    }
  }
}

// ---------------------------------------------------------------------------
// FALLBACK path kernels (small ws): round-1 versions
// ---------------------------------------------------------------------------
__global__ __launch_bounds__(256) void com_conv_kernel(
    const float* __restrict__ x, const float* __restrict__ cw,
    const float* __restrict__ cb, float* __restrict__ om)
{
  const int b    = blockIdx.z;
  const int ocg  = blockIdx.y;
  const int tile = blockIdx.x;
  const int th = (tile >> 2) * 32, tw = (tile & 3) * 32;
  const int tid = threadIdx.x;
  const int lw = (tid & 7) * 4;
  const int lh = tid >> 3;

  __shared__ float Xs[8 * 34 * 34];

  float acc[8][4];
#pragma unroll
  for (int a = 0; a < 8; ++a)
#pragma unroll
    for (int p = 0; p < 4; ++p) acc[a][p] = 0.f;

  for (int cc = 0; cc < 128; cc += 8) {
    __syncthreads();
    for (int idx = tid; idx < 8 * 1156; idx += 256) {
      int ic  = idx / 1156;
      int rem = idx - ic * 1156;
      int yy  = rem / 34;
      int xx  = rem - yy * 34;
      int gh = th + yy - 1, gw = tw + xx - 1;
      float v = 0.f;
      if ((unsigned)gh < 128u && (unsigned)gw < 128u)
        v = x[((size_t)(b * 128 + cc + ic) << 14) + (gh << 7) + gw];
      Xs[idx] = v;
    }
    __syncthreads();
#pragma unroll 1
    for (int ic = 0; ic < 8; ++ic) {
      float xr[3][6];
#pragma unroll
      for (int ky = 0; ky < 3; ++ky)
#pragma unroll
        for (int xx = 0; xx < 6; ++xx)
          xr[ky][xx] = Xs[ic * 1156 + (lh + ky) * 34 + lw + xx];
      const float* wp = cw + ((size_t)(ocg * 8) * 128 + (cc + ic)) * 9;
#pragma unroll
      for (int a = 0; a < 8; ++a) {
        const float* w9 = wp + a * 1152;
#pragma unroll
        for (int ky = 0; ky < 3; ++ky)
#pragma unroll
          for (int kx = 0; kx < 3; ++kx) {
            float wv = w9[ky * 3 + kx];
#pragma unroll
            for (int p = 0; p < 4; ++p)
              acc[a][p] = fmaf(wv, xr[ky][kx + p], acc[a][p]);
          }
      }
    }
  }

#pragma unroll
  for (int a = 0; a < 8; ++a) {
    int oc = ocg * 8 + a;
    float bv = cb[oc];
    float4 r = make_float4(acc[a][0] + bv, acc[a][1] + bv,
                           acc[a][2] + bv, acc[a][3] + bv);
    *(float4*)(om + ((size_t)(b * 216 + oc) << 14) + ((th + lh) << 7) + tw + lw) = r;
  }
}

__global__ __launch_bounds__(256) void wt_kernel(const float* __restrict__ dw,
                                                 float* __restrict__ wT)
{
  int idx = blockIdx.x * 256 + threadIdx.x;
  int o    = idx & 63;
  int rest = idx >> 6;
  int k    = rest % 9;
  int gc   = rest / 9;
  wT[idx] = dw[(o * 128 + gc) * 9 + k];
}

__global__ __launch_bounds__(256) void dcn_kernel(
    const float* __restrict__ fs, const float* __restrict__ om,
    const float* __restrict__ wT, const float* __restrict__ db,
    float* __restrict__ al)
{
  const int b   = blockIdx.y;
  const int p0  = blockIdx.x * 32;
  const int tid = threadIdx.x;
  const int px  = tid & 31;
  const int g   = tid >> 5;
  const int p = p0 + px;
  const int h = p >> 7, w = p & 127;

  float acc[64];
#pragma unroll
  for (int o = 0; o < 64; ++o) acc[o] = 0.f;

  const size_t omb = ((size_t)b * 216) << 14;
  const float* fsg = fs + (((size_t)(b * 128 + g * 16)) << 12);
  const float* wg  = wT + g * (16 * 9 * 64);

#pragma unroll 1
  for (int k = 0; k < 9; ++k) {
    float offy = om[omb + ((size_t)(g * 18 + 2 * k) << 14) + p];
    float offx = om[omb + ((size_t)(g * 18 + 2 * k + 1) << 14) + p];
    float mraw = om[omb + ((size_t)(144 + g * 9 + k) << 14) + p];
    float mv = 1.f / (1.f + __expf(-mraw));

    float py  = (float)(h + k / 3 - 1) + offy;
    float pxx = (float)(w + k % 3 - 1) + offx;
    float y0f = floorf(py), x0f = floorf(pxx);
    float ly = py - y0f, lx = pxx - x0f;
    int y0 = (int)y0f, x0i = (int)x0f;
    int y1 = y0 + 1, x1 = x0i + 1;

    int y0c = min(max(y0, 0), 127), y1c = min(max(y1, 0), 127);
    int x0c = min(max(x0i, 0), 127), x1c = min(max(x1, 0), 127);
    int ry0 = (y0c >> 1) << 6, ry1 = (y1c >> 1) << 6;
    int cx0 = x0c >> 1, cx1 = x1c >> 1;

    float w00 = (1.f - ly) * (1.f - lx) * mv;
    float w01 = (1.f - ly) * lx * mv;
    float w10 = ly * (1.f - lx) * mv;
    float w11 = ly * lx * mv;
    bool vy0 = (unsigned)y0 < 128u, vy1 = (unsigned)y1 < 128u;
    bool vx0 = (unsigned)x0i < 128u, vx1 = (unsigned)x1 < 128u;
    w00 = (vy0 && vx0) ? w00 : 0.f;
    w01 = (vy0 && vx1) ? w01 : 0.f;
    w10 = (vy1 && vx0) ? w10 : 0.f;
    w11 = (vy1 && vx1) ? w11 : 0.f;

#pragma unroll 1
    for (int c = 0; c < 16; ++c) {
      const float* fc = fsg + (c << 12);
      float v00 = fc[ry0 + cx0];
      float v01 = fc[ry0 + cx1];
      float v10 = fc[ry1 + cx0];
      float v11 = fc[ry1 + cx1];
      float v = w00 * v00 + w01 * v01 + w10 * v10 + w11 * v11;
      const float* wp = wg + (c * 9 + k) * 64;
#pragma unroll
      for (int oq = 0; oq < 16; ++oq) {
        float4 w4 = *(const float4*)(wp + oq * 4);
        acc[oq * 4 + 0] = fmaf(v, w4.x, acc[oq * 4 + 0]);
        acc[oq * 4 + 1] = fmaf(v, w4.y, acc[oq * 4 + 1]);
        acc[oq * 4 + 2] = fmaf(v, w4.z, acc[oq * 4 + 2]);
        acc[oq * 4 + 3] = fmaf(v, w4.w, acc[oq * 4 + 3]);
      }
    }
  }

  __shared__ float red[256][17];
  const int px2 = tid & 31;
  const int og  = tid >> 5;
#pragma unroll
  for (int r = 0; r < 4; ++r) {
    __syncthreads();
#pragma unroll
    for (int j = 0; j < 16; ++j) red[tid][j] = acc[r * 16 + j];
    __syncthreads();
#pragma unroll
    for (int jj = 0; jj < 2; ++jj) {
      int ol = og * 2 + jj;
      float s = 0.f;
#pragma unroll
      for (int gg = 0; gg < 8; ++gg) s += red[gg * 32 + px2][ol];
      int oc = r * 16 + ol;
      s += db[oc];
      al[((size_t)(b * 64 + oc) << 14) + p0 + px2] = fmaxf(s, 0.f);
    }
  }
}

// ---------------------------------------------------------------------------
extern "C" void kernel_launch(void* const* d_in, const int* in_sizes, int n_in,
                              void* d_out, int out_size, void* d_ws, size_t ws_size,
                              hipStream_t stream)
{
  const float* feat_l   = (const float*)d_in[0];
  const float* feat_s   = (const float*)d_in[1];
  const float* fsm_w    = (const float*)d_in[2];
  const float* offset_w = (const float*)d_in[3];
  const float* com_w    = (const float*)d_in[4];
  const float* com_b    = (const float*)d_in[5];
  const float* dcn_w    = (const float*)d_in[6];
  const float* dcn_b    = (const float*)d_in[7];
  const float* cat_w    = (const float*)d_in[8];
  float* out = (float*)d_out;
  float* ws  = (float*)d_ws;

  // Layout (floats): arm 4,194,304 | om 7,077,888 | al 2,097,152 (Wf borrows
  // its start; dead before al written) | fsT 1,048,576 | X 37,748,736:
  //   off at X[0..4,194,304)            (live: conv1x1<1> -> xcol)
  //   Xcol/valh f16 at X+4,194,304      (18,874,368 floats; Xcol live
  //     xcol->com_gemm, then valh overlays it sample->dcn_gemm)
  //   Wf2 at X[0..36,864)               (live: wf2 -> dcn_gemm; off dead then)
  const size_t NEED = (size_t)(4194304 + 7077888 + 2097152 + 1048576 + 37748736) * 4;

  if (ws_size >= NEED) {
    float* arm = ws;
    float* om  = ws + 4194304;
    float* al  = ws + 11272192;
    float* fsT = ws + 13369344;
    float* X   = ws + 14417920;
    float* off = X;
    _Float16* Xcol = (_Float16*)(X + 4194304);
    _Float16* valh = Xcol;            // same region, sequential lifetimes
    _Float16* Wf2  = (_Float16*)X;    // overlays dead off
    _Float16* Wf = (_Float16*)al;     // 258,048 f16, dead before al write

    hipLaunchKernelGGL(wf_kernel, dim3(126), dim3(256), 0, stream, com_w, Wf);
    hipLaunchKernelGGL((conv1x1_kernel<0, 128>), dim3(256, 2), dim3(256), 0, stream,
                       feat_l, nullptr, fsm_w, arm);
    hipLaunchKernelGGL(nhwc_kernel, dim3(128, 4, 2), dim3(256), 0, stream,
                       feat_s, fsT);
    hipLaunchKernelGGL((conv1x1_kernel<1, 256>), dim3(256, 2), dim3(256), 0, stream,
                       arm, feat_s, offset_w, off);
    hipLaunchKernelGGL(xcol_kernel, dim3(4608), dim3(256), 0, stream, off, Xcol);
    hipLaunchKernelGGL(wf2_kernel, dim3(36), dim3(256), 0, stream, dcn_w, Wf2);
    hipLaunchKernelGGL(com_gemm_kernel, dim3(256, 2), dim3(256), 0, stream,
                       Xcol, Wf, com_b, om);
    hipLaunchKernelGGL(sample_kernel, dim3(9216), dim3(256), 0, stream,
                       fsT, om, valh);
    hipLaunchKernelGGL(dcn_gemm_kernel, dim3(512, 2), dim3(256), 0, stream,
                       valh, Wf2, dcn_b, al);
    hipLaunchKernelGGL((conv1x1_kernel<2, 64>), dim3(256, 2), dim3(256), 0, stream,
                       al, arm, cat_w, out);
  } else {
    float* arm = ws;
    float* off = ws + 4194304;
    float* om  = ws + 8388608;
    float* al  = ws + 15466496;
    float* wT  = ws + 17563648;

    hipLaunchKernelGGL(wt_kernel, dim3(288), dim3(256), 0, stream, dcn_w, wT);
    hipLaunchKernelGGL((conv1x1_kernel<0, 128>), dim3(256, 2), dim3(256), 0, stream,
                       feat_l, nullptr, fsm_w, arm);
    hipLaunchKernelGGL((conv1x1_kernel<1, 256>), dim3(256, 2), dim3(256), 0, stream,
                       arm, feat_s, offset_w, off);
    hipLaunchKernelGGL(com_conv_kernel, dim3(16, 27, 2), dim3(256), 0, stream,
                       off, com_w, com_b, om);
    hipLaunchKernelGGL(dcn_kernel, dim3(512, 2), dim3(256), 0, stream,
                       feat_s, om, wT, dcn_b, al);
    hipLaunchKernelGGL((conv1x1_kernel<2, 64>), dim3(256, 2), dim3(256), 0, stream,
                       al, arm, cat_w, out);
  }
}

// Round 5
// 266.464 us; speedup vs baseline: 3.2393x; 1.2882x over previous
//
#include <hip/hip_runtime.h>
#include <cstdint>
#include <cstddef>

// Problem constants
// B=2, C=128, H=W=128, Hs=Ws=64, DG=8, KK=9, CG=16, COUT_DCN=64, HW=16384

typedef _Float16 f16x8 __attribute__((ext_vector_type(8)));
typedef _Float16 f16x4 __attribute__((ext_vector_type(4)));
typedef float    f32x4 __attribute__((ext_vector_type(4)));

__device__ __forceinline__ float relu_(float x) { return fmaxf(x, 0.f); }

// ---------------------------------------------------------------------------
// conv1x1 (fp32, LDS-tiled). Fast path uses only MODE 2 (cat+residual);
// MODE 0/1 retained for the fallback path.
// ---------------------------------------------------------------------------
template<int MODE, int CIN>
__global__ __launch_bounds__(256) void conv1x1_kernel(
    const float* __restrict__ in1, const float* __restrict__ in2,
    const float* __restrict__ Wm, float* __restrict__ out)
{
  constexpr int IN1C = (MODE == 2) ? 64 : 128;
  const int b  = blockIdx.y;
  const int p0 = blockIdx.x * 64;
  const int tid = threadIdx.x;
  const int tx = tid & 7;
  const int ty = tid >> 3;

  __shared__ float Xs[16][64];
  __shared__ float Wt[16][128];

  float acc[4][8];
#pragma unroll
  for (int i = 0; i < 4; ++i)
#pragma unroll
    for (int j = 0; j < 8; ++j) acc[i][j] = 0.f;

  const int cS  = tid >> 4;
  const int pxS = (tid & 15) * 4;
  const int ocS = (tid & 15) * 8;

  for (int cc = 0; cc < CIN; cc += 16) {
    __syncthreads();
    {
      int gc = cc + cS;
      float4 v;
      if (MODE == 1 && gc >= 128) {
        int sc = gc - 128;
        float t[4];
#pragma unroll
        for (int j = 0; j < 4; ++j) {
          int pp = p0 + pxS + j;
          int hh = pp >> 7, ww = pp & 127;
          t[j] = 2.f * in2[((size_t)(b * 128 + sc) << 12) + ((hh >> 1) << 6) + (ww >> 1)];
        }
        v = make_float4(t[0], t[1], t[2], t[3]);
      } else {
        v = *(const float4*)(in1 + ((size_t)(b * IN1C + gc) << 14) + p0 + pxS);
      }
      *(float4*)&Xs[cS][pxS] = v;
#pragma unroll
      for (int j = 0; j < 8; ++j)
        Wt[cS][ocS + j] = Wm[(ocS + j) * CIN + cc + cS];
    }
    __syncthreads();
#pragma unroll
    for (int c = 0; c < 16; ++c) {
      float4 wv = *(const float4*)&Wt[c][ty * 4];
      float4 x0 = *(const float4*)&Xs[c][tx * 8];
      float4 x1 = *(const float4*)&Xs[c][tx * 8 + 4];
      float xs[8] = {x0.x, x0.y, x0.z, x0.w, x1.x, x1.y, x1.z, x1.w};
      float wf[4] = {wv.x, wv.y, wv.z, wv.w};
#pragma unroll
      for (int i = 0; i < 4; ++i)
#pragma unroll
        for (int j = 0; j < 8; ++j)
          acc[i][j] = fmaf(wf[i], xs[j], acc[i][j]);
    }
  }

#pragma unroll
  for (int i = 0; i < 4; ++i) {
    int oc = ty * 4 + i;
    size_t base = ((size_t)(b * 128 + oc) << 14) + p0 + tx * 8;
    float r[8];
#pragma unroll
    for (int j = 0; j < 8; ++j) r[j] = relu_(acc[i][j]);
    if (MODE == 2) {
#pragma unroll
      for (int j = 0; j < 8; ++j) r[j] += in2[base + j];
    }
    *(float4*)(out + base)     = make_float4(r[0], r[1], r[2], r[3]);
    *(float4*)(out + base + 4) = make_float4(r[4], r[5], r[6], r[7]);
  }
}

// ---------------------------------------------------------------------------
// t2h: transpose [b][128][HW] f32 -> [b][HW][128] f16 (NHWC half).
// ---------------------------------------------------------------------------
__global__ __launch_bounds__(256) void t2h_kernel(
    const float* __restrict__ src, _Float16* __restrict__ dst, int HW)
{
  const int b  = blockIdx.z;
  const int c0 = blockIdx.y * 32;
  const int p0 = blockIdx.x * 32;
  const int tid = threadIdx.x;
  __shared__ float T[32][33];
  {
    int pxl = tid & 31, cy = tid >> 5;
#pragma unroll
    for (int j = 0; j < 4; ++j) {
      int c = cy + j * 8;
      T[c][pxl] = src[((size_t)(b * 128 + c0 + c)) * HW + p0 + pxl];
    }
  }
  __syncthreads();
  {
    int cq = tid & 7, pr = tid >> 3;
    f16x4 v;
#pragma unroll
    for (int e = 0; e < 4; ++e) v[e] = (_Float16)T[cq * 4 + e][pr];
    *(f16x4*)&dst[(((size_t)b * HW) + p0 + pr) * 128 + c0 + cq * 4] = v;
  }
}

// ---------------------------------------------------------------------------
// Weight packs into A-fragment order for mfma_f32_16x16x32_f16.
// Entry idx = (q*NM + m)*64 + lane; lane holds oc=m*16+(lane&15),
// k = q*32+(lane>>4)*8+j.
// ---------------------------------------------------------------------------
__global__ __launch_bounds__(256) void wfA_kernel(      // fsm_w [128][128]
    const float* __restrict__ w, _Float16* __restrict__ Wf)
{
  int idx = blockIdx.x * 256 + threadIdx.x;  // 4q*8m*64 = 2048
  int lane = idx & 63;
  int t = idx >> 6;
  int m = t & 7, q = t >> 3;
  int oc = m * 16 + (lane & 15);
  int c0 = q * 32 + (lane >> 4) * 8;
  f16x8 v;
#pragma unroll
  for (int j = 0; j < 8; ++j) v[j] = (_Float16)w[oc * 128 + c0 + j];
  ((f16x8*)Wf)[idx] = v;
}

__global__ __launch_bounds__(256) void wfB_kernel(      // offset_w [128][256], x2 on c>=128
    const float* __restrict__ w, _Float16* __restrict__ Wf)
{
  int idx = blockIdx.x * 256 + threadIdx.x;  // 8q*8m*64 = 4096
  int lane = idx & 63;
  int t = idx >> 6;
  int m = t & 7, q = t >> 3;
  int oc = m * 16 + (lane & 15);
  int c0 = q * 32 + (lane >> 4) * 8;
  float s = (q >= 4) ? 2.f : 1.f;
  f16x8 v;
#pragma unroll
  for (int j = 0; j < 8; ++j) v[j] = (_Float16)(w[oc * 256 + c0 + j] * s);
  ((f16x8*)Wf)[idx] = v;
}

__global__ __launch_bounds__(256) void wf_kernel(       // com_w, kk-major chunks
    const float* __restrict__ cw, _Float16* __restrict__ Wf)
{
  int idx = blockIdx.x * 256 + threadIdx.x;  // 36*14*64 = 32256 = 126*256
  int lane = idx & 63;
  int t = idx >> 6;          // q*14 + m
  int m = t % 14, q = t / 14;
  int kk = q >> 2;
  int ic0 = (q & 3) * 32 + (lane >> 4) * 8;
  int oc = m * 16 + (lane & 15);
  f16x8 v;
#pragma unroll
  for (int j = 0; j < 8; ++j) {
    float x = (oc < 216) ? cw[((size_t)oc * 128 + ic0 + j) * 9 + kk] : 0.f;
    v[j] = (_Float16)x;
  }
  ((f16x8*)Wf)[idx] = v;
}

__global__ __launch_bounds__(256) void wf2_kernel(      // dcn_w, r' = (g*9+k)*16+c
    const float* __restrict__ dw, _Float16* __restrict__ Wf2)
{
  int idx = blockIdx.x * 256 + threadIdx.x;  // 36*4*64 = 9216
  int lane = idx & 63;
  int t = idx >> 6;
  int m = t & 3, q = t >> 2;
  int oc = m * 16 + (lane & 15);
  f16x8 v;
#pragma unroll
  for (int j = 0; j < 8; ++j) {
    int rp = q * 32 + (lane >> 4) * 8 + j;
    int c = rp & 15, tt = rp >> 4;
    int g = tt / 9, k = tt % 9;
    v[j] = (_Float16)dw[((size_t)oc * 128 + g * 16 + c) * 9 + k];
  }
  ((f16x8*)Wf2)[idx] = v;
}

// ---------------------------------------------------------------------------
// fsm GEMM: arm = relu(fsm_w @ feat_l). A=WfA, B=flTh [p][128] f16.
// Wave = 16 px x 128 oc (8 m-tiles). Outputs arm f32 [oc][p] + armh f16 [p][oc].
// ---------------------------------------------------------------------------
__global__ __launch_bounds__(256) void fsm_gemm_kernel(
    const _Float16* __restrict__ flTh, const _Float16* __restrict__ WfA,
    float* __restrict__ arm, _Float16* __restrict__ armh)
{
  const int b    = blockIdx.y;
  const int tid  = threadIdx.x;
  const int wv   = tid >> 6;
  const int lane = tid & 63;
  const int px0  = blockIdx.x * 64 + wv * 16;
  const int pxl  = px0 + (lane & 15);

  f32x4 acc[8];
#pragma unroll
  for (int m = 0; m < 8; ++m) acc[m] = (f32x4){0.f, 0.f, 0.f, 0.f};

  const f16x8* Bp = (const f16x8*)flTh + (((size_t)b << 14) + pxl) * 16 + (lane >> 4);
  const f16x8* Ap = (const f16x8*)WfA + lane;

#pragma unroll
  for (int q = 0; q < 4; ++q) {
    f16x8 bf = Bp[q * 4];
#pragma unroll
    for (int m = 0; m < 8; ++m)
      acc[m] = __builtin_amdgcn_mfma_f32_16x16x32_f16(Ap[(q * 8 + m) * 64], bf, acc[m], 0, 0, 0);
  }

  const int r0 = (lane >> 4) * 4;
#pragma unroll
  for (int m = 0; m < 8; ++m) {
    f16x4 h;
#pragma unroll
    for (int r = 0; r < 4; ++r) {
      float v = relu_(acc[m][r]);
      arm[((size_t)(b * 128 + m * 16 + r0 + r) << 14) + pxl] = v;
      h[r] = (_Float16)v;
    }
    *(f16x4*)&armh[(((size_t)b << 14) + pxl) * 128 + m * 16 + r0] = h;
  }
}

// ---------------------------------------------------------------------------
// offset GEMM: offh = relu(offset_w @ [armh ; 2*featup]) in f16 [p][128].
// B chunks q<4 from armh; q>=4 from fsTh at upsample-source row (x2 in weights).
// ---------------------------------------------------------------------------
__global__ __launch_bounds__(256) void off_gemm_kernel(
    const _Float16* __restrict__ armh, const _Float16* __restrict__ fsTh,
    const _Float16* __restrict__ WfB, _Float16* __restrict__ offh)
{
  const int b    = blockIdx.y;
  const int tid  = threadIdx.x;
  const int wv   = tid >> 6;
  const int lane = tid & 63;
  const int px0  = blockIdx.x * 64 + wv * 16;
  const int pxl  = px0 + (lane & 15);
  const int h = pxl >> 7, w = pxl & 127;
  const int pup = ((h >> 1) << 6) + (w >> 1);

  f32x4 acc[8];
#pragma unroll
  for (int m = 0; m < 8; ++m) acc[m] = (f32x4){0.f, 0.f, 0.f, 0.f};

  const f16x8* BpA = (const f16x8*)armh + (((size_t)b << 14) + pxl) * 16 + (lane >> 4);
  const f16x8* BpU = (const f16x8*)fsTh + (((size_t)b << 12) + pup) * 16 + (lane >> 4);
  const f16x8* Ap  = (const f16x8*)WfB + lane;

#pragma unroll
  for (int q = 0; q < 8; ++q) {
    f16x8 bf = (q < 4) ? BpA[q * 4] : BpU[(q - 4) * 4];
#pragma unroll
    for (int m = 0; m < 8; ++m)
      acc[m] = __builtin_amdgcn_mfma_f32_16x16x32_f16(Ap[(q * 8 + m) * 64], bf, acc[m], 0, 0, 0);
  }

  const int r0 = (lane >> 4) * 4;
#pragma unroll
  for (int m = 0; m < 8; ++m) {
    f16x4 hh;
#pragma unroll
    for (int r = 0; r < 4; ++r) hh[r] = (_Float16)relu_(acc[m][r]);
    *(f16x4*)&offh[(((size_t)b << 14) + pxl) * 128 + m * 16 + r0] = hh;
  }
}

// ---------------------------------------------------------------------------
// com GEMM: om[b][oc][p] = sum_{kk,ic} com_w x off_feat(shifted) + cb.
// B-fragments loaded DIRECTLY from offh [p][128] at per-kk shifted pixel
// (border -> zero). No im2col materialization.
// ---------------------------------------------------------------------------
__global__ __launch_bounds__(256) void com_gemm_kernel(
    const _Float16* __restrict__ offh, const _Float16* __restrict__ Wf,
    const float* __restrict__ cb, float* __restrict__ om)
{
  const int b    = blockIdx.y;
  const int tid  = threadIdx.x;
  const int wv   = tid >> 6;
  const int lane = tid & 63;
  const int px0  = blockIdx.x * 64 + wv * 16;
  const int pxl  = px0 + (lane & 15);
  const int h = pxl >> 7, w = pxl & 127;

  f32x4 acc[14];
#pragma unroll
  for (int m = 0; m < 14; ++m) acc[m] = (f32x4){0.f, 0.f, 0.f, 0.f};

  const f16x8* base = (const f16x8*)offh + ((size_t)b << 14) * 16 + (lane >> 4);
  const f16x8* Ap   = (const f16x8*)Wf + lane;
  const f16x8 zero = {(_Float16)0.f, (_Float16)0.f, (_Float16)0.f, (_Float16)0.f,
                      (_Float16)0.f, (_Float16)0.f, (_Float16)0.f, (_Float16)0.f};

#pragma unroll 1
  for (int kk = 0; kk < 9; ++kk) {
    const int hh = h + kk / 3 - 1;
    const int ww = w + kk % 3 - 1;
    const bool valid = ((unsigned)hh < 128u) && ((unsigned)ww < 128u);
    const int ps = valid ? ((hh << 7) + ww) : 0;
    const f16x8* bp = base + (size_t)ps * 16;
#pragma unroll
    for (int ic4 = 0; ic4 < 4; ++ic4) {
      f16x8 bf = bp[ic4 * 4];
      bf = valid ? bf : zero;
      const f16x8* ap = Ap + (kk * 4 + ic4) * (14 * 64);
#pragma unroll
      for (int m = 0; m < 14; ++m)
        acc[m] = __builtin_amdgcn_mfma_f32_16x16x32_f16(ap[m * 64], bf, acc[m], 0, 0, 0);
    }
  }

  const int r0 = (lane >> 4) * 4;
#pragma unroll
  for (int m = 0; m < 14; ++m) {
    int ocb = m * 16 + r0;
#pragma unroll
    for (int r = 0; r < 4; ++r) {
      int oc = ocb + r;
      if (oc < 216)
        om[((size_t)(b * 216 + oc) << 14) + pxl] = acc[m][r] + cb[oc];
    }
  }
}

// ---------------------------------------------------------------------------
// sample_kernel: one thread per (b,g,k,px). Bilinear-sample 16 channels of
// nearest-upsampled feat_s (fsTh f16 NHWC), apply mask, write f16 B-fragments:
// valh[((b*36+q)*16384+px)*32 + (t9&1)*16 + c], t9 = g*9+k, q = t9>>1.
// ---------------------------------------------------------------------------
__global__ __launch_bounds__(256) void sample_kernel(
    const _Float16* __restrict__ fsTh, const float* __restrict__ om,
    _Float16* __restrict__ valh)
{
  const int idx = blockIdx.x * 256 + threadIdx.x;   // 2,359,296
  const int px = idx & 16383;
  const int t  = idx >> 14;        // b*72 + g*9 + k
  const int k  = t % 9;
  const int g  = (t / 9) & 7;
  const int b  = t / 72;
  const int h = px >> 7, w = px & 127;

  const size_t omb = ((size_t)b * 216) << 14;
  const float offy = om[omb + ((size_t)(g * 18 + 2 * k) << 14) + px];
  const float offx = om[omb + ((size_t)(g * 18 + 2 * k + 1) << 14) + px];
  const float mraw = om[omb + ((size_t)(144 + g * 9 + k) << 14) + px];
  const float mv = 1.f / (1.f + __expf(-mraw));

  const float py  = (float)(h + k / 3 - 1) + offy;
  const float pxx = (float)(w + k % 3 - 1) + offx;
  const float y0f = floorf(py), x0f = floorf(pxx);
  const float ly = py - y0f, lx = pxx - x0f;
  const int y0 = (int)y0f, x0i = (int)x0f;
  const int y1 = y0 + 1, x1 = x0i + 1;

  const int y0c = min(max(y0, 0), 127), y1c = min(max(y1, 0), 127);
  const int x0c = min(max(x0i, 0), 127), x1c = min(max(x1, 0), 127);

  float w00 = (1.f - ly) * (1.f - lx) * mv;
  float w01 = (1.f - ly) * lx * mv;
  float w10 = ly * (1.f - lx) * mv;
  float w11 = ly * lx * mv;
  const bool vy0 = (unsigned)y0 < 128u, vy1 = (unsigned)y1 < 128u;
  const bool vx0 = (unsigned)x0i < 128u, vx1 = (unsigned)x1 < 128u;
  w00 = (vy0 && vx0) ? w00 : 0.f;
  w01 = (vy0 && vx1) ? w01 : 0.f;
  w10 = (vy1 && vx0) ? w10 : 0.f;
  w11 = (vy1 && vx1) ? w11 : 0.f;

  // fsTh rows: 64x64 spatial, 128 ch; tap = 16 consecutive f16 (2 x f16x8)
  const _Float16* fb = fsTh + (((size_t)b << 12) << 7);
  const int a00 = ((((y0c >> 1) << 6) + (x0c >> 1)) << 7) + g * 16;
  const int a01 = ((((y0c >> 1) << 6) + (x1c >> 1)) << 7) + g * 16;
  const int a10 = ((((y1c >> 1) << 6) + (x0c >> 1)) << 7) + g * 16;
  const int a11 = ((((y1c >> 1) << 6) + (x1c >> 1)) << 7) + g * 16;

  f16x8 t00a = *(const f16x8*)(fb + a00), t00b = *(const f16x8*)(fb + a00 + 8);
  f16x8 t01a = *(const f16x8*)(fb + a01), t01b = *(const f16x8*)(fb + a01 + 8);
  f16x8 t10a = *(const f16x8*)(fb + a10), t10b = *(const f16x8*)(fb + a10 + 8);
  f16x8 t11a = *(const f16x8*)(fb + a11), t11b = *(const f16x8*)(fb + a11 + 8);

  f16x8 ov[2];
#pragma unroll
  for (int j = 0; j < 8; ++j) {
    ov[0][j] = (_Float16)(w00 * (float)t00a[j] + w01 * (float)t01a[j]
                        + w10 * (float)t10a[j] + w11 * (float)t11a[j]);
    ov[1][j] = (_Float16)(w00 * (float)t00b[j] + w01 * (float)t01b[j]
                        + w10 * (float)t10b[j] + w11 * (float)t11b[j]);
  }

  const int t9 = g * 9 + k;
  _Float16* dst = valh + (((size_t)(b * 36 + (t9 >> 1)) * 16384 + px) * 32 + (t9 & 1) * 16);
  ((f16x8*)dst)[0] = ov[0];
  ((f16x8*)dst)[1] = ov[1];
}

// ---------------------------------------------------------------------------
// dcn GEMM via MFMA f16 (unchanged; verified).
// ---------------------------------------------------------------------------
__global__ __launch_bounds__(256) void dcn_gemm_kernel(
    const _Float16* __restrict__ valh, const _Float16* __restrict__ Wf2,
    const float* __restrict__ db, float* __restrict__ al)
{
  const int b    = blockIdx.y;
  const int tid  = threadIdx.x;
  const int wv   = tid >> 6;
  const int lane = tid & 63;
  const int px0  = blockIdx.x * 32 + (wv >> 1) * 16;
  const int m0   = (wv & 1) * 2;

  f32x4 acc[2];
  acc[0] = (f32x4){0.f, 0.f, 0.f, 0.f};
  acc[1] = (f32x4){0.f, 0.f, 0.f, 0.f};

  const f16x8* Bp = (const f16x8*)valh
      + ((size_t)(b * 36) * 16384 + px0 + (lane & 15)) * 4 + (lane >> 4);
  const f16x8* Ap = (const f16x8*)Wf2 + m0 * 64 + lane;

#pragma unroll 2
  for (int q = 0; q < 36; ++q) {
    f16x8 bf = Bp[(size_t)q * 65536];
    const f16x8* ap = Ap + q * (4 * 64);
    f16x8 a0 = ap[0];
    f16x8 a1 = ap[64];
    acc[0] = __builtin_amdgcn_mfma_f32_16x16x32_f16(a0, bf, acc[0], 0, 0, 0);
    acc[1] = __builtin_amdgcn_mfma_f32_16x16x32_f16(a1, bf, acc[1], 0, 0, 0);
  }

  const int pxl = px0 + (lane & 15);
  const int r0  = (lane >> 4) * 4;
#pragma unroll
  for (int mm = 0; mm < 2; ++mm) {
#pragma unroll
    for (int r = 0; r < 4; ++r) {
      int oc = (m0 + mm) * 16 + r0 + r;
      al[((size_t)(b * 64 + oc) << 14) + pxl] = relu_(acc[mm][r] + db[oc]);
    }
  }
}

// ---------------------------------------------------------------------------
// FALLBACK path kernels (small ws): round-1 versions
// ---------------------------------------------------------------------------
__global__ __launch_bounds__(256) void com_conv_kernel(
    const float* __restrict__ x, const float* __restrict__ cw,
    const float* __restrict__ cb, float* __restrict__ om)
{
  const int b    = blockIdx.z;
  const int ocg  = blockIdx.y;
  const int tile = blockIdx.x;
  const int th = (tile >> 2) * 32, tw = (tile & 3) * 32;
  const int tid = threadIdx.x;
  const int lw = (tid & 7) * 4;
  const int lh = tid >> 3;

  __shared__ float Xs[8 * 34 * 34];

  float acc[8][4];
#pragma unroll
  for (int a = 0; a < 8; ++a)
#pragma unroll
    for (int p = 0; p < 4; ++p) acc[a][p] = 0.f;

  for (int cc = 0; cc < 128; cc += 8) {
    __syncthreads();
    for (int idx = tid; idx < 8 * 1156; idx += 256) {
      int ic  = idx / 1156;
      int rem = idx - ic * 1156;
      int yy  = rem / 34;
      int xx  = rem - yy * 34;
      int gh = th + yy - 1, gw = tw + xx - 1;
      float v = 0.f;
      if ((unsigned)gh < 128u && (unsigned)gw < 128u)
        v = x[((size_t)(b * 128 + cc + ic) << 14) + (gh << 7) + gw];
      Xs[idx] = v;
    }
    __syncthreads();
#pragma unroll 1
    for (int ic = 0; ic < 8; ++ic) {
      float xr[3][6];
#pragma unroll
      for (int ky = 0; ky < 3; ++ky)
#pragma unroll
        for (int xx = 0; xx < 6; ++xx)
          xr[ky][xx] = Xs[ic * 1156 + (lh + ky) * 34 + lw + xx];
      const float* wp = cw + ((size_t)(ocg * 8) * 128 + (cc + ic)) * 9;
#pragma unroll
      for (int a = 0; a < 8; ++a) {
        const float* w9 = wp + a * 1152;
#pragma unroll
        for (int ky = 0; ky < 3; ++ky)
#pragma unroll
          for (int kx = 0; kx < 3; ++kx) {
            float wv = w9[ky * 3 + kx];
#pragma unroll
            for (int p = 0; p < 4; ++p)
              acc[a][p] = fmaf(wv, xr[ky][kx + p], acc[a][p]);
          }
      }
    }
  }

#pragma unroll
  for (int a = 0; a < 8; ++a) {
    int oc = ocg * 8 + a;
    float bv = cb[oc];
    float4 r = make_float4(acc[a][0] + bv, acc[a][1] + bv,
                           acc[a][2] + bv, acc[a][3] + bv);
    *(float4*)(om + ((size_t)(b * 216 + oc) << 14) + ((th + lh) << 7) + tw + lw) = r;
  }
}

__global__ __launch_bounds__(256) void wt_kernel(const float* __restrict__ dw,
                                                 float* __restrict__ wT)
{
  int idx = blockIdx.x * 256 + threadIdx.x;
  int o    = idx & 63;
  int rest = idx >> 6;
  int k    = rest % 9;
  int gc   = rest / 9;
  wT[idx] = dw[(o * 128 + gc) * 9 + k];
}

__global__ __launch_bounds__(256) void dcn_kernel(
    const float* __restrict__ fs, const float* __restrict__ om,
    const float* __restrict__ wT, const float* __restrict__ db,
    float* __restrict__ al)
{
  const int b   = blockIdx.y;
  const int p0  = blockIdx.x * 32;
  const int tid = threadIdx.x;
  const int px  = tid & 31;
  const int g   = tid >> 5;
  const int p = p0 + px;
  const int h = p >> 7, w = p & 127;

  float acc[64];
#pragma unroll
  for (int o = 0; o < 64; ++o) acc[o] = 0.f;

  const size_t omb = ((size_t)b * 216) << 14;
  const float* fsg = fs + (((size_t)(b * 128 + g * 16)) << 12);
  const float* wg  = wT + g * (16 * 9 * 64);

#pragma unroll 1
  for (int k = 0; k < 9; ++k) {
    float offy = om[omb + ((size_t)(g * 18 + 2 * k) << 14) + p];
    float offx = om[omb + ((size_t)(g * 18 + 2 * k + 1) << 14) + p];
    float mraw = om[omb + ((size_t)(144 + g * 9 + k) << 14) + p];
    float mv = 1.f / (1.f + __expf(-mraw));

    float py  = (float)(h + k / 3 - 1) + offy;
    float pxx = (float)(w + k % 3 - 1) + offx;
    float y0f = floorf(py), x0f = floorf(pxx);
    float ly = py - y0f, lx = pxx - x0f;
    int y0 = (int)y0f, x0i = (int)x0f;
    int y1 = y0 + 1, x1 = x0i + 1;

    int y0c = min(max(y0, 0), 127), y1c = min(max(y1, 0), 127);
    int x0c = min(max(x0i, 0), 127), x1c = min(max(x1, 0), 127);
    int ry0 = (y0c >> 1) << 6, ry1 = (y1c >> 1) << 6;
    int cx0 = x0c >> 1, cx1 = x1c >> 1;

    float w00 = (1.f - ly) * (1.f - lx) * mv;
    float w01 = (1.f - ly) * lx * mv;
    float w10 = ly * (1.f - lx) * mv;
    float w11 = ly * lx * mv;
    bool vy0 = (unsigned)y0 < 128u, vy1 = (unsigned)y1 < 128u;
    bool vx0 = (unsigned)x0i < 128u, vx1 = (unsigned)x1 < 128u;
    w00 = (vy0 && vx0) ? w00 : 0.f;
    w01 = (vy0 && vx1) ? w01 : 0.f;
    w10 = (vy1 && vx0) ? w10 : 0.f;
    w11 = (vy1 && vx1) ? w11 : 0.f;

#pragma unroll 1
    for (int c = 0; c < 16; ++c) {
      const float* fc = fsg + (c << 12);
      float v00 = fc[ry0 + cx0];
      float v01 = fc[ry0 + cx1];
      float v10 = fc[ry1 + cx0];
      float v11 = fc[ry1 + cx1];
      float v = w00 * v00 + w01 * v01 + w10 * v10 + w11 * v11;
      const float* wp = wg + (c * 9 + k) * 64;
#pragma unroll
      for (int oq = 0; oq < 16; ++oq) {
        float4 w4 = *(const float4*)(wp + oq * 4);
        acc[oq * 4 + 0] = fmaf(v, w4.x, acc[oq * 4 + 0]);
        acc[oq * 4 + 1] = fmaf(v, w4.y, acc[oq * 4 + 1]);
        acc[oq * 4 + 2] = fmaf(v, w4.z, acc[oq * 4 + 2]);
        acc[oq * 4 + 3] = fmaf(v, w4.w, acc[oq * 4 + 3]);
      }
    }
  }

  __shared__ float red[256][17];
  const int px2 = tid & 31;
  const int og  = tid >> 5;
#pragma unroll
  for (int r = 0; r < 4; ++r) {
    __syncthreads();
#pragma unroll
    for (int j = 0; j < 16; ++j) red[tid][j] = acc[r * 16 + j];
    __syncthreads();
#pragma unroll
    for (int jj = 0; jj < 2; ++jj) {
      int ol = og * 2 + jj;
      float s = 0.f;
#pragma unroll
      for (int gg = 0; gg < 8; ++gg) s += red[gg * 32 + px2][ol];
      int oc = r * 16 + ol;
      s += db[oc];
      al[((size_t)(b * 64 + oc) << 14) + p0 + px2] = fmaxf(s, 0.f);
    }
  }
}

// ---------------------------------------------------------------------------
extern "C" void kernel_launch(void* const* d_in, const int* in_sizes, int n_in,
                              void* d_out, int out_size, void* d_ws, size_t ws_size,
                              hipStream_t stream)
{
  const float* feat_l   = (const float*)d_in[0];
  const float* feat_s   = (const float*)d_in[1];
  const float* fsm_w    = (const float*)d_in[2];
  const float* offset_w = (const float*)d_in[3];
  const float* com_w    = (const float*)d_in[4];
  const float* com_b    = (const float*)d_in[5];
  const float* dcn_w    = (const float*)d_in[6];
  const float* dcn_b    = (const float*)d_in[7];
  const float* cat_w    = (const float*)d_in[8];
  float* out = (float*)d_out;
  float* ws  = (float*)d_ws;

  const size_t NEED = (size_t)(4194304 + 7077888 + 2097152 + 1048576 + 37748736) * 4;

  if (ws_size >= NEED) {
    // float-offset layout (all disjoint; total 39,249,920 floats = 157 MB)
    float* arm      = ws;                       // 4,194,304 f32
    float* om       = ws + 4194304;             // 7,077,888 f32
    float* al       = ws + 11272192;            // 2,097,152 f32
    _Float16* fsTh  = (_Float16*)(ws + 13369344);  // 1,048,576 f16
    _Float16* flTh  = (_Float16*)(ws + 13893632);  // 4,194,304 f16
    _Float16* armh  = (_Float16*)(ws + 15990784);  // 4,194,304 f16
    _Float16* offh  = (_Float16*)(ws + 18087936);  // 4,194,304 f16
    _Float16* valh  = (_Float16*)(ws + 20185088);  // 37,748,736 f16
    _Float16* WfA   = (_Float16*)(ws + 39059456);  // 16,384 f16
    _Float16* WfB   = (_Float16*)(ws + 39067648);  // 32,768 f16
    _Float16* Wf    = (_Float16*)(ws + 39084032);  // 258,048 f16
    _Float16* Wf2   = (_Float16*)(ws + 39213056);  // 73,728 f16

    hipLaunchKernelGGL(wfA_kernel, dim3(8), dim3(256), 0, stream, fsm_w, WfA);
    hipLaunchKernelGGL(wfB_kernel, dim3(16), dim3(256), 0, stream, offset_w, WfB);
    hipLaunchKernelGGL(wf_kernel, dim3(126), dim3(256), 0, stream, com_w, Wf);
    hipLaunchKernelGGL(wf2_kernel, dim3(36), dim3(256), 0, stream, dcn_w, Wf2);
    hipLaunchKernelGGL(t2h_kernel, dim3(512, 4, 2), dim3(256), 0, stream,
                       feat_l, flTh, 16384);
    hipLaunchKernelGGL(t2h_kernel, dim3(128, 4, 2), dim3(256), 0, stream,
                       feat_s, fsTh, 4096);
    hipLaunchKernelGGL(fsm_gemm_kernel, dim3(256, 2), dim3(256), 0, stream,
                       flTh, WfA, arm, armh);
    hipLaunchKernelGGL(off_gemm_kernel, dim3(256, 2), dim3(256), 0, stream,
                       armh, fsTh, WfB, offh);
    hipLaunchKernelGGL(com_gemm_kernel, dim3(256, 2), dim3(256), 0, stream,
                       offh, Wf, com_b, om);
    hipLaunchKernelGGL(sample_kernel, dim3(9216), dim3(256), 0, stream,
                       fsTh, om, valh);
    hipLaunchKernelGGL(dcn_gemm_kernel, dim3(512, 2), dim3(256), 0, stream,
                       valh, Wf2, dcn_b, al);
    hipLaunchKernelGGL((conv1x1_kernel<2, 64>), dim3(256, 2), dim3(256), 0, stream,
                       al, arm, cat_w, out);
  } else {
    float* arm = ws;
    float* off = ws + 4194304;
    float* om  = ws + 8388608;
    float* al  = ws + 15466496;
    float* wT  = ws + 17563648;

    hipLaunchKernelGGL(wt_kernel, dim3(288), dim3(256), 0, stream, dcn_w, wT);
    hipLaunchKernelGGL((conv1x1_kernel<0, 128>), dim3(256, 2), dim3(256), 0, stream,
                       feat_l, nullptr, fsm_w, arm);
    hipLaunchKernelGGL((conv1x1_kernel<1, 256>), dim3(256, 2), dim3(256), 0, stream,
                       arm, feat_s, offset_w, off);
    hipLaunchKernelGGL(com_conv_kernel, dim3(16, 27, 2), dim3(256), 0, stream,
                       off, com_w, com_b, om);
    hipLaunchKernelGGL(dcn_kernel, dim3(512, 2), dim3(256), 0, stream,
                       feat_s, om, wT, dcn_b, al);
    hipLaunchKernelGGL((conv1x1_kernel<2, 64>), dim3(256, 2), dim3(256), 0, stream,
                       al, arm, cat_w, out);
  }
}

// Round 6
// 225.647 us; speedup vs baseline: 3.8253x; 1.1809x over previous
//
#include <hip/hip_runtime.h>
#include <cstdint>
#include <cstddef>

// Problem constants
// B=2, C=128, H=W=128, Hs=Ws=64, DG=8, KK=9, CG=16, COUT_DCN=64, HW=16384

typedef _Float16 f16x8 __attribute__((ext_vector_type(8)));
typedef _Float16 f16x4 __attribute__((ext_vector_type(4)));
typedef float    f32x4 __attribute__((ext_vector_type(4)));

__device__ __forceinline__ float relu_(float x) { return fmaxf(x, 0.f); }

// ---------------------------------------------------------------------------
// conv1x1 (fp32, LDS-tiled) — FALLBACK path only.
// ---------------------------------------------------------------------------
template<int MODE, int CIN>
__global__ __launch_bounds__(256) void conv1x1_kernel(
    const float* __restrict__ in1, const float* __restrict__ in2,
    const float* __restrict__ Wm, float* __restrict__ out)
{
  constexpr int IN1C = (MODE == 2) ? 64 : 128;
  const int b  = blockIdx.y;
  const int p0 = blockIdx.x * 64;
  const int tid = threadIdx.x;
  const int tx = tid & 7;
  const int ty = tid >> 3;

  __shared__ float Xs[16][64];
  __shared__ float Wt[16][128];

  float acc[4][8];
#pragma unroll
  for (int i = 0; i < 4; ++i)
#pragma unroll
    for (int j = 0; j < 8; ++j) acc[i][j] = 0.f;

  const int cS  = tid >> 4;
  const int pxS = (tid & 15) * 4;
  const int ocS = (tid & 15) * 8;

  for (int cc = 0; cc < CIN; cc += 16) {
    __syncthreads();
    {
      int gc = cc + cS;
      float4 v;
      if (MODE == 1 && gc >= 128) {
        int sc = gc - 128;
        float t[4];
#pragma unroll
        for (int j = 0; j < 4; ++j) {
          int pp = p0 + pxS + j;
          int hh = pp >> 7, ww = pp & 127;
          t[j] = 2.f * in2[((size_t)(b * 128 + sc) << 12) + ((hh >> 1) << 6) + (ww >> 1)];
        }
        v = make_float4(t[0], t[1], t[2], t[3]);
      } else {
        v = *(const float4*)(in1 + ((size_t)(b * IN1C + gc) << 14) + p0 + pxS);
      }
      *(float4*)&Xs[cS][pxS] = v;
#pragma unroll
      for (int j = 0; j < 8; ++j)
        Wt[cS][ocS + j] = Wm[(ocS + j) * CIN + cc + cS];
    }
    __syncthreads();
#pragma unroll
    for (int c = 0; c < 16; ++c) {
      float4 wv = *(const float4*)&Wt[c][ty * 4];
      float4 x0 = *(const float4*)&Xs[c][tx * 8];
      float4 x1 = *(const float4*)&Xs[c][tx * 8 + 4];
      float xs[8] = {x0.x, x0.y, x0.z, x0.w, x1.x, x1.y, x1.z, x1.w};
      float wf[4] = {wv.x, wv.y, wv.z, wv.w};
#pragma unroll
      for (int i = 0; i < 4; ++i)
#pragma unroll
        for (int j = 0; j < 8; ++j)
          acc[i][j] = fmaf(wf[i], xs[j], acc[i][j]);
    }
  }

#pragma unroll
  for (int i = 0; i < 4; ++i) {
    int oc = ty * 4 + i;
    size_t base = ((size_t)(b * 128 + oc) << 14) + p0 + tx * 8;
    float r[8];
#pragma unroll
    for (int j = 0; j < 8; ++j) r[j] = relu_(acc[i][j]);
    if (MODE == 2) {
#pragma unroll
      for (int j = 0; j < 8; ++j) r[j] += in2[base + j];
    }
    *(float4*)(out + base)     = make_float4(r[0], r[1], r[2], r[3]);
    *(float4*)(out + base + 4) = make_float4(r[4], r[5], r[6], r[7]);
  }
}

// ---------------------------------------------------------------------------
// t2h: transpose [b][128][HW] f32 -> [b][HW][128] f16 (NHWC half).
// ---------------------------------------------------------------------------
__global__ __launch_bounds__(256) void t2h_kernel(
    const float* __restrict__ src, _Float16* __restrict__ dst, int HW)
{
  const int b  = blockIdx.z;
  const int c0 = blockIdx.y * 32;
  const int p0 = blockIdx.x * 32;
  const int tid = threadIdx.x;
  __shared__ float T[32][33];
  {
    int pxl = tid & 31, cy = tid >> 5;
#pragma unroll
    for (int j = 0; j < 4; ++j) {
      int c = cy + j * 8;
      T[c][pxl] = src[((size_t)(b * 128 + c0 + c)) * HW + p0 + pxl];
    }
  }
  __syncthreads();
  {
    int cq = tid & 7, pr = tid >> 3;
    f16x4 v;
#pragma unroll
    for (int e = 0; e < 4; ++e) v[e] = (_Float16)T[cq * 4 + e][pr];
    *(f16x4*)&dst[(((size_t)b * HW) + p0 + pr) * 128 + c0 + cq * 4] = v;
  }
}

// ---------------------------------------------------------------------------
// Weight packs into A-fragment order for mfma_f32_16x16x32_f16.
// ---------------------------------------------------------------------------
__global__ __launch_bounds__(256) void wfA_kernel(      // fsm_w [128][128]
    const float* __restrict__ w, _Float16* __restrict__ Wf)
{
  int idx = blockIdx.x * 256 + threadIdx.x;  // 4q*8m*64 = 2048
  int lane = idx & 63;
  int t = idx >> 6;
  int m = t & 7, q = t >> 3;
  int oc = m * 16 + (lane & 15);
  int c0 = q * 32 + (lane >> 4) * 8;
  f16x8 v;
#pragma unroll
  for (int j = 0; j < 8; ++j) v[j] = (_Float16)w[oc * 128 + c0 + j];
  ((f16x8*)Wf)[idx] = v;
}

__global__ __launch_bounds__(256) void wfB_kernel(      // offset_w [128][256], x2 on c>=128
    const float* __restrict__ w, _Float16* __restrict__ Wf)
{
  int idx = blockIdx.x * 256 + threadIdx.x;  // 8q*8m*64 = 4096
  int lane = idx & 63;
  int t = idx >> 6;
  int m = t & 7, q = t >> 3;
  int oc = m * 16 + (lane & 15);
  int c0 = q * 32 + (lane >> 4) * 8;
  float s = (q >= 4) ? 2.f : 1.f;
  f16x8 v;
#pragma unroll
  for (int j = 0; j < 8; ++j) v[j] = (_Float16)(w[oc * 256 + c0 + j] * s);
  ((f16x8*)Wf)[idx] = v;
}

// com_w packed oc-half-major & padded to 256 oc:
// WfP[((q*2+half)*8 + m)*64 + lane] (f16x8 units); oc = half*128+m*16+(lane&15),
// k-chunk: kk=q>>2, ic = (q&3)*32 + (lane>>4)*8 + j; oc>=216 -> 0.
__global__ __launch_bounds__(256) void wfP_kernel(
    const float* __restrict__ cw, _Float16* __restrict__ WfP)
{
  int idx = blockIdx.x * 256 + threadIdx.x;  // 36*2*8*64 = 36864 = 144*256
  int lane = idx & 63;
  int t = idx >> 6;          // (q*2+half)*8 + m
  int m = t & 7;
  int t2 = t >> 3;
  int half = t2 & 1, q = t2 >> 1;
  int kk = q >> 2;
  int ic0 = (q & 3) * 32 + (lane >> 4) * 8;
  int oc = half * 128 + m * 16 + (lane & 15);
  f16x8 v;
#pragma unroll
  for (int j = 0; j < 8; ++j) {
    float x = (oc < 216) ? cw[((size_t)oc * 128 + ic0 + j) * 9 + kk] : 0.f;
    v[j] = (_Float16)x;
  }
  ((f16x8*)WfP)[idx] = v;
}

__global__ __launch_bounds__(256) void wf2_kernel(      // dcn_w, r' = (g*9+k)*16+c
    const float* __restrict__ dw, _Float16* __restrict__ Wf2)
{
  int idx = blockIdx.x * 256 + threadIdx.x;  // 36*4*64 = 9216
  int lane = idx & 63;
  int t = idx >> 6;
  int m = t & 3, q = t >> 2;
  int oc = m * 16 + (lane & 15);
  f16x8 v;
#pragma unroll
  for (int j = 0; j < 8; ++j) {
    int rp = q * 32 + (lane >> 4) * 8 + j;
    int c = rp & 15, tt = rp >> 4;
    int g = tt / 9, k = tt % 9;
    v[j] = (_Float16)dw[((size_t)oc * 128 + g * 16 + c) * 9 + k];
  }
  ((f16x8*)Wf2)[idx] = v;
}

__global__ __launch_bounds__(256) void wfC_kernel(      // cat_w [128][64]
    const float* __restrict__ w, _Float16* __restrict__ Wf)
{
  int idx = blockIdx.x * 256 + threadIdx.x;  // 2q*8m*64 = 1024 = 4*256
  int lane = idx & 63;
  int t = idx >> 6;
  int m = t & 7, q = t >> 3;
  int oc = m * 16 + (lane & 15);
  int k0 = q * 32 + (lane >> 4) * 8;
  f16x8 v;
#pragma unroll
  for (int j = 0; j < 8; ++j) v[j] = (_Float16)w[oc * 64 + k0 + j];
  ((f16x8*)Wf)[idx] = v;
}

// ---------------------------------------------------------------------------
// fsm GEMM: arm = relu(fsm_w @ feat_l). Outputs arm f32 [oc][p] + armh f16 [p][oc].
// ---------------------------------------------------------------------------
__global__ __launch_bounds__(256) void fsm_gemm_kernel(
    const _Float16* __restrict__ flTh, const _Float16* __restrict__ WfA,
    float* __restrict__ arm, _Float16* __restrict__ armh)
{
  const int b    = blockIdx.y;
  const int tid  = threadIdx.x;
  const int wv   = tid >> 6;
  const int lane = tid & 63;
  const int px0  = blockIdx.x * 64 + wv * 16;
  const int pxl  = px0 + (lane & 15);

  f32x4 acc[8];
#pragma unroll
  for (int m = 0; m < 8; ++m) acc[m] = (f32x4){0.f, 0.f, 0.f, 0.f};

  const f16x8* Bp = (const f16x8*)flTh + (((size_t)b << 14) + pxl) * 16 + (lane >> 4);
  const f16x8* Ap = (const f16x8*)WfA + lane;

#pragma unroll
  for (int q = 0; q < 4; ++q) {
    f16x8 bf = Bp[q * 4];
#pragma unroll
    for (int m = 0; m < 8; ++m)
      acc[m] = __builtin_amdgcn_mfma_f32_16x16x32_f16(Ap[(q * 8 + m) * 64], bf, acc[m], 0, 0, 0);
  }

  const int r0 = (lane >> 4) * 4;
#pragma unroll
  for (int m = 0; m < 8; ++m) {
    f16x4 h;
#pragma unroll
    for (int r = 0; r < 4; ++r) {
      float v = relu_(acc[m][r]);
      arm[((size_t)(b * 128 + m * 16 + r0 + r) << 14) + pxl] = v;
      h[r] = (_Float16)v;
    }
    *(f16x4*)&armh[(((size_t)b << 14) + pxl) * 128 + m * 16 + r0] = h;
  }
}

// ---------------------------------------------------------------------------
// offset GEMM: offh = relu(offset_w @ [armh ; 2*featup]) in f16 [p][128].
// ---------------------------------------------------------------------------
__global__ __launch_bounds__(256) void off_gemm_kernel(
    const _Float16* __restrict__ armh, const _Float16* __restrict__ fsTh,
    const _Float16* __restrict__ WfB, _Float16* __restrict__ offh)
{
  const int b    = blockIdx.y;
  const int tid  = threadIdx.x;
  const int wv   = tid >> 6;
  const int lane = tid & 63;
  const int px0  = blockIdx.x * 64 + wv * 16;
  const int pxl  = px0 + (lane & 15);
  const int h = pxl >> 7, w = pxl & 127;
  const int pup = ((h >> 1) << 6) + (w >> 1);

  f32x4 acc[8];
#pragma unroll
  for (int m = 0; m < 8; ++m) acc[m] = (f32x4){0.f, 0.f, 0.f, 0.f};

  const f16x8* BpA = (const f16x8*)armh + (((size_t)b << 14) + pxl) * 16 + (lane >> 4);
  const f16x8* BpU = (const f16x8*)fsTh + (((size_t)b << 12) + pup) * 16 + (lane >> 4);
  const f16x8* Ap  = (const f16x8*)WfB + lane;

#pragma unroll
  for (int q = 0; q < 8; ++q) {
    f16x8 bf = (q < 4) ? BpA[q * 4] : BpU[(q - 4) * 4];
#pragma unroll
    for (int m = 0; m < 8; ++m)
      acc[m] = __builtin_amdgcn_mfma_f32_16x16x32_f16(Ap[(q * 8 + m) * 64], bf, acc[m], 0, 0, 0);
  }

  const int r0 = (lane >> 4) * 4;
#pragma unroll
  for (int m = 0; m < 8; ++m) {
    f16x4 hh;
#pragma unroll
    for (int r = 0; r < 4; ++r) hh[r] = (_Float16)relu_(acc[m][r]);
    *(f16x4*)&offh[(((size_t)b << 14) + pxl) * 128 + m * 16 + r0] = hh;
  }
}

// ---------------------------------------------------------------------------
// com GEMM (LDS-staged): om[b][oc][p], oc-halves across blocks, oc padded 256.
// Block = 4 waves x 16px = 64 px, one oc-half (8 m-tiles). Per K-chunk (8KB A):
// reg-prefetch next chunk, ds_write to LDS, 2-barrier, 8 ds_read + 8 MFMA.
// Grid (256, 2half, 2b) = 1024 blocks.
// ---------------------------------------------------------------------------
__global__ __launch_bounds__(256) void com_gemm_kernel(
    const _Float16* __restrict__ offh, const _Float16* __restrict__ WfP,
    const float* __restrict__ cb, float* __restrict__ om)
{
  const int b    = blockIdx.z;
  const int half = blockIdx.y;
  const int tid  = threadIdx.x;
  const int wv   = tid >> 6;
  const int lane = tid & 63;
  const int px0  = blockIdx.x * 64 + wv * 16;
  const int pxl  = px0 + (lane & 15);
  const int h = pxl >> 7, w = pxl & 127;

  __shared__ f16x8 As[512];   // 8 KB

  f32x4 acc[8];
#pragma unroll
  for (int m = 0; m < 8; ++m) acc[m] = (f32x4){0.f, 0.f, 0.f, 0.f};

  const f16x8* Bbase = (const f16x8*)offh + ((size_t)b << 14) * 16 + (lane >> 4);
  const f16x8* Wp    = (const f16x8*)WfP + half * 512 + tid * 2;
  const f16x8 zero = {(_Float16)0.f, (_Float16)0.f, (_Float16)0.f, (_Float16)0.f,
                      (_Float16)0.f, (_Float16)0.f, (_Float16)0.f, (_Float16)0.f};

  // prefetch chunk 0 into registers
  f16x8 r0 = Wp[0];
  f16x8 r1 = Wp[1];

#pragma unroll 1
  for (int t = 0; t < 36; ++t) {
    __syncthreads();                 // As free (prev chunk's reads done)
    As[tid * 2]     = r0;
    As[tid * 2 + 1] = r1;
    __syncthreads();                 // As ready
    if (t < 35) {                    // issue next-chunk prefetch (overlaps MFMA)
      r0 = Wp[(t + 1) * 1024];
      r1 = Wp[(t + 1) * 1024 + 1];
    }
    const int kk = t >> 2, ic4 = t & 3;
    const int hh = h + kk / 3 - 1;
    const int ww = w + kk % 3 - 1;
    const bool valid = ((unsigned)hh < 128u) && ((unsigned)ww < 128u);
    const int ps = valid ? ((hh << 7) + ww) : 0;
    f16x8 bf = Bbase[(size_t)ps * 16 + ic4 * 4];
    bf = valid ? bf : zero;
#pragma unroll
    for (int m = 0; m < 8; ++m) {
      f16x8 af = As[m * 64 + lane];
      acc[m] = __builtin_amdgcn_mfma_f32_16x16x32_f16(af, bf, acc[m], 0, 0, 0);
    }
  }

  const int r0i = (lane >> 4) * 4;
#pragma unroll
  for (int m = 0; m < 8; ++m) {
#pragma unroll
    for (int r = 0; r < 4; ++r) {
      int oc = half * 128 + m * 16 + r0i + r;
      if (oc < 216)
        om[((size_t)(b * 216 + oc) << 14) + pxl] = acc[m][r] + cb[oc];
    }
  }
}

// ---------------------------------------------------------------------------
// sample_kernel (unchanged, verified): bilinear gather -> valh f16 B-fragments.
// ---------------------------------------------------------------------------
__global__ __launch_bounds__(256) void sample_kernel(
    const _Float16* __restrict__ fsTh, const float* __restrict__ om,
    _Float16* __restrict__ valh)
{
  const int idx = blockIdx.x * 256 + threadIdx.x;   // 2,359,296
  const int px = idx & 16383;
  const int t  = idx >> 14;        // b*72 + g*9 + k
  const int k  = t % 9;
  const int g  = (t / 9) & 7;
  const int b  = t / 72;
  const int h = px >> 7, w = px & 127;

  const size_t omb = ((size_t)b * 216) << 14;
  const float offy = om[omb + ((size_t)(g * 18 + 2 * k) << 14) + px];
  const float offx = om[omb + ((size_t)(g * 18 + 2 * k + 1) << 14) + px];
  const float mraw = om[omb + ((size_t)(144 + g * 9 + k) << 14) + px];
  const float mv = 1.f / (1.f + __expf(-mraw));

  const float py  = (float)(h + k / 3 - 1) + offy;
  const float pxx = (float)(w + k % 3 - 1) + offx;
  const float y0f = floorf(py), x0f = floorf(pxx);
  const float ly = py - y0f, lx = pxx - x0f;
  const int y0 = (int)y0f, x0i = (int)x0f;
  const int y1 = y0 + 1, x1 = x0i + 1;

  const int y0c = min(max(y0, 0), 127), y1c = min(max(y1, 0), 127);
  const int x0c = min(max(x0i, 0), 127), x1c = min(max(x1, 0), 127);

  float w00 = (1.f - ly) * (1.f - lx) * mv;
  float w01 = (1.f - ly) * lx * mv;
  float w10 = ly * (1.f - lx) * mv;
  float w11 = ly * lx * mv;
  const bool vy0 = (unsigned)y0 < 128u, vy1 = (unsigned)y1 < 128u;
  const bool vx0 = (unsigned)x0i < 128u, vx1 = (unsigned)x1 < 128u;
  w00 = (vy0 && vx0) ? w00 : 0.f;
  w01 = (vy0 && vx1) ? w01 : 0.f;
  w10 = (vy1 && vx0) ? w10 : 0.f;
  w11 = (vy1 && vx1) ? w11 : 0.f;

  const _Float16* fb = fsTh + (((size_t)b << 12) << 7);
  const int a00 = ((((y0c >> 1) << 6) + (x0c >> 1)) << 7) + g * 16;
  const int a01 = ((((y0c >> 1) << 6) + (x1c >> 1)) << 7) + g * 16;
  const int a10 = ((((y1c >> 1) << 6) + (x0c >> 1)) << 7) + g * 16;
  const int a11 = ((((y1c >> 1) << 6) + (x1c >> 1)) << 7) + g * 16;

  f16x8 t00a = *(const f16x8*)(fb + a00), t00b = *(const f16x8*)(fb + a00 + 8);
  f16x8 t01a = *(const f16x8*)(fb + a01), t01b = *(const f16x8*)(fb + a01 + 8);
  f16x8 t10a = *(const f16x8*)(fb + a10), t10b = *(const f16x8*)(fb + a10 + 8);
  f16x8 t11a = *(const f16x8*)(fb + a11), t11b = *(const f16x8*)(fb + a11 + 8);

  f16x8 ov[2];
#pragma unroll
  for (int j = 0; j < 8; ++j) {
    ov[0][j] = (_Float16)(w00 * (float)t00a[j] + w01 * (float)t01a[j]
                        + w10 * (float)t10a[j] + w11 * (float)t11a[j]);
    ov[1][j] = (_Float16)(w00 * (float)t00b[j] + w01 * (float)t01b[j]
                        + w10 * (float)t10b[j] + w11 * (float)t11b[j]);
  }

  const int t9 = g * 9 + k;
  _Float16* dst = valh + (((size_t)(b * 36 + (t9 >> 1)) * 16384 + px) * 32 + (t9 & 1) * 16);
  ((f16x8*)dst)[0] = ov[0];
  ((f16x8*)dst)[1] = ov[1];
}

// ---------------------------------------------------------------------------
// dcn GEMM via MFMA f16; now writes alh f16 [b][p][64] for the cat GEMM.
// ---------------------------------------------------------------------------
__global__ __launch_bounds__(256) void dcn_gemm_kernel(
    const _Float16* __restrict__ valh, const _Float16* __restrict__ Wf2,
    const float* __restrict__ db, _Float16* __restrict__ alh)
{
  const int b    = blockIdx.y;
  const int tid  = threadIdx.x;
  const int wv   = tid >> 6;
  const int lane = tid & 63;
  const int px0  = blockIdx.x * 32 + (wv >> 1) * 16;
  const int m0   = (wv & 1) * 2;

  f32x4 acc[2];
  acc[0] = (f32x4){0.f, 0.f, 0.f, 0.f};
  acc[1] = (f32x4){0.f, 0.f, 0.f, 0.f};

  const f16x8* Bp = (const f16x8*)valh
      + ((size_t)(b * 36) * 16384 + px0 + (lane & 15)) * 4 + (lane >> 4);
  const f16x8* Ap = (const f16x8*)Wf2 + m0 * 64 + lane;

#pragma unroll 2
  for (int q = 0; q < 36; ++q) {
    f16x8 bf = Bp[(size_t)q * 65536];
    const f16x8* ap = Ap + q * (4 * 64);
    f16x8 a0 = ap[0];
    f16x8 a1 = ap[64];
    acc[0] = __builtin_amdgcn_mfma_f32_16x16x32_f16(a0, bf, acc[0], 0, 0, 0);
    acc[1] = __builtin_amdgcn_mfma_f32_16x16x32_f16(a1, bf, acc[1], 0, 0, 0);
  }

  const int pxl = px0 + (lane & 15);
  const int r0  = (lane >> 4) * 4;
#pragma unroll
  for (int mm = 0; mm < 2; ++mm) {
    f16x4 hv;
#pragma unroll
    for (int r = 0; r < 4; ++r) {
      int oc = (m0 + mm) * 16 + r0 + r;
      hv[r] = (_Float16)relu_(acc[mm][r] + db[oc]);
    }
    *(f16x4*)&alh[(((size_t)b << 14) + pxl) * 64 + (m0 + mm) * 16 + r0] = hv;
  }
}

// ---------------------------------------------------------------------------
// cat GEMM: out[b][oc][p] = relu(cat_w @ feat_align) + arm. K=64 (2 chunks).
// ---------------------------------------------------------------------------
__global__ __launch_bounds__(256) void cat_gemm_kernel(
    const _Float16* __restrict__ alh, const _Float16* __restrict__ WfC,
    const float* __restrict__ arm, float* __restrict__ out)
{
  const int b    = blockIdx.y;
  const int tid  = threadIdx.x;
  const int wv   = tid >> 6;
  const int lane = tid & 63;
  const int px0  = blockIdx.x * 64 + wv * 16;
  const int pxl  = px0 + (lane & 15);

  f32x4 acc[8];
#pragma unroll
  for (int m = 0; m < 8; ++m) acc[m] = (f32x4){0.f, 0.f, 0.f, 0.f};

  const f16x8* Bp = (const f16x8*)alh + (((size_t)b << 14) + pxl) * 8 + (lane >> 4);
  const f16x8* Ap = (const f16x8*)WfC + lane;

#pragma unroll
  for (int q = 0; q < 2; ++q) {
    f16x8 bf = Bp[q * 4];
#pragma unroll
    for (int m = 0; m < 8; ++m)
      acc[m] = __builtin_amdgcn_mfma_f32_16x16x32_f16(Ap[(q * 8 + m) * 64], bf, acc[m], 0, 0, 0);
  }

  const int r0 = (lane >> 4) * 4;
#pragma unroll
  for (int m = 0; m < 8; ++m) {
#pragma unroll
    for (int r = 0; r < 4; ++r) {
      int oc = m * 16 + r0 + r;
      size_t a = ((size_t)(b * 128 + oc) << 14) + pxl;
      out[a] = relu_(acc[m][r]) + arm[a];
    }
  }
}

// ---------------------------------------------------------------------------
// FALLBACK path kernels (small ws): round-1 versions
// ---------------------------------------------------------------------------
__global__ __launch_bounds__(256) void com_conv_kernel(
    const float* __restrict__ x, const float* __restrict__ cw,
    const float* __restrict__ cb, float* __restrict__ om)
{
  const int b    = blockIdx.z;
  const int ocg  = blockIdx.y;
  const int tile = blockIdx.x;
  const int th = (tile >> 2) * 32, tw = (tile & 3) * 32;
  const int tid = threadIdx.x;
  const int lw = (tid & 7) * 4;
  const int lh = tid >> 3;

  __shared__ float Xs[8 * 34 * 34];

  float acc[8][4];
#pragma unroll
  for (int a = 0; a < 8; ++a)
#pragma unroll
    for (int p = 0; p < 4; ++p) acc[a][p] = 0.f;

  for (int cc = 0; cc < 128; cc += 8) {
    __syncthreads();
    for (int idx = tid; idx < 8 * 1156; idx += 256) {
      int ic  = idx / 1156;
      int rem = idx - ic * 1156;
      int yy  = rem / 34;
      int xx  = rem - yy * 34;
      int gh = th + yy - 1, gw = tw + xx - 1;
      float v = 0.f;
      if ((unsigned)gh < 128u && (unsigned)gw < 128u)
        v = x[((size_t)(b * 128 + cc + ic) << 14) + (gh << 7) + gw];
      Xs[idx] = v;
    }
    __syncthreads();
#pragma unroll 1
    for (int ic = 0; ic < 8; ++ic) {
      float xr[3][6];
#pragma unroll
      for (int ky = 0; ky < 3; ++ky)
#pragma unroll
        for (int xx = 0; xx < 6; ++xx)
          xr[ky][xx] = Xs[ic * 1156 + (lh + ky) * 34 + lw + xx];
      const float* wp = cw + ((size_t)(ocg * 8) * 128 + (cc + ic)) * 9;
#pragma unroll
      for (int a = 0; a < 8; ++a) {
        const float* w9 = wp + a * 1152;
#pragma unroll
        for (int ky = 0; ky < 3; ++ky)
#pragma unroll
          for (int kx = 0; kx < 3; ++kx) {
            float wv = w9[ky * 3 + kx];
#pragma unroll
            for (int p = 0; p < 4; ++p)
              acc[a][p] = fmaf(wv, xr[ky][kx + p], acc[a][p]);
          }
      }
    }
  }

#pragma unroll
  for (int a = 0; a < 8; ++a) {
    int oc = ocg * 8 + a;
    float bv = cb[oc];
    float4 r = make_float4(acc[a][0] + bv, acc[a][1] + bv,
                           acc[a][2] + bv, acc[a][3] + bv);
    *(float4*)(om + ((size_t)(b * 216 + oc) << 14) + ((th + lh) << 7) + tw + lw) = r;
  }
}

__global__ __launch_bounds__(256) void wt_kernel(const float* __restrict__ dw,
                                                 float* __restrict__ wT)
{
  int idx = blockIdx.x * 256 + threadIdx.x;
  int o    = idx & 63;
  int rest = idx >> 6;
  int k    = rest % 9;
  int gc   = rest / 9;
  wT[idx] = dw[(o * 128 + gc) * 9 + k];
}

__global__ __launch_bounds__(256) void dcn_kernel(
    const float* __restrict__ fs, const float* __restrict__ om,
    const float* __restrict__ wT, const float* __restrict__ db,
    float* __restrict__ al)
{
  const int b   = blockIdx.y;
  const int p0  = blockIdx.x * 32;
  const int tid = threadIdx.x;
  const int px  = tid & 31;
  const int g   = tid >> 5;
  const int p = p0 + px;
  const int h = p >> 7, w = p & 127;

  float acc[64];
#pragma unroll
  for (int o = 0; o < 64; ++o) acc[o] = 0.f;

  const size_t omb = ((size_t)b * 216) << 14;
  const float* fsg = fs + (((size_t)(b * 128 + g * 16)) << 12);
  const float* wg  = wT + g * (16 * 9 * 64);

#pragma unroll 1
  for (int k = 0; k < 9; ++k) {
    float offy = om[omb + ((size_t)(g * 18 + 2 * k) << 14) + p];
    float offx = om[omb + ((size_t)(g * 18 + 2 * k + 1) << 14) + p];
    float mraw = om[omb + ((size_t)(144 + g * 9 + k) << 14) + p];
    float mv = 1.f / (1.f + __expf(-mraw));

    float py  = (float)(h + k / 3 - 1) + offy;
    float pxx = (float)(w + k % 3 - 1) + offx;
    float y0f = floorf(py), x0f = floorf(pxx);
    float ly = py - y0f, lx = pxx - x0f;
    int y0 = (int)y0f, x0i = (int)x0f;
    int y1 = y0 + 1, x1 = x0i + 1;

    int y0c = min(max(y0, 0), 127), y1c = min(max(y1, 0), 127);
    int x0c = min(max(x0i, 0), 127), x1c = min(max(x1, 0), 127);
    int ry0 = (y0c >> 1) << 6, ry1 = (y1c >> 1) << 6;
    int cx0 = x0c >> 1, cx1 = x1c >> 1;

    float w00 = (1.f - ly) * (1.f - lx) * mv;
    float w01 = (1.f - ly) * lx * mv;
    float w10 = ly * (1.f - lx) * mv;
    float w11 = ly * lx * mv;
    bool vy0 = (unsigned)y0 < 128u, vy1 = (unsigned)y1 < 128u;
    bool vx0 = (unsigned)x0i < 128u, vx1 = (unsigned)x1 < 128u;
    w00 = (vy0 && vx0) ? w00 : 0.f;
    w01 = (vy0 && vx1) ? w01 : 0.f;
    w10 = (vy1 && vx0) ? w10 : 0.f;
    w11 = (vy1 && vx1) ? w11 : 0.f;

#pragma unroll 1
    for (int c = 0; c < 16; ++c) {
      const float* fc = fsg + (c << 12);
      float v00 = fc[ry0 + cx0];
      float v01 = fc[ry0 + cx1];
      float v10 = fc[ry1 + cx0];
      float v11 = fc[ry1 + cx1];
      float v = w00 * v00 + w01 * v01 + w10 * v10 + w11 * v11;
      const float* wp = wg + (c * 9 + k) * 64;
#pragma unroll
      for (int oq = 0; oq < 16; ++oq) {
        float4 w4 = *(const float4*)(wp + oq * 4);
        acc[oq * 4 + 0] = fmaf(v, w4.x, acc[oq * 4 + 0]);
        acc[oq * 4 + 1] = fmaf(v, w4.y, acc[oq * 4 + 1]);
        acc[oq * 4 + 2] = fmaf(v, w4.z, acc[oq * 4 + 2]);
        acc[oq * 4 + 3] = fmaf(v, w4.w, acc[oq * 4 + 3]);
      }
    }
  }

  __shared__ float red[256][17];
  const int px2 = tid & 31;
  const int og  = tid >> 5;
#pragma unroll
  for (int r = 0; r < 4; ++r) {
    __syncthreads();
#pragma unroll
    for (int j = 0; j < 16; ++j) red[tid][j] = acc[r * 16 + j];
    __syncthreads();
#pragma unroll
    for (int jj = 0; jj < 2; ++jj) {
      int ol = og * 2 + jj;
      float s = 0.f;
#pragma unroll
      for (int gg = 0; gg < 8; ++gg) s += red[gg * 32 + px2][ol];
      int oc = r * 16 + ol;
      s += db[oc];
      al[((size_t)(b * 64 + oc) << 14) + p0 + px2] = fmaxf(s, 0.f);
    }
  }
}

// ---------------------------------------------------------------------------
extern "C" void kernel_launch(void* const* d_in, const int* in_sizes, int n_in,
                              void* d_out, int out_size, void* d_ws, size_t ws_size,
                              hipStream_t stream)
{
  const float* feat_l   = (const float*)d_in[0];
  const float* feat_s   = (const float*)d_in[1];
  const float* fsm_w    = (const float*)d_in[2];
  const float* offset_w = (const float*)d_in[3];
  const float* com_w    = (const float*)d_in[4];
  const float* com_b    = (const float*)d_in[5];
  const float* dcn_w    = (const float*)d_in[6];
  const float* dcn_b    = (const float*)d_in[7];
  const float* cat_w    = (const float*)d_in[8];
  float* out = (float*)d_out;
  float* ws  = (float*)d_ws;

  const size_t NEED = (size_t)(4194304 + 7077888 + 2097152 + 1048576 + 37748736) * 4;

  if (ws_size >= NEED) {
    // float-offset layout (all disjoint, fits prior NEED = 157 MB)
    float* arm      = ws;                          // 4,194,304 f32
    float* om       = ws + 4194304;                // 7,077,888 f32
    _Float16* alh   = (_Float16*)(ws + 11272192);  // 2,097,152 f16 (1,048,576 fl)
    _Float16* Wf2   = (_Float16*)(ws + 12320768);  // 73,728 f16
    _Float16* WfC   = (_Float16*)(ws + 12357632);  // 8,192 f16
    _Float16* fsTh  = (_Float16*)(ws + 13369344);  // 1,048,576 f16
    _Float16* flTh  = (_Float16*)(ws + 13893632);  // 4,194,304 f16
    _Float16* armh  = (_Float16*)(ws + 15990784);  // 4,194,304 f16
    _Float16* offh  = (_Float16*)(ws + 18087936);  // 4,194,304 f16
    _Float16* valh  = (_Float16*)(ws + 20185088);  // 37,748,736 f16
    _Float16* WfA   = (_Float16*)(ws + 39059456);  // 16,384 f16
    _Float16* WfB   = (_Float16*)(ws + 39067648);  // 32,768 f16
    _Float16* WfP   = (_Float16*)(ws + 39084032);  // 294,912 f16 (ends 39,231,488)

    hipLaunchKernelGGL(wfA_kernel, dim3(8), dim3(256), 0, stream, fsm_w, WfA);
    hipLaunchKernelGGL(wfB_kernel, dim3(16), dim3(256), 0, stream, offset_w, WfB);
    hipLaunchKernelGGL(wfP_kernel, dim3(144), dim3(256), 0, stream, com_w, WfP);
    hipLaunchKernelGGL(wf2_kernel, dim3(36), dim3(256), 0, stream, dcn_w, Wf2);
    hipLaunchKernelGGL(wfC_kernel, dim3(4), dim3(256), 0, stream, cat_w, WfC);
    hipLaunchKernelGGL(t2h_kernel, dim3(512, 4, 2), dim3(256), 0, stream,
                       feat_l, flTh, 16384);
    hipLaunchKernelGGL(t2h_kernel, dim3(128, 4, 2), dim3(256), 0, stream,
                       feat_s, fsTh, 4096);
    hipLaunchKernelGGL(fsm_gemm_kernel, dim3(256, 2), dim3(256), 0, stream,
                       flTh, WfA, arm, armh);
    hipLaunchKernelGGL(off_gemm_kernel, dim3(256, 2), dim3(256), 0, stream,
                       armh, fsTh, WfB, offh);
    hipLaunchKernelGGL(com_gemm_kernel, dim3(256, 2, 2), dim3(256), 0, stream,
                       offh, WfP, com_b, om);
    hipLaunchKernelGGL(sample_kernel, dim3(9216), dim3(256), 0, stream,
                       fsTh, om, valh);
    hipLaunchKernelGGL(dcn_gemm_kernel, dim3(512, 2), dim3(256), 0, stream,
                       valh, Wf2, dcn_b, alh);
    hipLaunchKernelGGL(cat_gemm_kernel, dim3(256, 2), dim3(256), 0, stream,
                       alh, WfC, arm, out);
  } else {
    float* arm = ws;
    float* off = ws + 4194304;
    float* om  = ws + 8388608;
    float* al  = ws + 15466496;
    float* wT  = ws + 17563648;

    hipLaunchKernelGGL(wt_kernel, dim3(288), dim3(256), 0, stream, dcn_w, wT);
    hipLaunchKernelGGL((conv1x1_kernel<0, 128>), dim3(256, 2), dim3(256), 0, stream,
                       feat_l, nullptr, fsm_w, arm);
    hipLaunchKernelGGL((conv1x1_kernel<1, 256>), dim3(256, 2), dim3(256), 0, stream,
                       arm, feat_s, offset_w, off);
    hipLaunchKernelGGL(com_conv_kernel, dim3(16, 27, 2), dim3(256), 0, stream,
                       off, com_w, com_b, om);
    hipLaunchKernelGGL(dcn_kernel, dim3(512, 2), dim3(256), 0, stream,
                       feat_s, om, wT, dcn_b, al);
    hipLaunchKernelGGL((conv1x1_kernel<2, 64>), dim3(256, 2), dim3(256), 0, stream,
                       al, arm, cat_w, out);
  }
}

// Round 7
// 225.596 us; speedup vs baseline: 3.8261x; 1.0002x over previous
//
#include <hip/hip_runtime.h>
#include <cstdint>
#include <cstddef>

// Problem constants
// B=2, C=128, H=W=128, Hs=Ws=64, DG=8, KK=9, CG=16, COUT_DCN=64, HW=16384

typedef _Float16 f16x8 __attribute__((ext_vector_type(8)));
typedef _Float16 f16x4 __attribute__((ext_vector_type(4)));
typedef float    f32x4 __attribute__((ext_vector_type(4)));

__device__ __forceinline__ float relu_(float x) { return fmaxf(x, 0.f); }

// ---------------------------------------------------------------------------
// conv1x1 (fp32, LDS-tiled) — FALLBACK path only.
// ---------------------------------------------------------------------------
template<int MODE, int CIN>
__global__ __launch_bounds__(256) void conv1x1_kernel(
    const float* __restrict__ in1, const float* __restrict__ in2,
    const float* __restrict__ Wm, float* __restrict__ out)
{
  constexpr int IN1C = (MODE == 2) ? 64 : 128;
  const int b  = blockIdx.y;
  const int p0 = blockIdx.x * 64;
  const int tid = threadIdx.x;
  const int tx = tid & 7;
  const int ty = tid >> 3;

  __shared__ float Xs[16][64];
  __shared__ float Wt[16][128];

  float acc[4][8];
#pragma unroll
  for (int i = 0; i < 4; ++i)
#pragma unroll
    for (int j = 0; j < 8; ++j) acc[i][j] = 0.f;

  const int cS  = tid >> 4;
  const int pxS = (tid & 15) * 4;
  const int ocS = (tid & 15) * 8;

  for (int cc = 0; cc < CIN; cc += 16) {
    __syncthreads();
    {
      int gc = cc + cS;
      float4 v;
      if (MODE == 1 && gc >= 128) {
        int sc = gc - 128;
        float t[4];
#pragma unroll
        for (int j = 0; j < 4; ++j) {
          int pp = p0 + pxS + j;
          int hh = pp >> 7, ww = pp & 127;
          t[j] = 2.f * in2[((size_t)(b * 128 + sc) << 12) + ((hh >> 1) << 6) + (ww >> 1)];
        }
        v = make_float4(t[0], t[1], t[2], t[3]);
      } else {
        v = *(const float4*)(in1 + ((size_t)(b * IN1C + gc) << 14) + p0 + pxS);
      }
      *(float4*)&Xs[cS][pxS] = v;
#pragma unroll
      for (int j = 0; j < 8; ++j)
        Wt[cS][ocS + j] = Wm[(ocS + j) * CIN + cc + cS];
    }
    __syncthreads();
#pragma unroll
    for (int c = 0; c < 16; ++c) {
      float4 wv = *(const float4*)&Wt[c][ty * 4];
      float4 x0 = *(const float4*)&Xs[c][tx * 8];
      float4 x1 = *(const float4*)&Xs[c][tx * 8 + 4];
      float xs[8] = {x0.x, x0.y, x0.z, x0.w, x1.x, x1.y, x1.z, x1.w};
      float wf[4] = {wv.x, wv.y, wv.z, wv.w};
#pragma unroll
      for (int i = 0; i < 4; ++i)
#pragma unroll
        for (int j = 0; j < 8; ++j)
          acc[i][j] = fmaf(wf[i], xs[j], acc[i][j]);
    }
  }

#pragma unroll
  for (int i = 0; i < 4; ++i) {
    int oc = ty * 4 + i;
    size_t base = ((size_t)(b * 128 + oc) << 14) + p0 + tx * 8;
    float r[8];
#pragma unroll
    for (int j = 0; j < 8; ++j) r[j] = relu_(acc[i][j]);
    if (MODE == 2) {
#pragma unroll
      for (int j = 0; j < 8; ++j) r[j] += in2[base + j];
    }
    *(float4*)(out + base)     = make_float4(r[0], r[1], r[2], r[3]);
    *(float4*)(out + base + 4) = make_float4(r[4], r[5], r[6], r[7]);
  }
}

// ---------------------------------------------------------------------------
// t2h2: fused transpose of feat_l and feat_s: [b][128][HW] f32 -> [b][HW][128] f16
// blockIdx.x < 512 -> feat_l (HW=16384); else feat_s (HW=4096).
// ---------------------------------------------------------------------------
__global__ __launch_bounds__(256) void t2h2_kernel(
    const float* __restrict__ fl, const float* __restrict__ fs,
    _Float16* __restrict__ flTh, _Float16* __restrict__ fsTh)
{
  const int bx = blockIdx.x;
  const float* src;
  _Float16* dst;
  int HW, p0;
  if (bx < 512) { src = fl; dst = flTh; HW = 16384; p0 = bx * 32; }
  else          { src = fs; dst = fsTh; HW = 4096;  p0 = (bx - 512) * 32; }
  const int b  = blockIdx.z;
  const int c0 = blockIdx.y * 32;
  const int tid = threadIdx.x;
  __shared__ float T[32][33];
  {
    int pxl = tid & 31, cy = tid >> 5;
#pragma unroll
    for (int j = 0; j < 4; ++j) {
      int c = cy + j * 8;
      T[c][pxl] = src[((size_t)(b * 128 + c0 + c)) * HW + p0 + pxl];
    }
  }
  __syncthreads();
  {
    int cq = tid & 7, pr = tid >> 3;
    f16x4 v;
#pragma unroll
    for (int e = 0; e < 4; ++e) v[e] = (_Float16)T[cq * 4 + e][pr];
    *(f16x4*)&dst[(((size_t)b * HW) + p0 + pr) * 128 + c0 + cq * 4] = v;
  }
}

// ---------------------------------------------------------------------------
// wfall: all 5 weight packs in one launch. Block ranges:
// [0,8) WfA | [8,24) WfB | [24,168) WfP | [168,204) Wf2 | [204,208) WfC
// ---------------------------------------------------------------------------
__global__ __launch_bounds__(256) void wfall_kernel(
    const float* __restrict__ fsm_w, const float* __restrict__ offset_w,
    const float* __restrict__ com_w, const float* __restrict__ dcn_w,
    const float* __restrict__ cat_w,
    _Float16* __restrict__ WfA, _Float16* __restrict__ WfB,
    _Float16* __restrict__ WfP, _Float16* __restrict__ Wf2,
    _Float16* __restrict__ WfC)
{
  const int bid = blockIdx.x;
  if (bid < 8) {                         // WfA: fsm_w [128][128]
    int idx = bid * 256 + threadIdx.x;
    int lane = idx & 63;
    int t = idx >> 6;
    int m = t & 7, q = t >> 3;
    int oc = m * 16 + (lane & 15);
    int c0 = q * 32 + (lane >> 4) * 8;
    f16x8 v;
#pragma unroll
    for (int j = 0; j < 8; ++j) v[j] = (_Float16)fsm_w[oc * 128 + c0 + j];
    ((f16x8*)WfA)[idx] = v;
  } else if (bid < 24) {                 // WfB: offset_w [128][256], x2 on c>=128
    int idx = (bid - 8) * 256 + threadIdx.x;
    int lane = idx & 63;
    int t = idx >> 6;
    int m = t & 7, q = t >> 3;
    int oc = m * 16 + (lane & 15);
    int c0 = q * 32 + (lane >> 4) * 8;
    float s = (q >= 4) ? 2.f : 1.f;
    f16x8 v;
#pragma unroll
    for (int j = 0; j < 8; ++j) v[j] = (_Float16)(offset_w[oc * 256 + c0 + j] * s);
    ((f16x8*)WfB)[idx] = v;
  } else if (bid < 168) {                // WfP: com_w, oc-half-major, pad 256
    int idx = (bid - 24) * 256 + threadIdx.x;
    int lane = idx & 63;
    int t = idx >> 6;
    int m = t & 7;
    int t2 = t >> 3;
    int half = t2 & 1, q = t2 >> 1;
    int kk = q >> 2;
    int ic0 = (q & 3) * 32 + (lane >> 4) * 8;
    int oc = half * 128 + m * 16 + (lane & 15);
    f16x8 v;
#pragma unroll
    for (int j = 0; j < 8; ++j) {
      float x = (oc < 216) ? com_w[((size_t)oc * 128 + ic0 + j) * 9 + kk] : 0.f;
      v[j] = (_Float16)x;
    }
    ((f16x8*)WfP)[idx] = v;
  } else if (bid < 204) {                // Wf2: dcn_w, r' = (g*9+k)*16+c
    int idx = (bid - 168) * 256 + threadIdx.x;
    int lane = idx & 63;
    int t = idx >> 6;
    int m = t & 3, q = t >> 2;
    int oc = m * 16 + (lane & 15);
    f16x8 v;
#pragma unroll
    for (int j = 0; j < 8; ++j) {
      int rp = q * 32 + (lane >> 4) * 8 + j;
      int c = rp & 15, tt = rp >> 4;
      int g = tt / 9, k = tt % 9;
      v[j] = (_Float16)dcn_w[((size_t)oc * 128 + g * 16 + c) * 9 + k];
    }
    ((f16x8*)Wf2)[idx] = v;
  } else {                               // WfC: cat_w [128][64]
    int idx = (bid - 204) * 256 + threadIdx.x;
    int lane = idx & 63;
    int t = idx >> 6;
    int m = t & 7, q = t >> 3;
    int oc = m * 16 + (lane & 15);
    int k0 = q * 32 + (lane >> 4) * 8;
    f16x8 v;
#pragma unroll
    for (int j = 0; j < 8; ++j) v[j] = (_Float16)cat_w[oc * 64 + k0 + j];
    ((f16x8*)WfC)[idx] = v;
  }
}

// ---------------------------------------------------------------------------
// fsm GEMM: arm = relu(fsm_w @ feat_l). Outputs arm f32 [oc][p] + armh f16 [p][oc].
// ---------------------------------------------------------------------------
__global__ __launch_bounds__(256) void fsm_gemm_kernel(
    const _Float16* __restrict__ flTh, const _Float16* __restrict__ WfA,
    float* __restrict__ arm, _Float16* __restrict__ armh)
{
  const int b    = blockIdx.y;
  const int tid  = threadIdx.x;
  const int wv   = tid >> 6;
  const int lane = tid & 63;
  const int px0  = blockIdx.x * 64 + wv * 16;
  const int pxl  = px0 + (lane & 15);

  f32x4 acc[8];
#pragma unroll
  for (int m = 0; m < 8; ++m) acc[m] = (f32x4){0.f, 0.f, 0.f, 0.f};

  const f16x8* Bp = (const f16x8*)flTh + (((size_t)b << 14) + pxl) * 16 + (lane >> 4);
  const f16x8* Ap = (const f16x8*)WfA + lane;

#pragma unroll
  for (int q = 0; q < 4; ++q) {
    f16x8 bf = Bp[q * 4];
#pragma unroll
    for (int m = 0; m < 8; ++m)
      acc[m] = __builtin_amdgcn_mfma_f32_16x16x32_f16(Ap[(q * 8 + m) * 64], bf, acc[m], 0, 0, 0);
  }

  const int r0 = (lane >> 4) * 4;
#pragma unroll
  for (int m = 0; m < 8; ++m) {
    f16x4 h;
#pragma unroll
    for (int r = 0; r < 4; ++r) {
      float v = relu_(acc[m][r]);
      arm[((size_t)(b * 128 + m * 16 + r0 + r) << 14) + pxl] = v;
      h[r] = (_Float16)v;
    }
    *(f16x4*)&armh[(((size_t)b << 14) + pxl) * 128 + m * 16 + r0] = h;
  }
}

// ---------------------------------------------------------------------------
// offset GEMM: offh = relu(offset_w @ [armh ; 2*featup]) in f16 [p][128].
// ---------------------------------------------------------------------------
__global__ __launch_bounds__(256) void off_gemm_kernel(
    const _Float16* __restrict__ armh, const _Float16* __restrict__ fsTh,
    const _Float16* __restrict__ WfB, _Float16* __restrict__ offh)
{
  const int b    = blockIdx.y;
  const int tid  = threadIdx.x;
  const int wv   = tid >> 6;
  const int lane = tid & 63;
  const int px0  = blockIdx.x * 64 + wv * 16;
  const int pxl  = px0 + (lane & 15);
  const int h = pxl >> 7, w = pxl & 127;
  const int pup = ((h >> 1) << 6) + (w >> 1);

  f32x4 acc[8];
#pragma unroll
  for (int m = 0; m < 8; ++m) acc[m] = (f32x4){0.f, 0.f, 0.f, 0.f};

  const f16x8* BpA = (const f16x8*)armh + (((size_t)b << 14) + pxl) * 16 + (lane >> 4);
  const f16x8* BpU = (const f16x8*)fsTh + (((size_t)b << 12) + pup) * 16 + (lane >> 4);
  const f16x8* Ap  = (const f16x8*)WfB + lane;

#pragma unroll
  for (int q = 0; q < 8; ++q) {
    f16x8 bf = (q < 4) ? BpA[q * 4] : BpU[(q - 4) * 4];
#pragma unroll
    for (int m = 0; m < 8; ++m)
      acc[m] = __builtin_amdgcn_mfma_f32_16x16x32_f16(Ap[(q * 8 + m) * 64], bf, acc[m], 0, 0, 0);
  }

  const int r0 = (lane >> 4) * 4;
#pragma unroll
  for (int m = 0; m < 8; ++m) {
    f16x4 hh;
#pragma unroll
    for (int r = 0; r < 4; ++r) hh[r] = (_Float16)relu_(acc[m][r]);
    *(f16x4*)&offh[(((size_t)b << 14) + pxl) * 128 + m * 16 + r0] = hh;
  }
}

// ---------------------------------------------------------------------------
// com GEMM (LDS-staged, depth-2 B prefetch): om[b][oc][p], oc padded 256.
// Grid (256, 2half, 2b). Per K-chunk: A reg->LDS (2-barrier), B prefetched
// 2 chunks ahead (rotating bfA/bfB, static indices), 8 MFMA.
// ---------------------------------------------------------------------------
__global__ __launch_bounds__(256) void com_gemm_kernel(
    const _Float16* __restrict__ offh, const _Float16* __restrict__ WfP,
    const float* __restrict__ cb, float* __restrict__ om)
{
  const int b    = blockIdx.z;
  const int half = blockIdx.y;
  const int tid  = threadIdx.x;
  const int lane = tid & 63;
  const int px0  = blockIdx.x * 64 + (tid >> 6) * 16;
  const int pxl  = px0 + (lane & 15);
  const int h = pxl >> 7, w = pxl & 127;

  __shared__ f16x8 As[512];   // 8 KB

  f32x4 acc[8];
#pragma unroll
  for (int m = 0; m < 8; ++m) acc[m] = (f32x4){0.f, 0.f, 0.f, 0.f};

  const f16x8* Bbase = (const f16x8*)offh + ((size_t)b << 14) * 16 + (lane >> 4);
  const f16x8* Wp    = (const f16x8*)WfP + half * 512 + tid * 2;
  const f16x8 zero = {(_Float16)0.f, (_Float16)0.f, (_Float16)0.f, (_Float16)0.f,
                      (_Float16)0.f, (_Float16)0.f, (_Float16)0.f, (_Float16)0.f};

  auto loadB = [&](int t) -> f16x8 {
    const int kk = t >> 2, ic4 = t & 3;
    const int hh = h + kk / 3 - 1;
    const int ww = w + kk % 3 - 1;
    const bool valid = ((unsigned)hh < 128u) && ((unsigned)ww < 128u);
    const int ps = valid ? ((hh << 7) + ww) : 0;
    f16x8 bf = Bbase[(size_t)ps * 16 + ic4 * 4];
    return valid ? bf : zero;
  };

  f16x8 rA0 = Wp[0], rA1 = Wp[1];
  f16x8 bfA = loadB(0), bfB = loadB(1);

#pragma unroll 1
  for (int tt = 0; tt < 18; ++tt) {
    const int t0 = tt * 2;
    // ---- chunk t0 (uses bfA)
    __syncthreads();
    As[tid * 2] = rA0; As[tid * 2 + 1] = rA1;
    __syncthreads();
    rA0 = Wp[(t0 + 1) * 1024]; rA1 = Wp[(t0 + 1) * 1024 + 1];   // t0+1 <= 35
    {
      f16x8 bu = bfA;
      if (t0 + 2 < 36) bfA = loadB(t0 + 2);
#pragma unroll
      for (int m = 0; m < 8; ++m)
        acc[m] = __builtin_amdgcn_mfma_f32_16x16x32_f16(As[m * 64 + lane], bu, acc[m], 0, 0, 0);
    }
    // ---- chunk t0+1 (uses bfB)
    __syncthreads();
    As[tid * 2] = rA0; As[tid * 2 + 1] = rA1;
    __syncthreads();
    if (t0 + 2 < 36) { rA0 = Wp[(t0 + 2) * 1024]; rA1 = Wp[(t0 + 2) * 1024 + 1]; }
    {
      f16x8 bu = bfB;
      if (t0 + 3 < 36) bfB = loadB(t0 + 3);
#pragma unroll
      for (int m = 0; m < 8; ++m)
        acc[m] = __builtin_amdgcn_mfma_f32_16x16x32_f16(As[m * 64 + lane], bu, acc[m], 0, 0, 0);
    }
  }

  const int r0i = (lane >> 4) * 4;
#pragma unroll
  for (int m = 0; m < 8; ++m) {
#pragma unroll
    for (int r = 0; r < 4; ++r) {
      int oc = half * 128 + m * 16 + r0i + r;
      if (oc < 216)
        om[((size_t)(b * 216 + oc) << 14) + pxl] = acc[m][r] + cb[oc];
    }
  }
}

// ---------------------------------------------------------------------------
// sample_kernel: one thread per (b,g,k, 4 consecutive px). om loads as float4;
// per px: bilinear 16ch gather from fsTh, mask, write f16 B-fragments to valh.
// ---------------------------------------------------------------------------
__global__ __launch_bounds__(256) void sample_kernel(
    const _Float16* __restrict__ fsTh, const float* __restrict__ om,
    _Float16* __restrict__ valh)
{
  const int idx = blockIdx.x * 256 + threadIdx.x;   // B*72*4096 = 589,824
  const int px4 = (idx & 4095) << 2;
  const int t  = idx >> 12;        // b*72 + g*9 + k
  const int k  = t % 9;
  const int g  = (t / 9) & 7;
  const int b  = t / 72;

  const size_t omb = ((size_t)b * 216) << 14;
  const float4 oy4 = *(const float4*)(om + omb + ((size_t)(g * 18 + 2 * k) << 14) + px4);
  const float4 ox4 = *(const float4*)(om + omb + ((size_t)(g * 18 + 2 * k + 1) << 14) + px4);
  const float4 mr4 = *(const float4*)(om + omb + ((size_t)(144 + g * 9 + k) << 14) + px4);
  const float oys[4] = {oy4.x, oy4.y, oy4.z, oy4.w};
  const float oxs[4] = {ox4.x, ox4.y, ox4.z, ox4.w};
  const float mrs[4] = {mr4.x, mr4.y, mr4.z, mr4.w};

  const _Float16* fb = fsTh + ((size_t)b << 19);
  const int t9 = g * 9 + k;
  _Float16* dstb = valh + (((size_t)(b * 36 + (t9 >> 1)) * 16384 + px4) * 32 + (t9 & 1) * 16);

  const int kdy = k / 3 - 1, kdx = k % 3 - 1;
  const int h = px4 >> 7, w0 = px4 & 127;   // 4-aligned, same row for i=0..3
  const int gbase = g * 16;

#pragma unroll
  for (int i = 0; i < 4; ++i) {
    const float mv = 1.f / (1.f + __expf(-mrs[i]));
    const float py  = (float)(h + kdy) + oys[i];
    const float pxx = (float)(w0 + i + kdx) + oxs[i];
    const float y0f = floorf(py), x0f = floorf(pxx);
    const float ly = py - y0f, lx = pxx - x0f;
    const int y0 = (int)y0f, x0i = (int)x0f;
    const int y1 = y0 + 1, x1 = x0i + 1;

    const int y0c = min(max(y0, 0), 127), y1c = min(max(y1, 0), 127);
    const int x0c = min(max(x0i, 0), 127), x1c = min(max(x1, 0), 127);

    float w00 = (1.f - ly) * (1.f - lx) * mv;
    float w01 = (1.f - ly) * lx * mv;
    float w10 = ly * (1.f - lx) * mv;
    float w11 = ly * lx * mv;
    const bool vy0 = (unsigned)y0 < 128u, vy1 = (unsigned)y1 < 128u;
    const bool vx0 = (unsigned)x0i < 128u, vx1 = (unsigned)x1 < 128u;
    w00 = (vy0 && vx0) ? w00 : 0.f;
    w01 = (vy0 && vx1) ? w01 : 0.f;
    w10 = (vy1 && vx0) ? w10 : 0.f;
    w11 = (vy1 && vx1) ? w11 : 0.f;

    const int a00 = ((((y0c >> 1) << 6) + (x0c >> 1)) << 7) + gbase;
    const int a01 = ((((y0c >> 1) << 6) + (x1c >> 1)) << 7) + gbase;
    const int a10 = ((((y1c >> 1) << 6) + (x0c >> 1)) << 7) + gbase;
    const int a11 = ((((y1c >> 1) << 6) + (x1c >> 1)) << 7) + gbase;

    f16x8 t00a = *(const f16x8*)(fb + a00), t00b = *(const f16x8*)(fb + a00 + 8);
    f16x8 t01a = *(const f16x8*)(fb + a01), t01b = *(const f16x8*)(fb + a01 + 8);
    f16x8 t10a = *(const f16x8*)(fb + a10), t10b = *(const f16x8*)(fb + a10 + 8);
    f16x8 t11a = *(const f16x8*)(fb + a11), t11b = *(const f16x8*)(fb + a11 + 8);

    f16x8 ov0, ov1;
#pragma unroll
    for (int j = 0; j < 8; ++j) {
      ov0[j] = (_Float16)(w00 * (float)t00a[j] + w01 * (float)t01a[j]
                        + w10 * (float)t10a[j] + w11 * (float)t11a[j]);
      ov1[j] = (_Float16)(w00 * (float)t00b[j] + w01 * (float)t01b[j]
                        + w10 * (float)t10b[j] + w11 * (float)t11b[j]);
    }

    _Float16* dst = dstb + i * 32;
    ((f16x8*)dst)[0] = ov0;
    ((f16x8*)dst)[1] = ov1;
  }
}

// ---------------------------------------------------------------------------
// dcn GEMM: wave = 16 px x ALL 64 oc (4 m-tiles) -> valh read exactly once.
// Grid (256, 2) = 512 blocks x 4 waves. Writes alh f16 [b][p][64].
// ---------------------------------------------------------------------------
__global__ __launch_bounds__(256) void dcn_gemm_kernel(
    const _Float16* __restrict__ valh, const _Float16* __restrict__ Wf2,
    const float* __restrict__ db, _Float16* __restrict__ alh)
{
  const int b    = blockIdx.y;
  const int tid  = threadIdx.x;
  const int wv   = tid >> 6;
  const int lane = tid & 63;
  const int px0  = blockIdx.x * 64 + wv * 16;

  f32x4 acc[4];
#pragma unroll
  for (int m = 0; m < 4; ++m) acc[m] = (f32x4){0.f, 0.f, 0.f, 0.f};

  const f16x8* Bp = (const f16x8*)valh
      + ((size_t)(b * 36) * 16384 + px0 + (lane & 15)) * 4 + (lane >> 4);
  const f16x8* Ap = (const f16x8*)Wf2 + lane;

#pragma unroll 2
  for (int q = 0; q < 36; ++q) {
    f16x8 bf = Bp[(size_t)q * 65536];
    const f16x8* ap = Ap + q * 256;
#pragma unroll
    for (int m = 0; m < 4; ++m)
      acc[m] = __builtin_amdgcn_mfma_f32_16x16x32_f16(ap[m * 64], bf, acc[m], 0, 0, 0);
  }

  const int pxl = px0 + (lane & 15);
  const int r0  = (lane >> 4) * 4;
#pragma unroll
  for (int m = 0; m < 4; ++m) {
    f16x4 hv;
#pragma unroll
    for (int r = 0; r < 4; ++r) {
      int oc = m * 16 + r0 + r;
      hv[r] = (_Float16)relu_(acc[m][r] + db[oc]);
    }
    *(f16x4*)&alh[(((size_t)b << 14) + pxl) * 64 + m * 16 + r0] = hv;
  }
}

// ---------------------------------------------------------------------------
// cat GEMM: out[b][oc][p] = relu(cat_w @ feat_align) + arm. K=64 (2 chunks).
// ---------------------------------------------------------------------------
__global__ __launch_bounds__(256) void cat_gemm_kernel(
    const _Float16* __restrict__ alh, const _Float16* __restrict__ WfC,
    const float* __restrict__ arm, float* __restrict__ out)
{
  const int b    = blockIdx.y;
  const int tid  = threadIdx.x;
  const int wv   = tid >> 6;
  const int lane = tid & 63;
  const int px0  = blockIdx.x * 64 + wv * 16;
  const int pxl  = px0 + (lane & 15);

  f32x4 acc[8];
#pragma unroll
  for (int m = 0; m < 8; ++m) acc[m] = (f32x4){0.f, 0.f, 0.f, 0.f};

  const f16x8* Bp = (const f16x8*)alh + (((size_t)b << 14) + pxl) * 8 + (lane >> 4);
  const f16x8* Ap = (const f16x8*)WfC + lane;

#pragma unroll
  for (int q = 0; q < 2; ++q) {
    f16x8 bf = Bp[q * 4];
#pragma unroll
    for (int m = 0; m < 8; ++m)
      acc[m] = __builtin_amdgcn_mfma_f32_16x16x32_f16(Ap[(q * 8 + m) * 64], bf, acc[m], 0, 0, 0);
  }

  const int r0 = (lane >> 4) * 4;
#pragma unroll
  for (int m = 0; m < 8; ++m) {
#pragma unroll
    for (int r = 0; r < 4; ++r) {
      int oc = m * 16 + r0 + r;
      size_t a = ((size_t)(b * 128 + oc) << 14) + pxl;
      out[a] = relu_(acc[m][r]) + arm[a];
    }
  }
}

// ---------------------------------------------------------------------------
// FALLBACK path kernels (small ws): round-1 versions
// ---------------------------------------------------------------------------
__global__ __launch_bounds__(256) void com_conv_kernel(
    const float* __restrict__ x, const float* __restrict__ cw,
    const float* __restrict__ cb, float* __restrict__ om)
{
  const int b    = blockIdx.z;
  const int ocg  = blockIdx.y;
  const int tile = blockIdx.x;
  const int th = (tile >> 2) * 32, tw = (tile & 3) * 32;
  const int tid = threadIdx.x;
  const int lw = (tid & 7) * 4;
  const int lh = tid >> 3;

  __shared__ float Xs[8 * 34 * 34];

  float acc[8][4];
#pragma unroll
  for (int a = 0; a < 8; ++a)
#pragma unroll
    for (int p = 0; p < 4; ++p) acc[a][p] = 0.f;

  for (int cc = 0; cc < 128; cc += 8) {
    __syncthreads();
    for (int idx = tid; idx < 8 * 1156; idx += 256) {
      int ic  = idx / 1156;
      int rem = idx - ic * 1156;
      int yy  = rem / 34;
      int xx  = rem - yy * 34;
      int gh = th + yy - 1, gw = tw + xx - 1;
      float v = 0.f;
      if ((unsigned)gh < 128u && (unsigned)gw < 128u)
        v = x[((size_t)(b * 128 + cc + ic) << 14) + (gh << 7) + gw];
      Xs[idx] = v;
    }
    __syncthreads();
#pragma unroll 1
    for (int ic = 0; ic < 8; ++ic) {
      float xr[3][6];
#pragma unroll
      for (int ky = 0; ky < 3; ++ky)
#pragma unroll
        for (int xx = 0; xx < 6; ++xx)
          xr[ky][xx] = Xs[ic * 1156 + (lh + ky) * 34 + lw + xx];
      const float* wp = cw + ((size_t)(ocg * 8) * 128 + (cc + ic)) * 9;
#pragma unroll
      for (int a = 0; a < 8; ++a) {
        const float* w9 = wp + a * 1152;
#pragma unroll
        for (int ky = 0; ky < 3; ++ky)
#pragma unroll
          for (int kx = 0; kx < 3; ++kx) {
            float wv = w9[ky * 3 + kx];
#pragma unroll
            for (int p = 0; p < 4; ++p)
              acc[a][p] = fmaf(wv, xr[ky][kx + p], acc[a][p]);
          }
      }
    }
  }

#pragma unroll
  for (int a = 0; a < 8; ++a) {
    int oc = ocg * 8 + a;
    float bv = cb[oc];
    float4 r = make_float4(acc[a][0] + bv, acc[a][1] + bv,
                           acc[a][2] + bv, acc[a][3] + bv);
    *(float4*)(om + ((size_t)(b * 216 + oc) << 14) + ((th + lh) << 7) + tw + lw) = r;
  }
}

__global__ __launch_bounds__(256) void wt_kernel(const float* __restrict__ dw,
                                                 float* __restrict__ wT)
{
  int idx = blockIdx.x * 256 + threadIdx.x;
  int o    = idx & 63;
  int rest = idx >> 6;
  int k    = rest % 9;
  int gc   = rest / 9;
  wT[idx] = dw[(o * 128 + gc) * 9 + k];
}

__global__ __launch_bounds__(256) void dcn_kernel(
    const float* __restrict__ fs, const float* __restrict__ om,
    const float* __restrict__ wT, const float* __restrict__ db,
    float* __restrict__ al)
{
  const int b   = blockIdx.y;
  const int p0  = blockIdx.x * 32;
  const int tid = threadIdx.x;
  const int px  = tid & 31;
  const int g   = tid >> 5;
  const int p = p0 + px;
  const int h = p >> 7, w = p & 127;

  float acc[64];
#pragma unroll
  for (int o = 0; o < 64; ++o) acc[o] = 0.f;

  const size_t omb = ((size_t)b * 216) << 14;
  const float* fsg = fs + (((size_t)(b * 128 + g * 16)) << 12);
  const float* wg  = wT + g * (16 * 9 * 64);

#pragma unroll 1
  for (int k = 0; k < 9; ++k) {
    float offy = om[omb + ((size_t)(g * 18 + 2 * k) << 14) + p];
    float offx = om[omb + ((size_t)(g * 18 + 2 * k + 1) << 14) + p];
    float mraw = om[omb + ((size_t)(144 + g * 9 + k) << 14) + p];
    float mv = 1.f / (1.f + __expf(-mraw));

    float py  = (float)(h + k / 3 - 1) + offy;
    float pxx = (float)(w + k % 3 - 1) + offx;
    float y0f = floorf(py), x0f = floorf(pxx);
    float ly = py - y0f, lx = pxx - x0f;
    int y0 = (int)y0f, x0i = (int)x0f;
    int y1 = y0 + 1, x1 = x0i + 1;

    int y0c = min(max(y0, 0), 127), y1c = min(max(y1, 0), 127);
    int x0c = min(max(x0i, 0), 127), x1c = min(max(x1, 0), 127);
    int ry0 = (y0c >> 1) << 6, ry1 = (y1c >> 1) << 6;
    int cx0 = x0c >> 1, cx1 = x1c >> 1;

    float w00 = (1.f - ly) * (1.f - lx) * mv;
    float w01 = (1.f - ly) * lx * mv;
    float w10 = ly * (1.f - lx) * mv;
    float w11 = ly * lx * mv;
    bool vy0 = (unsigned)y0 < 128u, vy1 = (unsigned)y1 < 128u;
    bool vx0 = (unsigned)x0i < 128u, vx1 = (unsigned)x1 < 128u;
    w00 = (vy0 && vx0) ? w00 : 0.f;
    w01 = (vy0 && vx1) ? w01 : 0.f;
    w10 = (vy1 && vx0) ? w10 : 0.f;
    w11 = (vy1 && vx1) ? w11 : 0.f;

#pragma unroll 1
    for (int c = 0; c < 16; ++c) {
      const float* fc = fsg + (c << 12);
      float v00 = fc[ry0 + cx0];
      float v01 = fc[ry0 + cx1];
      float v10 = fc[ry1 + cx0];
      float v11 = fc[ry1 + cx1];
      float v = w00 * v00 + w01 * v01 + w10 * v10 + w11 * v11;
      const float* wp = wg + (c * 9 + k) * 64;
#pragma unroll
      for (int oq = 0; oq < 16; ++oq) {
        float4 w4 = *(const float4*)(wp + oq * 4);
        acc[oq * 4 + 0] = fmaf(v, w4.x, acc[oq * 4 + 0]);
        acc[oq * 4 + 1] = fmaf(v, w4.y, acc[oq * 4 + 1]);
        acc[oq * 4 + 2] = fmaf(v, w4.z, acc[oq * 4 + 2]);
        acc[oq * 4 + 3] = fmaf(v, w4.w, acc[oq * 4 + 3]);
      }
    }
  }

  __shared__ float red[256][17];
  const int px2 = tid & 31;
  const int og  = tid >> 5;
#pragma unroll
  for (int r = 0; r < 4; ++r) {
    __syncthreads();
#pragma unroll
    for (int j = 0; j < 16; ++j) red[tid][j] = acc[r * 16 + j];
    __syncthreads();
#pragma unroll
    for (int jj = 0; jj < 2; ++jj) {
      int ol = og * 2 + jj;
      float s = 0.f;
#pragma unroll
      for (int gg = 0; gg < 8; ++gg) s += red[gg * 32 + px2][ol];
      int oc = r * 16 + ol;
      s += db[oc];
      al[((size_t)(b * 64 + oc) << 14) + p0 + px2] = fmaxf(s, 0.f);
    }
  }
}

// ---------------------------------------------------------------------------
extern "C" void kernel_launch(void* const* d_in, const int* in_sizes, int n_in,
                              void* d_out, int out_size, void* d_ws, size_t ws_size,
                              hipStream_t stream)
{
  const float* feat_l   = (const float*)d_in[0];
  const float* feat_s   = (const float*)d_in[1];
  const float* fsm_w    = (const float*)d_in[2];
  const float* offset_w = (const float*)d_in[3];
  const float* com_w    = (const float*)d_in[4];
  const float* com_b    = (const float*)d_in[5];
  const float* dcn_w    = (const float*)d_in[6];
  const float* dcn_b    = (const float*)d_in[7];
  const float* cat_w    = (const float*)d_in[8];
  float* out = (float*)d_out;
  float* ws  = (float*)d_ws;

  const size_t NEED = (size_t)(4194304 + 7077888 + 2097152 + 1048576 + 37748736) * 4;

  if (ws_size >= NEED) {
    float* arm      = ws;                          // 4,194,304 f32
    float* om       = ws + 4194304;                // 7,077,888 f32
    _Float16* alh   = (_Float16*)(ws + 11272192);  // 2,097,152 f16
    _Float16* Wf2   = (_Float16*)(ws + 12320768);  // 73,728 f16
    _Float16* WfC   = (_Float16*)(ws + 12357632);  // 8,192 f16
    _Float16* fsTh  = (_Float16*)(ws + 13369344);  // 1,048,576 f16
    _Float16* flTh  = (_Float16*)(ws + 13893632);  // 4,194,304 f16
    _Float16* armh  = (_Float16*)(ws + 15990784);  // 4,194,304 f16
    _Float16* offh  = (_Float16*)(ws + 18087936);  // 4,194,304 f16
    _Float16* valh  = (_Float16*)(ws + 20185088);  // 37,748,736 f16
    _Float16* WfA   = (_Float16*)(ws + 39059456);  // 16,384 f16
    _Float16* WfB   = (_Float16*)(ws + 39067648);  // 32,768 f16
    _Float16* WfP   = (_Float16*)(ws + 39084032);  // 294,912 f16

    hipLaunchKernelGGL(wfall_kernel, dim3(208), dim3(256), 0, stream,
                       fsm_w, offset_w, com_w, dcn_w, cat_w, WfA, WfB, WfP, Wf2, WfC);
    hipLaunchKernelGGL(t2h2_kernel, dim3(640, 4, 2), dim3(256), 0, stream,
                       feat_l, feat_s, flTh, fsTh);
    hipLaunchKernelGGL(fsm_gemm_kernel, dim3(256, 2), dim3(256), 0, stream,
                       flTh, WfA, arm, armh);
    hipLaunchKernelGGL(off_gemm_kernel, dim3(256, 2), dim3(256), 0, stream,
                       armh, fsTh, WfB, offh);
    hipLaunchKernelGGL(com_gemm_kernel, dim3(256, 2, 2), dim3(256), 0, stream,
                       offh, WfP, com_b, om);
    hipLaunchKernelGGL(sample_kernel, dim3(2304), dim3(256), 0, stream,
                       fsTh, om, valh);
    hipLaunchKernelGGL(dcn_gemm_kernel, dim3(256, 2), dim3(256), 0, stream,
                       valh, Wf2, dcn_b, alh);
    hipLaunchKernelGGL(cat_gemm_kernel, dim3(256, 2), dim3(256), 0, stream,
                       alh, WfC, arm, out);
  } else {
    float* arm = ws;
    float* off = ws + 4194304;
    float* om  = ws + 8388608;
    float* al  = ws + 15466496;
    float* wT  = ws + 17563648;

    hipLaunchKernelGGL(wt_kernel, dim3(288), dim3(256), 0, stream, dcn_w, wT);
    hipLaunchKernelGGL((conv1x1_kernel<0, 128>), dim3(256, 2), dim3(256), 0, stream,
                       feat_l, nullptr, fsm_w, arm);
    hipLaunchKernelGGL((conv1x1_kernel<1, 256>), dim3(256, 2), dim3(256), 0, stream,
                       arm, feat_s, offset_w, off);
    hipLaunchKernelGGL(com_conv_kernel, dim3(16, 27, 2), dim3(256), 0, stream,
                       off, com_w, com_b, om);
    hipLaunchKernelGGL(dcn_kernel, dim3(512, 2), dim3(256), 0, stream,
                       feat_s, om, wT, dcn_b, al);
    hipLaunchKernelGGL((conv1x1_kernel<2, 64>), dim3(256, 2), dim3(256), 0, stream,
                       al, arm, cat_w, out);
  }
}

// Round 8
// 187.691 us; speedup vs baseline: 4.5989x; 1.2020x over previous
//
#include <hip/hip_runtime.h>
#include <cstdint>
#include <cstddef>

// Problem constants
// B=2, C=128, H=W=128, Hs=Ws=64, DG=8, KK=9, CG=16, COUT_DCN=64, HW=16384

typedef _Float16 f16x8 __attribute__((ext_vector_type(8)));
typedef _Float16 f16x4 __attribute__((ext_vector_type(4)));
typedef float    f32x4 __attribute__((ext_vector_type(4)));

__device__ __forceinline__ float relu_(float x) { return fmaxf(x, 0.f); }

// ---------------------------------------------------------------------------
// conv1x1 (fp32, LDS-tiled) — FALLBACK path only.
// ---------------------------------------------------------------------------
template<int MODE, int CIN>
__global__ __launch_bounds__(256) void conv1x1_kernel(
    const float* __restrict__ in1, const float* __restrict__ in2,
    const float* __restrict__ Wm, float* __restrict__ out)
{
  constexpr int IN1C = (MODE == 2) ? 64 : 128;
  const int b  = blockIdx.y;
  const int p0 = blockIdx.x * 64;
  const int tid = threadIdx.x;
  const int tx = tid & 7;
  const int ty = tid >> 3;

  __shared__ float Xs[16][64];
  __shared__ float Wt[16][128];

  float acc[4][8];
#pragma unroll
  for (int i = 0; i < 4; ++i)
#pragma unroll
    for (int j = 0; j < 8; ++j) acc[i][j] = 0.f;

  const int cS  = tid >> 4;
  const int pxS = (tid & 15) * 4;
  const int ocS = (tid & 15) * 8;

  for (int cc = 0; cc < CIN; cc += 16) {
    __syncthreads();
    {
      int gc = cc + cS;
      float4 v;
      if (MODE == 1 && gc >= 128) {
        int sc = gc - 128;
        float t[4];
#pragma unroll
        for (int j = 0; j < 4; ++j) {
          int pp = p0 + pxS + j;
          int hh = pp >> 7, ww = pp & 127;
          t[j] = 2.f * in2[((size_t)(b * 128 + sc) << 12) + ((hh >> 1) << 6) + (ww >> 1)];
        }
        v = make_float4(t[0], t[1], t[2], t[3]);
      } else {
        v = *(const float4*)(in1 + ((size_t)(b * IN1C + gc) << 14) + p0 + pxS);
      }
      *(float4*)&Xs[cS][pxS] = v;
#pragma unroll
      for (int j = 0; j < 8; ++j)
        Wt[cS][ocS + j] = Wm[(ocS + j) * CIN + cc + cS];
    }
    __syncthreads();
#pragma unroll
    for (int c = 0; c < 16; ++c) {
      float4 wv = *(const float4*)&Wt[c][ty * 4];
      float4 x0 = *(const float4*)&Xs[c][tx * 8];
      float4 x1 = *(const float4*)&Xs[c][tx * 8 + 4];
      float xs[8] = {x0.x, x0.y, x0.z, x0.w, x1.x, x1.y, x1.z, x1.w};
      float wf[4] = {wv.x, wv.y, wv.z, wv.w};
#pragma unroll
      for (int i = 0; i < 4; ++i)
#pragma unroll
        for (int j = 0; j < 8; ++j)
          acc[i][j] = fmaf(wf[i], xs[j], acc[i][j]);
    }
  }

#pragma unroll
  for (int i = 0; i < 4; ++i) {
    int oc = ty * 4 + i;
    size_t base = ((size_t)(b * 128 + oc) << 14) + p0 + tx * 8;
    float r[8];
#pragma unroll
    for (int j = 0; j < 8; ++j) r[j] = relu_(acc[i][j]);
    if (MODE == 2) {
#pragma unroll
      for (int j = 0; j < 8; ++j) r[j] += in2[base + j];
    }
    *(float4*)(out + base)     = make_float4(r[0], r[1], r[2], r[3]);
    *(float4*)(out + base + 4) = make_float4(r[4], r[5], r[6], r[7]);
  }
}

// ---------------------------------------------------------------------------
// t2h2: fused transpose of feat_l and feat_s: [b][128][HW] f32 -> [b][HW][128] f16
// ---------------------------------------------------------------------------
__global__ __launch_bounds__(256) void t2h2_kernel(
    const float* __restrict__ fl, const float* __restrict__ fs,
    _Float16* __restrict__ flTh, _Float16* __restrict__ fsTh)
{
  const int bx = blockIdx.x;
  const float* src;
  _Float16* dst;
  int HW, p0;
  if (bx < 512) { src = fl; dst = flTh; HW = 16384; p0 = bx * 32; }
  else          { src = fs; dst = fsTh; HW = 4096;  p0 = (bx - 512) * 32; }
  const int b  = blockIdx.z;
  const int c0 = blockIdx.y * 32;
  const int tid = threadIdx.x;
  __shared__ float T[32][33];
  {
    int pxl = tid & 31, cy = tid >> 5;
#pragma unroll
    for (int j = 0; j < 4; ++j) {
      int c = cy + j * 8;
      T[c][pxl] = src[((size_t)(b * 128 + c0 + c)) * HW + p0 + pxl];
    }
  }
  __syncthreads();
  {
    int cq = tid & 7, pr = tid >> 3;
    f16x4 v;
#pragma unroll
    for (int e = 0; e < 4; ++e) v[e] = (_Float16)T[cq * 4 + e][pr];
    *(f16x4*)&dst[(((size_t)b * HW) + p0 + pr) * 128 + c0 + cq * 4] = v;
  }
}

// ---------------------------------------------------------------------------
// wfall: all 5 weight packs in one launch. Block ranges:
// [0,8) WfA | [8,24) WfB | [24,168) WfP | [168,204) Wf2 | [204,208) WfC
// ---------------------------------------------------------------------------
__global__ __launch_bounds__(256) void wfall_kernel(
    const float* __restrict__ fsm_w, const float* __restrict__ offset_w,
    const float* __restrict__ com_w, const float* __restrict__ dcn_w,
    const float* __restrict__ cat_w,
    _Float16* __restrict__ WfA, _Float16* __restrict__ WfB,
    _Float16* __restrict__ WfP, _Float16* __restrict__ Wf2,
    _Float16* __restrict__ WfC)
{
  const int bid = blockIdx.x;
  if (bid < 8) {                         // WfA: fsm_w [128][128]
    int idx = bid * 256 + threadIdx.x;
    int lane = idx & 63;
    int t = idx >> 6;
    int m = t & 7, q = t >> 3;
    int oc = m * 16 + (lane & 15);
    int c0 = q * 32 + (lane >> 4) * 8;
    f16x8 v;
#pragma unroll
    for (int j = 0; j < 8; ++j) v[j] = (_Float16)fsm_w[oc * 128 + c0 + j];
    ((f16x8*)WfA)[idx] = v;
  } else if (bid < 24) {                 // WfB: offset_w [128][256], x2 on c>=128
    int idx = (bid - 8) * 256 + threadIdx.x;
    int lane = idx & 63;
    int t = idx >> 6;
    int m = t & 7, q = t >> 3;
    int oc = m * 16 + (lane & 15);
    int c0 = q * 32 + (lane >> 4) * 8;
    float s = (q >= 4) ? 2.f : 1.f;
    f16x8 v;
#pragma unroll
    for (int j = 0; j < 8; ++j) v[j] = (_Float16)(offset_w[oc * 256 + c0 + j] * s);
    ((f16x8*)WfB)[idx] = v;
  } else if (bid < 168) {                // WfP: com_w, oc-half-major, pad 256
    int idx = (bid - 24) * 256 + threadIdx.x;
    int lane = idx & 63;
    int t = idx >> 6;
    int m = t & 7;
    int t2 = t >> 3;
    int half = t2 & 1, q = t2 >> 1;
    int kk = q >> 2;
    int ic0 = (q & 3) * 32 + (lane >> 4) * 8;
    int oc = half * 128 + m * 16 + (lane & 15);
    f16x8 v;
#pragma unroll
    for (int j = 0; j < 8; ++j) {
      float x = (oc < 216) ? com_w[((size_t)oc * 128 + ic0 + j) * 9 + kk] : 0.f;
      v[j] = (_Float16)x;
    }
    ((f16x8*)WfP)[idx] = v;
  } else if (bid < 204) {                // Wf2: dcn_w, r' = (g*9+k)*16+c
    int idx = (bid - 168) * 256 + threadIdx.x;
    int lane = idx & 63;
    int t = idx >> 6;
    int m = t & 3, q = t >> 2;
    int oc = m * 16 + (lane & 15);
    f16x8 v;
#pragma unroll
    for (int j = 0; j < 8; ++j) {
      int rp = q * 32 + (lane >> 4) * 8 + j;
      int c = rp & 15, tt = rp >> 4;
      int g = tt / 9, k = tt % 9;
      v[j] = (_Float16)dcn_w[((size_t)oc * 128 + g * 16 + c) * 9 + k];
    }
    ((f16x8*)Wf2)[idx] = v;
  } else {                               // WfC: cat_w [128][64]
    int idx = (bid - 204) * 256 + threadIdx.x;
    int lane = idx & 63;
    int t = idx >> 6;
    int m = t & 7, q = t >> 3;
    int oc = m * 16 + (lane & 15);
    int k0 = q * 32 + (lane >> 4) * 8;
    f16x8 v;
#pragma unroll
    for (int j = 0; j < 8; ++j) v[j] = (_Float16)cat_w[oc * 64 + k0 + j];
    ((f16x8*)WfC)[idx] = v;
  }
}

// ---------------------------------------------------------------------------
// fsm GEMM: arm = relu(fsm_w @ feat_l). Outputs arm f32 [oc][p] + armh f16 [p][oc].
// ---------------------------------------------------------------------------
__global__ __launch_bounds__(256) void fsm_gemm_kernel(
    const _Float16* __restrict__ flTh, const _Float16* __restrict__ WfA,
    float* __restrict__ arm, _Float16* __restrict__ armh)
{
  const int b    = blockIdx.y;
  const int tid  = threadIdx.x;
  const int wv   = tid >> 6;
  const int lane = tid & 63;
  const int px0  = blockIdx.x * 64 + wv * 16;
  const int pxl  = px0 + (lane & 15);

  f32x4 acc[8];
#pragma unroll
  for (int m = 0; m < 8; ++m) acc[m] = (f32x4){0.f, 0.f, 0.f, 0.f};

  const f16x8* Bp = (const f16x8*)flTh + (((size_t)b << 14) + pxl) * 16 + (lane >> 4);
  const f16x8* Ap = (const f16x8*)WfA + lane;

#pragma unroll
  for (int q = 0; q < 4; ++q) {
    f16x8 bf = Bp[q * 4];
#pragma unroll
    for (int m = 0; m < 8; ++m)
      acc[m] = __builtin_amdgcn_mfma_f32_16x16x32_f16(Ap[(q * 8 + m) * 64], bf, acc[m], 0, 0, 0);
  }

  const int r0 = (lane >> 4) * 4;
#pragma unroll
  for (int m = 0; m < 8; ++m) {
    f16x4 h;
#pragma unroll
    for (int r = 0; r < 4; ++r) {
      float v = relu_(acc[m][r]);
      arm[((size_t)(b * 128 + m * 16 + r0 + r) << 14) + pxl] = v;
      h[r] = (_Float16)v;
    }
    *(f16x4*)&armh[(((size_t)b << 14) + pxl) * 128 + m * 16 + r0] = h;
  }
}

// ---------------------------------------------------------------------------
// offset GEMM: offh = relu(offset_w @ [armh ; 2*featup]) in f16 [p][128].
// ---------------------------------------------------------------------------
__global__ __launch_bounds__(256) void off_gemm_kernel(
    const _Float16* __restrict__ armh, const _Float16* __restrict__ fsTh,
    const _Float16* __restrict__ WfB, _Float16* __restrict__ offh)
{
  const int b    = blockIdx.y;
  const int tid  = threadIdx.x;
  const int wv   = tid >> 6;
  const int lane = tid & 63;
  const int px0  = blockIdx.x * 64 + wv * 16;
  const int pxl  = px0 + (lane & 15);
  const int h = pxl >> 7, w = pxl & 127;
  const int pup = ((h >> 1) << 6) + (w >> 1);

  f32x4 acc[8];
#pragma unroll
  for (int m = 0; m < 8; ++m) acc[m] = (f32x4){0.f, 0.f, 0.f, 0.f};

  const f16x8* BpA = (const f16x8*)armh + (((size_t)b << 14) + pxl) * 16 + (lane >> 4);
  const f16x8* BpU = (const f16x8*)fsTh + (((size_t)b << 12) + pup) * 16 + (lane >> 4);
  const f16x8* Ap  = (const f16x8*)WfB + lane;

#pragma unroll
  for (int q = 0; q < 8; ++q) {
    f16x8 bf = (q < 4) ? BpA[q * 4] : BpU[(q - 4) * 4];
#pragma unroll
    for (int m = 0; m < 8; ++m)
      acc[m] = __builtin_amdgcn_mfma_f32_16x16x32_f16(Ap[(q * 8 + m) * 64], bf, acc[m], 0, 0, 0);
  }

  const int r0 = (lane >> 4) * 4;
#pragma unroll
  for (int m = 0; m < 8; ++m) {
    f16x4 hh;
#pragma unroll
    for (int r = 0; r < 4; ++r) hh[r] = (_Float16)relu_(acc[m][r]);
    *(f16x4*)&offh[(((size_t)b << 14) + pxl) * 128 + m * 16 + r0] = hh;
  }
}

// ---------------------------------------------------------------------------
// com GEMM (LDS-staged, depth-2 B prefetch): om[b][oc][p], oc padded 256.
// ---------------------------------------------------------------------------
__global__ __launch_bounds__(256) void com_gemm_kernel(
    const _Float16* __restrict__ offh, const _Float16* __restrict__ WfP,
    const float* __restrict__ cb, float* __restrict__ om)
{
  const int b    = blockIdx.z;
  const int half = blockIdx.y;
  const int tid  = threadIdx.x;
  const int lane = tid & 63;
  const int px0  = blockIdx.x * 64 + (tid >> 6) * 16;
  const int pxl  = px0 + (lane & 15);
  const int h = pxl >> 7, w = pxl & 127;

  __shared__ f16x8 As[512];   // 8 KB

  f32x4 acc[8];
#pragma unroll
  for (int m = 0; m < 8; ++m) acc[m] = (f32x4){0.f, 0.f, 0.f, 0.f};

  const f16x8* Bbase = (const f16x8*)offh + ((size_t)b << 14) * 16 + (lane >> 4);
  const f16x8* Wp    = (const f16x8*)WfP + half * 512 + tid * 2;
  const f16x8 zero = {(_Float16)0.f, (_Float16)0.f, (_Float16)0.f, (_Float16)0.f,
                      (_Float16)0.f, (_Float16)0.f, (_Float16)0.f, (_Float16)0.f};

  auto loadB = [&](int t) -> f16x8 {
    const int kk = t >> 2, ic4 = t & 3;
    const int hh = h + kk / 3 - 1;
    const int ww = w + kk % 3 - 1;
    const bool valid = ((unsigned)hh < 128u) && ((unsigned)ww < 128u);
    const int ps = valid ? ((hh << 7) + ww) : 0;
    f16x8 bf = Bbase[(size_t)ps * 16 + ic4 * 4];
    return valid ? bf : zero;
  };

  f16x8 rA0 = Wp[0], rA1 = Wp[1];
  f16x8 bfA = loadB(0), bfB = loadB(1);

#pragma unroll 1
  for (int tt = 0; tt < 18; ++tt) {
    const int t0 = tt * 2;
    __syncthreads();
    As[tid * 2] = rA0; As[tid * 2 + 1] = rA1;
    __syncthreads();
    rA0 = Wp[(t0 + 1) * 1024]; rA1 = Wp[(t0 + 1) * 1024 + 1];
    {
      f16x8 bu = bfA;
      if (t0 + 2 < 36) bfA = loadB(t0 + 2);
#pragma unroll
      for (int m = 0; m < 8; ++m)
        acc[m] = __builtin_amdgcn_mfma_f32_16x16x32_f16(As[m * 64 + lane], bu, acc[m], 0, 0, 0);
    }
    __syncthreads();
    As[tid * 2] = rA0; As[tid * 2 + 1] = rA1;
    __syncthreads();
    if (t0 + 2 < 36) { rA0 = Wp[(t0 + 2) * 1024]; rA1 = Wp[(t0 + 2) * 1024 + 1]; }
    {
      f16x8 bu = bfB;
      if (t0 + 3 < 36) bfB = loadB(t0 + 3);
#pragma unroll
      for (int m = 0; m < 8; ++m)
        acc[m] = __builtin_amdgcn_mfma_f32_16x16x32_f16(As[m * 64 + lane], bu, acc[m], 0, 0, 0);
    }
  }

  const int r0i = (lane >> 4) * 4;
#pragma unroll
  for (int m = 0; m < 8; ++m) {
#pragma unroll
    for (int r = 0; r < 4; ++r) {
      int oc = half * 128 + m * 16 + r0i + r;
      if (oc < 216)
        om[((size_t)(b * 216 + oc) << 14) + pxl] = acc[m][r] + cb[oc];
    }
  }
}

// ---------------------------------------------------------------------------
// dcn FUSED kernel: bilinear sampling + masked einsum in one pass, no val
// materialization. Wave = 16 px x 64 oc, K = 1152 in 36 chunks.
// Per chunk, lane s=lane>>4 supplies B-fragment elements for
// t9 = 2q + (lane>>5), c = ((lane>>4)&1)*8 + j -- computed IN-REGISTER:
// 3 coalesced om loads + 4 f16x8 taps + f32 bilinear -> f16x8 bf -> 4 MFMA.
// Numerics identical to the former sample+gemm pair. Writes alh f16 [b][p][64].
// ---------------------------------------------------------------------------
__global__ __launch_bounds__(256) void dcn_fused_kernel(
    const _Float16* __restrict__ fsTh, const float* __restrict__ om,
    const _Float16* __restrict__ Wf2, const float* __restrict__ db,
    _Float16* __restrict__ alh)
{
  const int b    = blockIdx.y;
  const int tid  = threadIdx.x;
  const int wv   = tid >> 6;
  const int lane = tid & 63;
  const int px0  = blockIdx.x * 64 + wv * 16;
  const int pxl  = px0 + (lane & 15);
  const int h = pxl >> 7, w = pxl & 127;
  const int t9add = lane >> 5;             // 0 or 1
  const int chalf = ((lane >> 4) & 1) << 3; // 0 or 8

  const float* omp = om + (((size_t)b * 216) << 14) + pxl;
  const _Float16* fb = fsTh + ((size_t)b << 19);
  const f16x8* Ap = (const f16x8*)Wf2 + lane;

  f32x4 acc[4];
#pragma unroll
  for (int m = 0; m < 4; ++m) acc[m] = (f32x4){0.f, 0.f, 0.f, 0.f};

#pragma unroll 1
  for (int q = 0; q < 36; ++q) {
    const int t9 = 2 * q + t9add;
    const int g = t9 / 9;                  // magic-mul div
    const int k = t9 - g * 9;

    const float offy = omp[(size_t)(g * 18 + 2 * k) << 14];
    const float offx = omp[(size_t)(g * 18 + 2 * k + 1) << 14];
    const float mraw = omp[(size_t)(144 + t9) << 14];
    const float mv = 1.f / (1.f + __expf(-mraw));

    const float py  = (float)(h + k / 3 - 1) + offy;
    const float pxx = (float)(w + k % 3 - 1) + offx;
    const float y0f = floorf(py), x0f = floorf(pxx);
    const float ly = py - y0f, lx = pxx - x0f;
    const int y0 = (int)y0f, x0i = (int)x0f;
    const int y1 = y0 + 1, x1 = x0i + 1;

    const int y0c = min(max(y0, 0), 127), y1c = min(max(y1, 0), 127);
    const int x0c = min(max(x0i, 0), 127), x1c = min(max(x1, 0), 127);

    float w00 = (1.f - ly) * (1.f - lx) * mv;
    float w01 = (1.f - ly) * lx * mv;
    float w10 = ly * (1.f - lx) * mv;
    float w11 = ly * lx * mv;
    const bool vy0 = (unsigned)y0 < 128u, vy1 = (unsigned)y1 < 128u;
    const bool vx0 = (unsigned)x0i < 128u, vx1 = (unsigned)x1 < 128u;
    w00 = (vy0 && vx0) ? w00 : 0.f;
    w01 = (vy0 && vx1) ? w01 : 0.f;
    w10 = (vy1 && vx0) ? w10 : 0.f;
    w11 = (vy1 && vx1) ? w11 : 0.f;

    const int gb = g * 16 + chalf;
    const int a00 = ((((y0c >> 1) << 6) + (x0c >> 1)) << 7) + gb;
    const int a01 = ((((y0c >> 1) << 6) + (x1c >> 1)) << 7) + gb;
    const int a10 = ((((y1c >> 1) << 6) + (x0c >> 1)) << 7) + gb;
    const int a11 = ((((y1c >> 1) << 6) + (x1c >> 1)) << 7) + gb;

    f16x8 t00 = *(const f16x8*)(fb + a00);
    f16x8 t01 = *(const f16x8*)(fb + a01);
    f16x8 t10 = *(const f16x8*)(fb + a10);
    f16x8 t11 = *(const f16x8*)(fb + a11);

    f16x8 bf;
#pragma unroll
    for (int j = 0; j < 8; ++j)
      bf[j] = (_Float16)(w00 * (float)t00[j] + w01 * (float)t01[j]
                       + w10 * (float)t10[j] + w11 * (float)t11[j]);

    const f16x8* ap = Ap + q * 256;
#pragma unroll
    for (int m = 0; m < 4; ++m)
      acc[m] = __builtin_amdgcn_mfma_f32_16x16x32_f16(ap[m * 64], bf, acc[m], 0, 0, 0);
  }

  const int r0 = (lane >> 4) * 4;
#pragma unroll
  for (int m = 0; m < 4; ++m) {
    f16x4 hv;
#pragma unroll
    for (int r = 0; r < 4; ++r) {
      int oc = m * 16 + r0 + r;
      hv[r] = (_Float16)relu_(acc[m][r] + db[oc]);
    }
    *(f16x4*)&alh[(((size_t)b << 14) + pxl) * 64 + m * 16 + r0] = hv;
  }
}

// ---------------------------------------------------------------------------
// cat GEMM: out[b][oc][p] = relu(cat_w @ feat_align) + arm. K=64 (2 chunks).
// ---------------------------------------------------------------------------
__global__ __launch_bounds__(256) void cat_gemm_kernel(
    const _Float16* __restrict__ alh, const _Float16* __restrict__ WfC,
    const float* __restrict__ arm, float* __restrict__ out)
{
  const int b    = blockIdx.y;
  const int tid  = threadIdx.x;
  const int wv   = tid >> 6;
  const int lane = tid & 63;
  const int px0  = blockIdx.x * 64 + wv * 16;
  const int pxl  = px0 + (lane & 15);

  f32x4 acc[8];
#pragma unroll
  for (int m = 0; m < 8; ++m) acc[m] = (f32x4){0.f, 0.f, 0.f, 0.f};

  const f16x8* Bp = (const f16x8*)alh + (((size_t)b << 14) + pxl) * 8 + (lane >> 4);
  const f16x8* Ap = (const f16x8*)WfC + lane;

#pragma unroll
  for (int q = 0; q < 2; ++q) {
    f16x8 bf = Bp[q * 4];
#pragma unroll
    for (int m = 0; m < 8; ++m)
      acc[m] = __builtin_amdgcn_mfma_f32_16x16x32_f16(Ap[(q * 8 + m) * 64], bf, acc[m], 0, 0, 0);
  }

  const int r0 = (lane >> 4) * 4;
#pragma unroll
  for (int m = 0; m < 8; ++m) {
#pragma unroll
    for (int r = 0; r < 4; ++r) {
      int oc = m * 16 + r0 + r;
      size_t a = ((size_t)(b * 128 + oc) << 14) + pxl;
      out[a] = relu_(acc[m][r]) + arm[a];
    }
  }
}

// ---------------------------------------------------------------------------
// FALLBACK path kernels (small ws): round-1 versions
// ---------------------------------------------------------------------------
__global__ __launch_bounds__(256) void com_conv_kernel(
    const float* __restrict__ x, const float* __restrict__ cw,
    const float* __restrict__ cb, float* __restrict__ om)
{
  const int b    = blockIdx.z;
  const int ocg  = blockIdx.y;
  const int tile = blockIdx.x;
  const int th = (tile >> 2) * 32, tw = (tile & 3) * 32;
  const int tid = threadIdx.x;
  const int lw = (tid & 7) * 4;
  const int lh = tid >> 3;

  __shared__ float Xs[8 * 34 * 34];

  float acc[8][4];
#pragma unroll
  for (int a = 0; a < 8; ++a)
#pragma unroll
    for (int p = 0; p < 4; ++p) acc[a][p] = 0.f;

  for (int cc = 0; cc < 128; cc += 8) {
    __syncthreads();
    for (int idx = tid; idx < 8 * 1156; idx += 256) {
      int ic  = idx / 1156;
      int rem = idx - ic * 1156;
      int yy  = rem / 34;
      int xx  = rem - yy * 34;
      int gh = th + yy - 1, gw = tw + xx - 1;
      float v = 0.f;
      if ((unsigned)gh < 128u && (unsigned)gw < 128u)
        v = x[((size_t)(b * 128 + cc + ic) << 14) + (gh << 7) + gw];
      Xs[idx] = v;
    }
    __syncthreads();
#pragma unroll 1
    for (int ic = 0; ic < 8; ++ic) {
      float xr[3][6];
#pragma unroll
      for (int ky = 0; ky < 3; ++ky)
#pragma unroll
        for (int xx = 0; xx < 6; ++xx)
          xr[ky][xx] = Xs[ic * 1156 + (lh + ky) * 34 + lw + xx];
      const float* wp = cw + ((size_t)(ocg * 8) * 128 + (cc + ic)) * 9;
#pragma unroll
      for (int a = 0; a < 8; ++a) {
        const float* w9 = wp + a * 1152;
#pragma unroll
        for (int ky = 0; ky < 3; ++ky)
#pragma unroll
          for (int kx = 0; kx < 3; ++kx) {
            float wv = w9[ky * 3 + kx];
#pragma unroll
            for (int p = 0; p < 4; ++p)
              acc[a][p] = fmaf(wv, xr[ky][kx + p], acc[a][p]);
          }
      }
    }
  }

#pragma unroll
  for (int a = 0; a < 8; ++a) {
    int oc = ocg * 8 + a;
    float bv = cb[oc];
    float4 r = make_float4(acc[a][0] + bv, acc[a][1] + bv,
                           acc[a][2] + bv, acc[a][3] + bv);
    *(float4*)(om + ((size_t)(b * 216 + oc) << 14) + ((th + lh) << 7) + tw + lw) = r;
  }
}

__global__ __launch_bounds__(256) void wt_kernel(const float* __restrict__ dw,
                                                 float* __restrict__ wT)
{
  int idx = blockIdx.x * 256 + threadIdx.x;
  int o    = idx & 63;
  int rest = idx >> 6;
  int k    = rest % 9;
  int gc   = rest / 9;
  wT[idx] = dw[(o * 128 + gc) * 9 + k];
}

__global__ __launch_bounds__(256) void dcn_kernel(
    const float* __restrict__ fs, const float* __restrict__ om,
    const float* __restrict__ wT, const float* __restrict__ db,
    float* __restrict__ al)
{
  const int b   = blockIdx.y;
  const int p0  = blockIdx.x * 32;
  const int tid = threadIdx.x;
  const int px  = tid & 31;
  const int g   = tid >> 5;
  const int p = p0 + px;
  const int h = p >> 7, w = p & 127;

  float acc[64];
#pragma unroll
  for (int o = 0; o < 64; ++o) acc[o] = 0.f;

  const size_t omb = ((size_t)b * 216) << 14;
  const float* fsg = fs + (((size_t)(b * 128 + g * 16)) << 12);
  const float* wg  = wT + g * (16 * 9 * 64);

#pragma unroll 1
  for (int k = 0; k < 9; ++k) {
    float offy = om[omb + ((size_t)(g * 18 + 2 * k) << 14) + p];
    float offx = om[omb + ((size_t)(g * 18 + 2 * k + 1) << 14) + p];
    float mraw = om[omb + ((size_t)(144 + g * 9 + k) << 14) + p];
    float mv = 1.f / (1.f + __expf(-mraw));

    float py  = (float)(h + k / 3 - 1) + offy;
    float pxx = (float)(w + k % 3 - 1) + offx;
    float y0f = floorf(py), x0f = floorf(pxx);
    float ly = py - y0f, lx = pxx - x0f;
    int y0 = (int)y0f, x0i = (int)x0f;
    int y1 = y0 + 1, x1 = x0i + 1;

    int y0c = min(max(y0, 0), 127), y1c = min(max(y1, 0), 127);
    int x0c = min(max(x0i, 0), 127), x1c = min(max(x1, 0), 127);
    int ry0 = (y0c >> 1) << 6, ry1 = (y1c >> 1) << 6;
    int cx0 = x0c >> 1, cx1 = x1c >> 1;

    float w00 = (1.f - ly) * (1.f - lx) * mv;
    float w01 = (1.f - ly) * lx * mv;
    float w10 = ly * (1.f - lx) * mv;
    float w11 = ly * lx * mv;
    bool vy0 = (unsigned)y0 < 128u, vy1 = (unsigned)y1 < 128u;
    bool vx0 = (unsigned)x0i < 128u, vx1 = (unsigned)x1 < 128u;
    w00 = (vy0 && vx0) ? w00 : 0.f;
    w01 = (vy0 && vx1) ? w01 : 0.f;
    w10 = (vy1 && vx0) ? w10 : 0.f;
    w11 = (vy1 && vx1) ? w11 : 0.f;

#pragma unroll 1
    for (int c = 0; c < 16; ++c) {
      const float* fc = fsg + (c << 12);
      float v00 = fc[ry0 + cx0];
      float v01 = fc[ry0 + cx1];
      float v10 = fc[ry1 + cx0];
      float v11 = fc[ry1 + cx1];
      float v = w00 * v00 + w01 * v01 + w10 * v10 + w11 * v11;
      const float* wp = wg + (c * 9 + k) * 64;
#pragma unroll
      for (int oq = 0; oq < 16; ++oq) {
        float4 w4 = *(const float4*)(wp + oq * 4);
        acc[oq * 4 + 0] = fmaf(v, w4.x, acc[oq * 4 + 0]);
        acc[oq * 4 + 1] = fmaf(v, w4.y, acc[oq * 4 + 1]);
        acc[oq * 4 + 2] = fmaf(v, w4.z, acc[oq * 4 + 2]);
        acc[oq * 4 + 3] = fmaf(v, w4.w, acc[oq * 4 + 3]);
      }
    }
  }

  __shared__ float red[256][17];
  const int px2 = tid & 31;
  const int og  = tid >> 5;
#pragma unroll
  for (int r = 0; r < 4; ++r) {
    __syncthreads();
#pragma unroll
    for (int j = 0; j < 16; ++j) red[tid][j] = acc[r * 16 + j];
    __syncthreads();
#pragma unroll
    for (int jj = 0; jj < 2; ++jj) {
      int ol = og * 2 + jj;
      float s = 0.f;
#pragma unroll
      for (int gg = 0; gg < 8; ++gg) s += red[gg * 32 + px2][ol];
      int oc = r * 16 + ol;
      s += db[oc];
      al[((size_t)(b * 64 + oc) << 14) + p0 + px2] = fmaxf(s, 0.f);
    }
  }
}

// ---------------------------------------------------------------------------
extern "C" void kernel_launch(void* const* d_in, const int* in_sizes, int n_in,
                              void* d_out, int out_size, void* d_ws, size_t ws_size,
                              hipStream_t stream)
{
  const float* feat_l   = (const float*)d_in[0];
  const float* feat_s   = (const float*)d_in[1];
  const float* fsm_w    = (const float*)d_in[2];
  const float* offset_w = (const float*)d_in[3];
  const float* com_w    = (const float*)d_in[4];
  const float* com_b    = (const float*)d_in[5];
  const float* dcn_w    = (const float*)d_in[6];
  const float* dcn_b    = (const float*)d_in[7];
  const float* cat_w    = (const float*)d_in[8];
  float* out = (float*)d_out;
  float* ws  = (float*)d_ws;

  const size_t NEED = (size_t)(4194304 + 7077888 + 2097152 + 1048576 + 37748736) * 4;

  if (ws_size >= NEED) {
    float* arm      = ws;                          // 4,194,304 f32
    float* om       = ws + 4194304;                // 7,077,888 f32
    _Float16* alh   = (_Float16*)(ws + 11272192);  // 2,097,152 f16
    _Float16* Wf2   = (_Float16*)(ws + 12320768);  // 73,728 f16
    _Float16* WfC   = (_Float16*)(ws + 12357632);  // 8,192 f16
    _Float16* fsTh  = (_Float16*)(ws + 13369344);  // 1,048,576 f16
    _Float16* flTh  = (_Float16*)(ws + 13893632);  // 4,194,304 f16
    _Float16* armh  = (_Float16*)(ws + 15990784);  // 4,194,304 f16
    _Float16* offh  = (_Float16*)(ws + 18087936);  // 4,194,304 f16
    _Float16* WfA   = (_Float16*)(ws + 39059456);  // 16,384 f16
    _Float16* WfB   = (_Float16*)(ws + 39067648);  // 32,768 f16
    _Float16* WfP   = (_Float16*)(ws + 39084032);  // 294,912 f16

    hipLaunchKernelGGL(wfall_kernel, dim3(208), dim3(256), 0, stream,
                       fsm_w, offset_w, com_w, dcn_w, cat_w, WfA, WfB, WfP, Wf2, WfC);
    hipLaunchKernelGGL(t2h2_kernel, dim3(640, 4, 2), dim3(256), 0, stream,
                       feat_l, feat_s, flTh, fsTh);
    hipLaunchKernelGGL(fsm_gemm_kernel, dim3(256, 2), dim3(256), 0, stream,
                       flTh, WfA, arm, armh);
    hipLaunchKernelGGL(off_gemm_kernel, dim3(256, 2), dim3(256), 0, stream,
                       armh, fsTh, WfB, offh);
    hipLaunchKernelGGL(com_gemm_kernel, dim3(256, 2, 2), dim3(256), 0, stream,
                       offh, WfP, com_b, om);
    hipLaunchKernelGGL(dcn_fused_kernel, dim3(256, 2), dim3(256), 0, stream,
                       fsTh, om, Wf2, dcn_b, alh);
    hipLaunchKernelGGL(cat_gemm_kernel, dim3(256, 2), dim3(256), 0, stream,
                       alh, WfC, arm, out);
  } else {
    float* arm = ws;
    float* off = ws + 4194304;
    float* om  = ws + 8388608;
    float* al  = ws + 15466496;
    float* wT  = ws + 17563648;

    hipLaunchKernelGGL(wt_kernel, dim3(288), dim3(256), 0, stream, dcn_w, wT);
    hipLaunchKernelGGL((conv1x1_kernel<0, 128>), dim3(256, 2), dim3(256), 0, stream,
                       feat_l, nullptr, fsm_w, arm);
    hipLaunchKernelGGL((conv1x1_kernel<1, 256>), dim3(256, 2), dim3(256), 0, stream,
                       arm, feat_s, offset_w, off);
    hipLaunchKernelGGL(com_conv_kernel, dim3(16, 27, 2), dim3(256), 0, stream,
                       off, com_w, com_b, om);
    hipLaunchKernelGGL(dcn_kernel, dim3(512, 2), dim3(256), 0, stream,
                       feat_s, om, wT, dcn_b, al);
    hipLaunchKernelGGL((conv1x1_kernel<2, 64>), dim3(256, 2), dim3(256), 0, stream,
                       al, arm, cat_w, out);
  }
}